// Round 4
// baseline (735.096 us; speedup 1.0000x reference)
//
#include <hip/hip_runtime.h>

typedef unsigned short u16;
typedef unsigned int u32;
typedef __bf16 bf16x8 __attribute__((ext_vector_type(8)));
typedef float f32x4 __attribute__((ext_vector_type(4)));

#define B_ 2
#define T_ 2048
#define C_ 2048
#define H_ 16
#define HS_ 128
#define AL_ 10
#define C3_ 6144
#define MASKV (-3.0e38f)   // finite "-inf": exp(MASKV - m) == 0
#define MFMA16(a, b, c) __builtin_amdgcn_mfma_f32_16x16x32_bf16(a, b, c, 0, 0, 0)

// async global->LDS DMA, 16B per lane. LDS dest = wave-uniform base + lane*16;
// global src is per-lane. size MUST be a literal (guide: Common-mistake #1).
#define GLDS16(g, l) __builtin_amdgcn_global_load_lds(                         \
    (const __attribute__((address_space(1))) u32*)(const void*)(g),            \
    (__attribute__((address_space(3))) u32*)(void*)(l), 16, 0, 0)

__device__ __forceinline__ float b2f(u16 v) {
  union { u32 u; float f; } x; x.u = ((u32)v) << 16; return x.f;
}
__device__ __forceinline__ u16 f2b(float f) {
  u32 u = __builtin_bit_cast(u32, f);
  return (u16)((u + 0x7FFFu + ((u >> 16) & 1u)) >> 16);  // RNE
}
// fp32 -> bf16 -> fp32 (match the np ref's bf16-cast of fp32 inputs)
__device__ __forceinline__ float rb(float f) { return b2f(f2b(f)); }

// ---------------------------------------------------------------------------
// f32 -> bf16 bulk convert, 8 elem/thread (16B out per lane).
// ---------------------------------------------------------------------------
__global__ __launch_bounds__(256) void f32_to_bf16(
    const float* __restrict__ in, u16* __restrict__ out, int n8)
{
  const int i = blockIdx.x * 256 + threadIdx.x;
  if (i >= n8) return;
  union { float4 v[2]; float s[8]; } f;
  f.v[0] = *(const float4*)(in + (size_t)i * 8);
  f.v[1] = *(const float4*)(in + (size_t)i * 8 + 4);
  union { uint4 v; u16 e[8]; } o;
#pragma unroll
  for (int j = 0; j < 8; j++) o.e[j] = f2b(f.s[j]);
  *(uint4*)(out + (size_t)i * 8) = o.v;
}

// ---------------------------------------------------------------------------
// Fast GEMM (m97 structure): C(MxN) = A(MxK) * B(NxK)^T, both bf16, fp32
// accum. 128x128 tile, BK=32, 4 waves x 64x64 quadrant, global_load_lds
// width-16 staging, 2 barriers/iter, bijective XCD swizzle.
// ---------------------------------------------------------------------------
template <bool OUTF32>
__global__ __launch_bounds__(256) void gemm_lds(
    const u16* __restrict__ Ap, const u16* __restrict__ Bp,
    void* __restrict__ Cp, int N, int K, int lda)
{
  __shared__ u16 lA[128 * 32];
  __shared__ u16 lB[128 * 32];
  const int tid  = threadIdx.x;
  const int lane = tid & 63, wave = tid >> 6;
  const int quad = lane >> 4, l16 = lane & 15;
  const int nwg = gridDim.x * gridDim.y;
  int bid = blockIdx.y * gridDim.x + blockIdx.x;
  bid = (bid & 7) * (nwg >> 3) + (bid >> 3);
  const int bm = (bid / gridDim.x) * 128, bn = (bid % gridDim.x) * 128;
  const int wm = (wave >> 1) * 64, wn = (wave & 1) * 64;

  // staging map: LDS byte = wave*1024 + j*4096 + lane*16
  const int r0 = wave * 16 + (lane >> 2);
  const int c0 = (lane & 3) * 8;
  const u16* ga0 = Ap + (size_t)(bm + r0) * lda + c0;
  const u16* ga1 = ga0 + (size_t)64 * lda;
  const u16* gb0 = Bp + (size_t)(bn + r0) * K + c0;
  const u16* gb1 = gb0 + (size_t)64 * K;
  u16* la0 = &lA[wave * 512];
  u16* lb0 = &lB[wave * 512];

  f32x4 acc[4][4] = {};
  for (int k0 = 0; k0 < K; k0 += 32) {
    __syncthreads();                       // prior-iter LDS reads done
    GLDS16(ga0, la0);
    GLDS16(ga1, la0 + 2048);
    GLDS16(gb0, lb0);
    GLDS16(gb1, lb0 + 2048);
    ga0 += 32; ga1 += 32; gb0 += 32; gb1 += 32;
    __syncthreads();                       // DMA landed
    bf16x8 af[4], bfv[4];
#pragma unroll
    for (int i = 0; i < 4; i++)
      af[i] = *(const bf16x8*)&lA[(wm + i * 16 + l16) * 32 + quad * 8];
#pragma unroll
    for (int i = 0; i < 4; i++)
      bfv[i] = *(const bf16x8*)&lB[(wn + i * 16 + l16) * 32 + quad * 8];
#pragma unroll
    for (int i = 0; i < 4; i++)
#pragma unroll
      for (int j = 0; j < 4; j++)
        acc[i][j] = MFMA16(af[i], bfv[j], acc[i][j]);
  }
  // C/D layout: col = lane&15, row = quad*4 + reg  [m89/m91 verified]
#pragma unroll
  for (int i = 0; i < 4; i++) {
#pragma unroll
    for (int r = 0; r < 4; r++) {
      const int row = bm + wm + i * 16 + quad * 4 + r;
      if constexpr (OUTF32) {
        float* crow = (float*)Cp + (size_t)row * N + bn + wn + l16;
#pragma unroll
        for (int j = 0; j < 4; j++)
          crow[j * 16] = acc[i][j][r];
      } else {
        u16* crow = (u16*)Cp + (size_t)row * N + bn + wn + l16;
#pragma unroll
        for (int j = 0; j < 4; j++)
          crow[j * 16] = f2b(acc[i][j][r]);
      }
    }
  }
}

// ---------------------------------------------------------------------------
// Fallback GEMM (used only if ws_size can't host bf16 copies).
// ---------------------------------------------------------------------------
template <bool AF32, bool BF32, bool OUTF32>
__global__ __launch_bounds__(256) void gemm_nt(
    const void* __restrict__ Ap, const void* __restrict__ Bp,
    void* __restrict__ Cp, int N, int K, int lda)
{
  __shared__ u16 lA[128 * 32];
  __shared__ u16 lB[128 * 32];
  const int tid  = threadIdx.x;
  const int lane = tid & 63, wave = tid >> 6;
  const int quad = lane >> 4, l16 = lane & 15;
  const int bm = blockIdx.y * 128, bn = blockIdx.x * 128;
  const int wm = (wave >> 1) * 64, wn = (wave & 1) * 64;
  const int srow = tid >> 1, scol = (tid & 1) * 16;
  f32x4 acc[4][4] = {};

  for (int k0 = 0; k0 < K; k0 += 32) {
    __align__(16) u16 abuf[16], bbuf[16];
    if constexpr (AF32) {
      const float* gA = (const float*)Ap + (size_t)(bm + srow) * lda + scol + k0;
      union { float4 v[4]; float s[16]; } fa;
#pragma unroll
      for (int j = 0; j < 4; j++) fa.v[j] = *(const float4*)(gA + j * 4);
#pragma unroll
      for (int j = 0; j < 16; j++) abuf[j] = f2b(fa.s[j]);
    } else {
      const u16* gA = (const u16*)Ap + (size_t)(bm + srow) * lda + scol + k0;
      *(uint4*)&abuf[0] = *(const uint4*)(gA);
      *(uint4*)&abuf[8] = *(const uint4*)(gA + 8);
    }
    if constexpr (BF32) {
      const float* gB = (const float*)Bp + (size_t)(bn + srow) * K + scol + k0;
      union { float4 v[4]; float s[16]; } fb;
#pragma unroll
      for (int j = 0; j < 4; j++) fb.v[j] = *(const float4*)(gB + j * 4);
#pragma unroll
      for (int j = 0; j < 16; j++) bbuf[j] = f2b(fb.s[j]);
    } else {
      const u16* gB = (const u16*)Bp + (size_t)(bn + srow) * K + scol + k0;
      *(uint4*)&bbuf[0] = *(const uint4*)(gB);
      *(uint4*)&bbuf[8] = *(const uint4*)(gB + 8);
    }
    __syncthreads();
    *(uint4*)&lA[srow * 32 + scol]     = *(uint4*)&abuf[0];
    *(uint4*)&lA[srow * 32 + scol + 8] = *(uint4*)&abuf[8];
    *(uint4*)&lB[srow * 32 + scol]     = *(uint4*)&bbuf[0];
    *(uint4*)&lB[srow * 32 + scol + 8] = *(uint4*)&bbuf[8];
    __syncthreads();
    bf16x8 af[4], bfv[4];
#pragma unroll
    for (int i = 0; i < 4; i++)
      af[i] = *(const bf16x8*)&lA[(wm + i * 16 + l16) * 32 + quad * 8];
#pragma unroll
    for (int i = 0; i < 4; i++)
      bfv[i] = *(const bf16x8*)&lB[(wn + i * 16 + l16) * 32 + quad * 8];
#pragma unroll
    for (int i = 0; i < 4; i++)
#pragma unroll
      for (int j = 0; j < 4; j++)
        acc[i][j] = MFMA16(af[i], bfv[j], acc[i][j]);
  }
#pragma unroll
  for (int i = 0; i < 4; i++) {
#pragma unroll
    for (int r = 0; r < 4; r++) {
      const int row = bm + wm + i * 16 + quad * 4 + r;
      if constexpr (OUTF32) {
        float* crow = (float*)Cp + (size_t)row * N + bn + wn + l16;
#pragma unroll
        for (int j = 0; j < 4; j++)
          crow[j * 16] = acc[i][j][r];
      } else {
        u16* crow = (u16*)Cp + (size_t)row * N + bn + wn + l16;
#pragma unroll
        for (int j = 0; j < 4; j++)
          crow[j * 16] = f2b(acc[i][j][r]);
      }
    }
  }
}

// ---------------------------------------------------------------------------
// Adapter pqkv: ak/av[h][l][d] = bf16(adapter_emb[l]) . bf16(W_attn[...]).
// ---------------------------------------------------------------------------
__global__ __launch_bounds__(256) void adapter_pqkv(
    const float* __restrict__ emb, const float* __restrict__ W,
    float* __restrict__ akb, float* __restrict__ avb)
{
  const int tid = threadIdx.x;
  const int lane = tid & 63;
  const int w = blockIdx.x * 4 + (tid >> 6);      // 0..4095
  const int part = w >> 11;                        // 0 = k, 1 = v
  const int col = w & 2047;                        // h*128 + d
  const float* wrow = W + (size_t)(C_ + part * C_ + col) * C_;
  float acc[AL_];
#pragma unroll
  for (int l = 0; l < AL_; l++) acc[l] = 0.f;
  for (int i = 0; i < 32; i++) {
    const int c = i * 64 + lane;
    const float wv = rb(wrow[c]);
#pragma unroll
    for (int l = 0; l < AL_; l++) acc[l] += wv * rb(emb[l * C_ + c]);
  }
#pragma unroll
  for (int l = 0; l < AL_; l++) {
    for (int off = 32; off > 0; off >>= 1) acc[l] += __shfl_xor(acc[l], off);
  }
  if (lane == 0) {
    const int h = col >> 7, d = col & 127;
    float* dst = (part == 0 ? akb : avb) + (size_t)h * AL_ * HS_ + d;
#pragma unroll
    for (int l = 0; l < AL_; l++) dst[l * HS_] = acc[l];
  }
}

// ---------------------------------------------------------------------------
// RoPE in-place on qkv's q and k parts (qkv is bf16). rope table is FP32.
// ---------------------------------------------------------------------------
__global__ __launch_bounds__(256) void rope_inplace(
    u16* __restrict__ qkv, const float* __restrict__ rope)
{
  const int g = blockIdx.x * 256 + threadIdx.x;
  const int j2 = g & 63;
  const int h  = (g >> 6) & 15;
  const int t  = (g >> 10) & 2047;
  const int b  = g >> 21;
  u16* src = qkv + (size_t)(b * T_ + t) * C3_ + h * HS_ + j2 * 2;
  const u32 qp = *(const u32*)(src);
  const u32 kp = *(const u32*)(src + C_);
  const float2 rp = *(const float2*)(rope + (t * 64 + j2) * 2);
  const float c = rb(rp.x), s = rb(rp.y);
  const float q0 = b2f((u16)qp), q1 = b2f((u16)(qp >> 16));
  const float k0 = b2f((u16)kp), k1 = b2f((u16)(kp >> 16));
  const float qr0 = q0 * c - q1 * s, qr1 = q1 * c + q0 * s;
  const float kr0 = k0 * c - k1 * s, kr1 = k1 * c + k0 * s;
  *(u32*)(src)      = (u32)f2b(qr0) | ((u32)f2b(qr1) << 16);
  *(u32*)(src + C_) = (u32)f2b(kr0) | ((u32)f2b(kr1) << 16);
}

// ---------------------------------------------------------------------------
// V transpose: vt[b][h][d][t] = qkv v-part (bf16).
// ---------------------------------------------------------------------------
__global__ __launch_bounds__(256) void transpose_v(
    const u16* __restrict__ qkv, u16* __restrict__ vt)
{
  __shared__ __align__(16) char lT[64 * 256];
  const int tid = threadIdx.x;
  const int t0 = blockIdx.x * 64, h = blockIdx.y, b = blockIdx.z;
  const u16* Vg = qkv + (size_t)(b * T_ + t0) * C3_ + 2 * C_ + h * HS_;
#pragma unroll
  for (int i = 0; i < 4; i++) {
    const int e = (i * 256 + tid) * 8;      // u16 linear index in 64x128
    const int t = e >> 7, c = e & 127;
    *(uint4*)(lT + t * 256 + ((c * 2) ^ ((t & 7) << 4))) =
        *(const uint4*)(Vg + (size_t)t * C3_ + c);
  }
  __syncthreads();
  const int d = tid >> 1, half = tid & 1;
  __align__(16) u16 out[32];
#pragma unroll
  for (int tt = 0; tt < 32; tt++) {
    const int t = half * 32 + tt;
    out[tt] = *(const u16*)(lT + t * 256 + ((d * 2) ^ ((t & 7) << 4)));
  }
  u16* dst = vt + ((size_t)(b * H_ + h) * HS_ + d) * T_ + t0 + half * 32;
  *(uint4*)(dst)      = *(const uint4*)&out[0];
  *(uint4*)(dst + 8)  = *(const uint4*)&out[8];
  *(uint4*)(dst + 16) = *(const uint4*)&out[16];
  *(uint4*)(dst + 24) = *(const uint4*)&out[24];
}

// ---------------------------------------------------------------------------
// Flash attention + gated adapter attention.
// This round: double-buffered K/V LDS + T14 reg-staged prefetch (issue next
// tile's global loads before compute, write LDS after PV) -> barriers 3->2
// per kt and stage latency off the critical path; exact defer-max fast path
// (skip alpha-exp + O-rescale when the running max didn't grow; bit-exact
// since alpha==1 then); s_setprio(1) around MFMA clusters (m191).
// ---------------------------------------------------------------------------
__global__ __launch_bounds__(256) void attn_flash(
    u16* __restrict__ qkv, const u16* __restrict__ vt,
    const float* __restrict__ akbuf, const float* __restrict__ avbuf,
    const float* __restrict__ gating)
{
  __shared__ __align__(16) char smem[79872];
  char* smQ  = smem;                   // [0,32768)   128 rows x 256B swizzled
  char* smKb = smem + 32768;           // [32768,49152)  2 x (32 rows x 256B)
  char* smVb = smem + 49152;           // [49152,69632)  2 x (128 d-rows x 80B)
  char* smP  = smem + 69632;           // [69632,79872)  P: 128 rows x 80B

  const int tid  = threadIdx.x;
  const int lane = tid & 63, wave = tid >> 6;
  const int quad = lane >> 4, l16 = lane & 15;
  const int qt = 15 - (int)blockIdx.x, h = blockIdx.y, b = blockIdx.z;
  u16* Qg = qkv + ((size_t)(b * T_) + qt * 128) * C3_ + h * HS_;          // q-part
  const u16* Kg = qkv + (size_t)(b * T_) * C3_ + C_ + h * HS_;            // k-part
  const u16* Vt = vt + (size_t)(b * H_ + h) * HS_ * T_;
  const float scale = 0.08838834764831845f;   // 1/sqrt(128)

#pragma unroll
  for (int i = 0; i < 8; i++) {                // Q tile, swizzled rows
    const int e = (i * 256 + tid) * 8;
    const int row = e >> 7, col = e & 127;
    *(uint4*)(smQ + row * 256 + ((col * 2) ^ ((row & 7) << 4))) =
        *(const uint4*)(Qg + (size_t)row * C3_ + col);
  }
  f32x4 acc[2][8] = {};
  float mst[2][4], lst[2][4];
#pragma unroll
  for (int mt = 0; mt < 2; mt++)
#pragma unroll
    for (int r = 0; r < 4; r++) { mst[mt][r] = MASKV; lst[mt][r] = 0.f; }

  const int nkt = (qt + 1) * 4;
  const int krow = tid >> 3, kcolb = (tid & 7) * 32;   // K staging (byte col)
  const int ksw = (krow & 7) << 4;
  const int vd = tid >> 2, vc = tid & 3;               // V staging coords

  // ---- prologue: tile 0 -> buffer 0 ----
  uint4 pk0, pk1, pv0, pv1;
  {
    const u16* ks = Kg + (size_t)krow * C3_ + (kcolb >> 1);
    pk0 = *(const uint4*)(ks);
    pk1 = *(const uint4*)(ks + 8);
    const u16* vs = Vt + (size_t)vd * T_ + vc * 8;
    pv0 = *(const uint4*)(vs);
    pv1 = *(const uint4*)(vs + (size_t)64 * T_);
  }
  {
    char* kb = smKb + krow * 256;
    *(uint4*)(kb + (kcolb ^ ksw))        = pk0;
    *(uint4*)(kb + ((kcolb + 16) ^ ksw)) = pk1;
    *(uint4*)(smVb + vd * 80 + vc * 16)        = pv0;
    *(uint4*)(smVb + (64 + vd) * 80 + vc * 16) = pv1;
  }
  __syncthreads();                             // Q + tile0 visible

  int cur = 0;
  for (int kt = 0; kt < nkt; kt++) {
    // ---- T14: issue NEXT tile's global loads now; consume after PV ----
    if (kt + 1 < nkt) {
      const u16* ks = Kg + (size_t)((kt + 1) * 32 + krow) * C3_ + (kcolb >> 1);
      pk0 = *(const uint4*)(ks);
      pk1 = *(const uint4*)(ks + 8);
      const u16* vs = Vt + (size_t)vd * T_ + (kt + 1) * 32 + vc * 8;
      pv0 = *(const uint4*)(vs);
      pv1 = *(const uint4*)(vs + (size_t)64 * T_);
    }
    const char* smK = smKb + cur * 8192;
    const char* smV = smVb + cur * 10240;
    // ---- S = Q K^T ----
    f32x4 sacc[2][2] = {};
    const int sw = (l16 & 7) << 4;
    __builtin_amdgcn_s_setprio(1);
#pragma unroll
    for (int kk = 0; kk < 4; kk++) {
      const int co = (kk * 64 + quad * 16) ^ sw;
      bf16x8 aq0 = *(const bf16x8*)(smQ + (wave * 32 + l16) * 256 + co);
      bf16x8 aq1 = *(const bf16x8*)(smQ + (wave * 32 + 16 + l16) * 256 + co);
      bf16x8 bk0 = *(const bf16x8*)(smK + l16 * 256 + co);
      bf16x8 bk1 = *(const bf16x8*)(smK + (16 + l16) * 256 + co);
      sacc[0][0] = MFMA16(aq0, bk0, sacc[0][0]);
      sacc[0][1] = MFMA16(aq0, bk1, sacc[0][1]);
      sacc[1][0] = MFMA16(aq1, bk0, sacc[1][0]);
      sacc[1][1] = MFMA16(aq1, bk1, sacc[1][1]);
    }
    __builtin_amdgcn_s_setprio(0);
    // ---- online softmax (exact defer-max fast path) ----
#pragma unroll
    for (int mt = 0; mt < 2; mt++) {
      float p0[4], p1[4], mnew[4], rs[4];
      bool grow = false;
#pragma unroll
      for (int r = 0; r < 4; r++) {
        const int qg = qt * 128 + wave * 32 + mt * 16 + quad * 4 + r;
        float s0 = sacc[mt][0][r] * scale;
        float s1 = sacc[mt][1][r] * scale;
        if (kt * 32 + l16 > qg)      s0 = MASKV;
        if (kt * 32 + 16 + l16 > qg) s1 = MASKV;
        float rmax = fmaxf(s0, s1);
#pragma unroll
        for (int off = 1; off < 16; off <<= 1)
          rmax = fmaxf(rmax, __shfl_xor(rmax, off));
        grow |= (rmax > mst[mt][r]);
        mnew[r] = fmaxf(mst[mt][r], rmax);
        p0[r] = __expf(s0 - mnew[r]);
        p1[r] = __expf(s1 - mnew[r]);
        float rsv = p0[r] + p1[r];
#pragma unroll
        for (int off = 1; off < 16; off <<= 1)
          rsv += __shfl_xor(rsv, off);
        rs[r] = rsv;
      }
      if (__any(grow)) {                       // rescale path
        float alpha[4];
#pragma unroll
        for (int r = 0; r < 4; r++) {
          alpha[r] = __expf(mst[mt][r] - mnew[r]);
          mst[mt][r] = mnew[r];
          lst[mt][r] = lst[mt][r] * alpha[r] + rs[r];
        }
#pragma unroll
        for (int nt = 0; nt < 8; nt++)
#pragma unroll
          for (int r = 0; r < 4; r++) acc[mt][nt][r] *= alpha[r];
      } else {                                 // max unchanged: alpha == 1 exactly
#pragma unroll
        for (int r = 0; r < 4; r++) lst[mt][r] += rs[r];
      }
#pragma unroll
      for (int r = 0; r < 4; r++) {            // P: C-layout -> row-major LDS
        const int row = wave * 32 + mt * 16 + quad * 4 + r;
        *(u16*)(smP + row * 80 + l16 * 2)      = f2b(p0[r]);
        *(u16*)(smP + row * 80 + 32 + l16 * 2) = f2b(p1[r]);
      }
    }
    // ---- fence: P-stores ordered before P-loads ----
    __syncthreads();
    // ---- O += P V ----
    __builtin_amdgcn_s_setprio(1);
#pragma unroll
    for (int mt = 0; mt < 2; mt++) {
      bf16x8 ap = *(const bf16x8*)(smP + (wave * 32 + mt * 16 + l16) * 80 + quad * 16);
#pragma unroll
      for (int nt = 0; nt < 8; nt++) {
        bf16x8 bv = *(const bf16x8*)(smV + (nt * 16 + l16) * 80 + quad * 16);
        acc[mt][nt] = MFMA16(ap, bv, acc[mt][nt]);
      }
    }
    __builtin_amdgcn_s_setprio(0);
    // ---- write prefetched tile into the other buffer ----
    if (kt + 1 < nkt) {
      const int nb = cur ^ 1;
      char* kb = smKb + nb * 8192 + krow * 256;
      *(uint4*)(kb + (kcolb ^ ksw))        = pk0;
      *(uint4*)(kb + ((kcolb + 16) ^ ksw)) = pk1;
      char* vb = smVb + nb * 10240;
      *(uint4*)(vb + vd * 80 + vc * 16)        = pv0;
      *(uint4*)(vb + (64 + vd) * 80 + vc * 16) = pv1;
    }
    cur ^= 1;
    __syncthreads();                           // next buffer visible; P reads done
  }
  // ---- adapter attention (10 prefix keys, separate softmax) ----
  // loop's trailing barrier: all waves past PV; lK/lV/lP dead
  float* lAk = (float*)smKb;                   // overlay [32768,43008)
  float* lAv = lAk + AL_ * HS_;
  {
    const float* aks = akbuf + (size_t)h * AL_ * HS_;
    const float* avs = avbuf + (size_t)h * AL_ * HS_;
    for (int i = tid; i < AL_ * HS_; i += 256) { lAk[i] = aks[i]; lAv[i] = avs[i]; }
  }
  __syncthreads();
  const int ar = tid >> 1, ah = tid & 1;       // 2 threads per q-row
  const int asw = (ar & 7) << 4;
  float sa[AL_];
#pragma unroll
  for (int l = 0; l < AL_; l++) sa[l] = 0.f;
#pragma unroll
  for (int c = 0; c < 8; c++) {                // own half of d, b128 reads
    const int col = ah * 64 + c * 8;
    union { uint4 v; u16 e[8]; } qv;
    qv.v = *(const uint4*)(smQ + ar * 256 + ((col * 2) ^ asw));
#pragma unroll
    for (int j = 0; j < 8; j++) {
      const float qf = b2f(qv.e[j]);
#pragma unroll
      for (int l = 0; l < AL_; l++) sa[l] += qf * lAk[l * HS_ + col + j];
    }
  }
#pragma unroll
  for (int l = 0; l < AL_; l++) sa[l] = (sa[l] + __shfl_xor(sa[l], 1)) * scale;
  float smax = sa[0];
#pragma unroll
  for (int l = 1; l < AL_; l++) smax = fmaxf(smax, sa[l]);
  float ssum = 0.f;
#pragma unroll
  for (int l = 0; l < AL_; l++) { sa[l] = __expf(sa[l] - smax); ssum += sa[l]; }
  const float inv = 1.f / ssum;
#pragma unroll
  for (int l = 0; l < AL_; l++) sa[l] *= inv;
  __syncthreads();                             // all lQ reads done -> overlay lAy
  u16* lAy = (u16*)smem;                       // 128 x 128, linear
#pragma unroll
  for (int c = 0; c < 8; c++) {
    const int col = ah * 64 + c * 8;
    union { uint4 v; u16 e[8]; } ov;
#pragma unroll
    for (int j = 0; j < 8; j++) {
      float a = 0.f;
#pragma unroll
      for (int l = 0; l < AL_; l++) a += sa[l] * lAv[l * HS_ + col + j];
      ov.e[j] = f2b(a);
    }
    *(uint4*)(lAy + ar * HS_ + col) = ov.v;
  }
  __syncthreads();
  // ---- epilogue: y = O/l + g*ay, written over qkv q-part (block's own patch)
  const float g = rb(gating[h]);
#pragma unroll
  for (int mt = 0; mt < 2; mt++) {
#pragma unroll
    for (int r = 0; r < 4; r++) {
      const int row = wave * 32 + mt * 16 + quad * 4 + r;
      const float linv = 1.f / lst[mt][r];
      u16* yrow = Qg + (size_t)row * C3_ + l16;
#pragma unroll
      for (int nt = 0; nt < 8; nt++) {
        const float v = acc[mt][nt][r] * linv + g * b2f(lAy[row * HS_ + nt * 16 + l16]);
        yrow[nt * 16] = f2b(v);
      }
    }
  }
}

// ---------------------------------------------------------------------------
extern "C" void kernel_launch(void* const* d_in, const int* in_sizes, int n_in,
                              void* d_out, int out_size, void* d_ws, size_t ws_size,
                              hipStream_t stream) {
  (void)out_size;
  int ix = 0, irope = 1, iW = 3, iP = 4, iE = 5, iG = 6;
  for (int i = 0; i < n_in; i++) {
    switch (in_sizes[i]) {
      case 8388608:  ix = i;    break;   // x (2,2048,2048)
      case 262144:   irope = i; break;   // rope (2048,64,2)
      case 12582912: iW = i;    break;   // W_attn (6144,2048)
      case 20480:    iE = i;    break;   // adapter_emb (10,2048)
      case 16:       iG = i;    break;   // gating (1,16,1,1)
      case 4194304:  iP = i;    break;   // mask (idx 2) then W_proj (idx 4): last wins
      default: break;
    }
  }
  const float* x      = (const float*)d_in[ix];
  const float* rope   = (const float*)d_in[irope];
  const float* W_attn = (const float*)d_in[iW];
  const float* W_proj = (const float*)d_in[iP];
  const float* emb    = (const float*)d_in[iE];
  const float* gating = (const float*)d_in[iG];

  // Workspace layout (fast path, 96 MiB):
  //   [0,48M) qkv bf16 | [48,64M) xb | [64,88M) Wab | [88,96M) Wpb
  // d_out (32 MiB, dead until proj GEMM) hosts ak/av fp32 (160 KiB) + vt (16 MiB).
  u16*   qkv = (u16*)d_ws;
  float* akb = (float*)d_out;
  float* avb = akb + (size_t)H_ * AL_ * HS_;
  u16*   vtb = (u16*)(avb + (size_t)H_ * AL_ * HS_);

  const bool fast = ws_size >= (size_t)100663296;  // 96 MiB
  if (fast) {
    u16* xb  = qkv + (size_t)25165824;   // 48 MiB / 2
    u16* Wab = xb  + (size_t)8388608;
    u16* Wpb = Wab + (size_t)12582912;
    f32_to_bf16<<<dim3(4096), 256, 0, stream>>>(x, xb, 1048576);
    f32_to_bf16<<<dim3(6144), 256, 0, stream>>>(W_attn, Wab, 1572864);
    f32_to_bf16<<<dim3(2048), 256, 0, stream>>>(W_proj, Wpb, 524288);
    gemm_lds<false><<<dim3(48, 32), 256, 0, stream>>>(xb, Wab, qkv, 6144, 2048, 2048);
    adapter_pqkv<<<dim3(1024), 256, 0, stream>>>(emb, W_attn, akb, avb);
    rope_inplace<<<dim3(16384), 256, 0, stream>>>(qkv, rope);
    transpose_v<<<dim3(32, 16, 2), 256, 0, stream>>>(qkv, vtb);
    attn_flash<<<dim3(16, 16, 2), 256, 0, stream>>>(qkv, vtb, akb, avb, gating);
    gemm_lds<true><<<dim3(16, 32), 256, 0, stream>>>(qkv, Wpb, (float*)d_out, 2048, 2048, 6144);
  } else {
    gemm_nt<true, true, false><<<dim3(48, 32), 256, 0, stream>>>(
        x, W_attn, qkv, 6144, 2048, 2048);
    adapter_pqkv<<<dim3(1024), 256, 0, stream>>>(emb, W_attn, akb, avb);
    rope_inplace<<<dim3(16384), 256, 0, stream>>>(qkv, rope);
    transpose_v<<<dim3(32, 16, 2), 256, 0, stream>>>(qkv, vtb);
    attn_flash<<<dim3(16, 16, 2), 256, 0, stream>>>(qkv, vtb, akb, avb, gating);
    gemm_nt<false, true, true><<<dim3(16, 32), 256, 0, stream>>>(
        qkv, W_proj, (float*)d_out, 2048, 2048, 6144);
  }
}

// Round 5
// 629.843 us; speedup vs baseline: 1.1671x; 1.1671x over previous
//
#include <hip/hip_runtime.h>

typedef unsigned short u16;
typedef unsigned int u32;
typedef __bf16 bf16x8 __attribute__((ext_vector_type(8)));
typedef float f32x4 __attribute__((ext_vector_type(4)));

#define B_ 2
#define T_ 2048
#define C_ 2048
#define H_ 16
#define HS_ 128
#define AL_ 10
#define C3_ 6144
#define MASKV (-3.0e38f)   // finite "-inf": exp(MASKV - m) == 0
#define MFMA16(a, b, c) __builtin_amdgcn_mfma_f32_16x16x32_bf16(a, b, c, 0, 0, 0)

// async global->LDS DMA, 16B per lane. LDS dest = wave-uniform base + lane*16;
// global src is per-lane. size MUST be a literal (guide: Common-mistake #1).
#define GLDS16(g, l) __builtin_amdgcn_global_load_lds(                         \
    (const __attribute__((address_space(1))) u32*)(const void*)(g),            \
    (__attribute__((address_space(3))) u32*)(void*)(l), 16, 0, 0)

__device__ __forceinline__ float b2f(u16 v) {
  union { u32 u; float f; } x; x.u = ((u32)v) << 16; return x.f;
}
__device__ __forceinline__ u16 f2b(float f) {
  u32 u = __builtin_bit_cast(u32, f);
  return (u16)((u + 0x7FFFu + ((u >> 16) & 1u)) >> 16);  // RNE
}
// fp32 -> bf16 -> fp32 (match the np ref's bf16-cast of fp32 inputs)
__device__ __forceinline__ float rb(float f) { return b2f(f2b(f)); }

// ---------------------------------------------------------------------------
// f32 -> bf16 bulk convert, 8 elem/thread (16B out per lane).
// ---------------------------------------------------------------------------
__global__ __launch_bounds__(256) void f32_to_bf16(
    const float* __restrict__ in, u16* __restrict__ out, int n8)
{
  const int i = blockIdx.x * 256 + threadIdx.x;
  if (i >= n8) return;
  union { float4 v[2]; float s[8]; } f;
  f.v[0] = *(const float4*)(in + (size_t)i * 8);
  f.v[1] = *(const float4*)(in + (size_t)i * 8 + 4);
  union { uint4 v; u16 e[8]; } o;
#pragma unroll
  for (int j = 0; j < 8; j++) o.e[j] = f2b(f.s[j]);
  *(uint4*)(out + (size_t)i * 8) = o.v;
}

// ---------------------------------------------------------------------------
// Fast GEMM (m97 structure): C(MxN) = A(MxK) * B(NxK)^T, both bf16, fp32
// accum. 128x128 tile, BK=32, 4 waves x 64x64 quadrant, global_load_lds
// width-16 staging, 2 barriers/iter, bijective XCD swizzle. (unchanged)
// ---------------------------------------------------------------------------
template <bool OUTF32>
__global__ __launch_bounds__(256) void gemm_lds(
    const u16* __restrict__ Ap, const u16* __restrict__ Bp,
    void* __restrict__ Cp, int N, int K, int lda)
{
  __shared__ u16 lA[128 * 32];
  __shared__ u16 lB[128 * 32];
  const int tid  = threadIdx.x;
  const int lane = tid & 63, wave = tid >> 6;
  const int quad = lane >> 4, l16 = lane & 15;
  const int nwg = gridDim.x * gridDim.y;
  int bid = blockIdx.y * gridDim.x + blockIdx.x;
  bid = (bid & 7) * (nwg >> 3) + (bid >> 3);
  const int bm = (bid / gridDim.x) * 128, bn = (bid % gridDim.x) * 128;
  const int wm = (wave >> 1) * 64, wn = (wave & 1) * 64;

  // staging map: LDS byte = wave*1024 + j*4096 + lane*16
  const int r0 = wave * 16 + (lane >> 2);
  const int c0 = (lane & 3) * 8;
  const u16* ga0 = Ap + (size_t)(bm + r0) * lda + c0;
  const u16* ga1 = ga0 + (size_t)64 * lda;
  const u16* gb0 = Bp + (size_t)(bn + r0) * K + c0;
  const u16* gb1 = gb0 + (size_t)64 * K;
  u16* la0 = &lA[wave * 512];
  u16* lb0 = &lB[wave * 512];

  f32x4 acc[4][4] = {};
  for (int k0 = 0; k0 < K; k0 += 32) {
    __syncthreads();                       // prior-iter LDS reads done
    GLDS16(ga0, la0);
    GLDS16(ga1, la0 + 2048);
    GLDS16(gb0, lb0);
    GLDS16(gb1, lb0 + 2048);
    ga0 += 32; ga1 += 32; gb0 += 32; gb1 += 32;
    __syncthreads();                       // DMA landed
    bf16x8 af[4], bfv[4];
#pragma unroll
    for (int i = 0; i < 4; i++)
      af[i] = *(const bf16x8*)&lA[(wm + i * 16 + l16) * 32 + quad * 8];
#pragma unroll
    for (int i = 0; i < 4; i++)
      bfv[i] = *(const bf16x8*)&lB[(wn + i * 16 + l16) * 32 + quad * 8];
#pragma unroll
    for (int i = 0; i < 4; i++)
#pragma unroll
      for (int j = 0; j < 4; j++)
        acc[i][j] = MFMA16(af[i], bfv[j], acc[i][j]);
  }
  // C/D layout: col = lane&15, row = quad*4 + reg  [m89/m91 verified]
#pragma unroll
  for (int i = 0; i < 4; i++) {
#pragma unroll
    for (int r = 0; r < 4; r++) {
      const int row = bm + wm + i * 16 + quad * 4 + r;
      if constexpr (OUTF32) {
        float* crow = (float*)Cp + (size_t)row * N + bn + wn + l16;
#pragma unroll
        for (int j = 0; j < 4; j++)
          crow[j * 16] = acc[i][j][r];
      } else {
        u16* crow = (u16*)Cp + (size_t)row * N + bn + wn + l16;
#pragma unroll
        for (int j = 0; j < 4; j++)
          crow[j * 16] = f2b(acc[i][j][r]);
      }
    }
  }
}

// ---------------------------------------------------------------------------
// Fallback GEMM (used only if ws_size can't host bf16 copies).
// ---------------------------------------------------------------------------
template <bool AF32, bool BF32, bool OUTF32>
__global__ __launch_bounds__(256) void gemm_nt(
    const void* __restrict__ Ap, const void* __restrict__ Bp,
    void* __restrict__ Cp, int N, int K, int lda)
{
  __shared__ u16 lA[128 * 32];
  __shared__ u16 lB[128 * 32];
  const int tid  = threadIdx.x;
  const int lane = tid & 63, wave = tid >> 6;
  const int quad = lane >> 4, l16 = lane & 15;
  const int bm = blockIdx.y * 128, bn = blockIdx.x * 128;
  const int wm = (wave >> 1) * 64, wn = (wave & 1) * 64;
  const int srow = tid >> 1, scol = (tid & 1) * 16;
  f32x4 acc[4][4] = {};

  for (int k0 = 0; k0 < K; k0 += 32) {
    __align__(16) u16 abuf[16], bbuf[16];
    if constexpr (AF32) {
      const float* gA = (const float*)Ap + (size_t)(bm + srow) * lda + scol + k0;
      union { float4 v[4]; float s[16]; } fa;
#pragma unroll
      for (int j = 0; j < 4; j++) fa.v[j] = *(const float4*)(gA + j * 4);
#pragma unroll
      for (int j = 0; j < 16; j++) abuf[j] = f2b(fa.s[j]);
    } else {
      const u16* gA = (const u16*)Ap + (size_t)(bm + srow) * lda + scol + k0;
      *(uint4*)&abuf[0] = *(const uint4*)(gA);
      *(uint4*)&abuf[8] = *(const uint4*)(gA + 8);
    }
    if constexpr (BF32) {
      const float* gB = (const float*)Bp + (size_t)(bn + srow) * K + scol + k0;
      union { float4 v[4]; float s[16]; } fb;
#pragma unroll
      for (int j = 0; j < 4; j++) fb.v[j] = *(const float4*)(gB + j * 4);
#pragma unroll
      for (int j = 0; j < 16; j++) bbuf[j] = f2b(fb.s[j]);
    } else {
      const u16* gB = (const u16*)Bp + (size_t)(bn + srow) * K + scol + k0;
      *(uint4*)&bbuf[0] = *(const uint4*)(gB);
      *(uint4*)&bbuf[8] = *(const uint4*)(gB + 8);
    }
    __syncthreads();
    *(uint4*)&lA[srow * 32 + scol]     = *(uint4*)&abuf[0];
    *(uint4*)&lA[srow * 32 + scol + 8] = *(uint4*)&abuf[8];
    *(uint4*)&lB[srow * 32 + scol]     = *(uint4*)&bbuf[0];
    *(uint4*)&lB[srow * 32 + scol + 8] = *(uint4*)&bbuf[8];
    __syncthreads();
    bf16x8 af[4], bfv[4];
#pragma unroll
    for (int i = 0; i < 4; i++)
      af[i] = *(const bf16x8*)&lA[(wm + i * 16 + l16) * 32 + quad * 8];
#pragma unroll
    for (int i = 0; i < 4; i++)
      bfv[i] = *(const bf16x8*)&lB[(wn + i * 16 + l16) * 32 + quad * 8];
#pragma unroll
    for (int i = 0; i < 4; i++)
#pragma unroll
      for (int j = 0; j < 4; j++)
        acc[i][j] = MFMA16(af[i], bfv[j], acc[i][j]);
  }
#pragma unroll
  for (int i = 0; i < 4; i++) {
#pragma unroll
    for (int r = 0; r < 4; r++) {
      const int row = bm + wm + i * 16 + quad * 4 + r;
      if constexpr (OUTF32) {
        float* crow = (float*)Cp + (size_t)row * N + bn + wn + l16;
#pragma unroll
        for (int j = 0; j < 4; j++)
          crow[j * 16] = acc[i][j][r];
      } else {
        u16* crow = (u16*)Cp + (size_t)row * N + bn + wn + l16;
#pragma unroll
        for (int j = 0; j < 4; j++)
          crow[j * 16] = f2b(acc[i][j][r]);
      }
    }
  }
}

// ---------------------------------------------------------------------------
// Adapter pqkv: ak/av[h][l][d] = bf16(adapter_emb[l]) . bf16(W_attn[...]).
// ---------------------------------------------------------------------------
__global__ __launch_bounds__(256) void adapter_pqkv(
    const float* __restrict__ emb, const float* __restrict__ W,
    float* __restrict__ akb, float* __restrict__ avb)
{
  const int tid = threadIdx.x;
  const int lane = tid & 63;
  const int w = blockIdx.x * 4 + (tid >> 6);      // 0..4095
  const int part = w >> 11;                        // 0 = k, 1 = v
  const int col = w & 2047;                        // h*128 + d
  const float* wrow = W + (size_t)(C_ + part * C_ + col) * C_;
  float acc[AL_];
#pragma unroll
  for (int l = 0; l < AL_; l++) acc[l] = 0.f;
  for (int i = 0; i < 32; i++) {
    const int c = i * 64 + lane;
    const float wv = rb(wrow[c]);
#pragma unroll
    for (int l = 0; l < AL_; l++) acc[l] += wv * rb(emb[l * C_ + c]);
  }
#pragma unroll
  for (int l = 0; l < AL_; l++) {
    for (int off = 32; off > 0; off >>= 1) acc[l] += __shfl_xor(acc[l], off);
  }
  if (lane == 0) {
    const int h = col >> 7, d = col & 127;
    float* dst = (part == 0 ? akb : avb) + (size_t)h * AL_ * HS_ + d;
#pragma unroll
    for (int l = 0; l < AL_; l++) dst[l * HS_] = acc[l];
  }
}

// ---------------------------------------------------------------------------
// RoPE in-place on qkv's q and k parts (qkv is bf16). rope table is FP32.
// ---------------------------------------------------------------------------
__global__ __launch_bounds__(256) void rope_inplace(
    u16* __restrict__ qkv, const float* __restrict__ rope)
{
  const int g = blockIdx.x * 256 + threadIdx.x;
  const int j2 = g & 63;
  const int h  = (g >> 6) & 15;
  const int t  = (g >> 10) & 2047;
  const int b  = g >> 21;
  u16* src = qkv + (size_t)(b * T_ + t) * C3_ + h * HS_ + j2 * 2;
  const u32 qp = *(const u32*)(src);
  const u32 kp = *(const u32*)(src + C_);
  const float2 rp = *(const float2*)(rope + (t * 64 + j2) * 2);
  const float c = rb(rp.x), s = rb(rp.y);
  const float q0 = b2f((u16)qp), q1 = b2f((u16)(qp >> 16));
  const float k0 = b2f((u16)kp), k1 = b2f((u16)(kp >> 16));
  const float qr0 = q0 * c - q1 * s, qr1 = q1 * c + q0 * s;
  const float kr0 = k0 * c - k1 * s, kr1 = k1 * c + k0 * s;
  *(u32*)(src)      = (u32)f2b(qr0) | ((u32)f2b(qr1) << 16);
  *(u32*)(src + C_) = (u32)f2b(kr0) | ((u32)f2b(kr1) << 16);
}

// ---------------------------------------------------------------------------
// V transpose: vt[b][h][d][t] = qkv v-part (bf16).
// ---------------------------------------------------------------------------
__global__ __launch_bounds__(256) void transpose_v(
    const u16* __restrict__ qkv, u16* __restrict__ vt)
{
  __shared__ __align__(16) char lT[64 * 256];
  const int tid = threadIdx.x;
  const int t0 = blockIdx.x * 64, h = blockIdx.y, b = blockIdx.z;
  const u16* Vg = qkv + (size_t)(b * T_ + t0) * C3_ + 2 * C_ + h * HS_;
#pragma unroll
  for (int i = 0; i < 4; i++) {
    const int e = (i * 256 + tid) * 8;      // u16 linear index in 64x128
    const int t = e >> 7, c = e & 127;
    *(uint4*)(lT + t * 256 + ((c * 2) ^ ((t & 7) << 4))) =
        *(const uint4*)(Vg + (size_t)t * C3_ + c);
  }
  __syncthreads();
  const int d = tid >> 1, half = tid & 1;
  __align__(16) u16 out[32];
#pragma unroll
  for (int tt = 0; tt < 32; tt++) {
    const int t = half * 32 + tt;
    out[tt] = *(const u16*)(lT + t * 256 + ((d * 2) ^ ((t & 7) << 4)));
  }
  u16* dst = vt + ((size_t)(b * H_ + h) * HS_ + d) * T_ + t0 + half * 32;
  *(uint4*)(dst)      = *(const uint4*)&out[0];
  *(uint4*)(dst + 8)  = *(const uint4*)&out[8];
  *(uint4*)(dst + 16) = *(const uint4*)&out[16];
  *(uint4*)(dst + 24) = *(const uint4*)&out[24];
}

// ---------------------------------------------------------------------------
// Flash attention + gated adapter attention.
// R4 post-mortem: the dbuf/prefetch/setprio/defer bundle regressed 17% ->
// reverted to the R1 3-barrier loop semantics. This round's single variable:
// QBLK 128 -> 64 (one 16-row tier per wave), LDS 61440 -> 39936 B ->
// 4 blocks/CU instead of 2 (cross-block latency hiding), launch_bounds(256,4)
// caps VGPR at 128 so occupancy is LDS-bound, grid.x 16 -> 32.
// y written IN-PLACE over qkv q-part (block-private patch).
// ---------------------------------------------------------------------------
__global__ __launch_bounds__(256, 4) void attn_flash(
    u16* __restrict__ qkv, const u16* __restrict__ vt,
    const float* __restrict__ akbuf, const float* __restrict__ avbuf,
    const float* __restrict__ gating)
{
  __shared__ __align__(16) char smem[39936];
  char* smQ = smem;                    // [0,16384)   64 rows x 256B swizzled
  char* smK = smem + 16384;            // [16384,24576)  32 rows x 256B swizzled
  char* smV = smem + 24576;            // [24576,34816)  Vt: 128 d-rows x 80B
  char* smP = smem + 34816;            // [34816,39936)  P: 64 rows x 80B

  const int tid  = threadIdx.x;
  const int lane = tid & 63, wave = tid >> 6;
  const int quad = lane >> 4, l16 = lane & 15;
  const int qt = 31 - (int)blockIdx.x, h = blockIdx.y, b = blockIdx.z;
  u16* Qg = qkv + ((size_t)(b * T_) + qt * 64) * C3_ + h * HS_;           // q-part
  const u16* Kg = qkv + (size_t)(b * T_) * C3_ + C_ + h * HS_;            // k-part
  const u16* Vt = vt + (size_t)(b * H_ + h) * HS_ * T_;
  const float scale = 0.08838834764831845f;   // 1/sqrt(128)

#pragma unroll
  for (int i = 0; i < 4; i++) {                // Q tile (64 rows), swizzled
    const int e = (i * 256 + tid) * 8;
    const int row = e >> 7, col = e & 127;
    *(uint4*)(smQ + row * 256 + ((col * 2) ^ ((row & 7) << 4))) =
        *(const uint4*)(Qg + (size_t)row * C3_ + col);
  }
  f32x4 acc[8] = {};
  float mst[4], lst[4];
#pragma unroll
  for (int r = 0; r < 4; r++) { mst[r] = MASKV; lst[r] = 0.f; }

  const int nkt = (qt + 1) * 2;
  const int krow = tid >> 3, kcolb = (tid & 7) * 32;   // K staging (byte col)
  const int ksw = (krow & 7) << 4;
  for (int kt = 0; kt < nkt; kt++) {
    __syncthreads();                           // prior-iter lK/lV/lP reads done
    {
      const u16* ks = Kg + (size_t)(kt * 32 + krow) * C3_ + (kcolb >> 1);
      char* kb = smK + krow * 256;
      *(uint4*)(kb + ((kcolb)      ^ ksw)) = *(const uint4*)(ks);
      *(uint4*)(kb + ((kcolb + 16) ^ ksw)) = *(const uint4*)(ks + 8);
      // Vt tile: 128 d-rows x 32 keys, coalesced 64B-per-4-lanes reads
#pragma unroll
      for (int it = 0; it < 2; it++) {
        const int d = it * 64 + (tid >> 2), c = tid & 3;
        *(uint4*)(smV + d * 80 + c * 16) =
            *(const uint4*)(Vt + (size_t)d * T_ + kt * 32 + c * 8);
      }
    }
    __syncthreads();
    // ---- S = Q K^T (one 16-row tier per wave) ----
    f32x4 sacc[2] = {};
    const int sw = (l16 & 7) << 4;
#pragma unroll
    for (int kk = 0; kk < 4; kk++) {
      const int co = (kk * 64 + quad * 16) ^ sw;
      bf16x8 aq  = *(const bf16x8*)(smQ + (wave * 16 + l16) * 256 + co);
      bf16x8 bk0 = *(const bf16x8*)(smK + l16 * 256 + co);
      bf16x8 bk1 = *(const bf16x8*)(smK + (16 + l16) * 256 + co);
      sacc[0] = MFMA16(aq, bk0, sacc[0]);
      sacc[1] = MFMA16(aq, bk1, sacc[1]);
    }
    // ---- online softmax ----
    {
      float p0[4], p1[4], alpha[4];
#pragma unroll
      for (int r = 0; r < 4; r++) {
        const int qg = qt * 64 + wave * 16 + quad * 4 + r;
        float s0 = sacc[0][r] * scale;
        float s1 = sacc[1][r] * scale;
        if (kt * 32 + l16 > qg)      s0 = MASKV;
        if (kt * 32 + 16 + l16 > qg) s1 = MASKV;
        float rmax = fmaxf(s0, s1);
#pragma unroll
        for (int off = 1; off < 16; off <<= 1)
          rmax = fmaxf(rmax, __shfl_xor(rmax, off));
        const float mnew = fmaxf(mst[r], rmax);
        alpha[r] = __expf(mst[r] - mnew);
        mst[r] = mnew;
        p0[r] = __expf(s0 - mnew);
        p1[r] = __expf(s1 - mnew);
        float rs = p0[r] + p1[r];
#pragma unroll
        for (int off = 1; off < 16; off <<= 1)
          rs += __shfl_xor(rs, off);
        lst[r] = lst[r] * alpha[r] + rs;
      }
#pragma unroll
      for (int r = 0; r < 4; r++) {            // P: C-layout -> row-major LDS
        const int row = wave * 16 + quad * 4 + r;
        *(u16*)(smP + row * 80 + l16 * 2)      = f2b(p0[r]);
        *(u16*)(smP + row * 80 + 32 + l16 * 2) = f2b(p1[r]);
      }
#pragma unroll
      for (int nt = 0; nt < 8; nt++)           // rescale O (lane-local alpha)
#pragma unroll
        for (int r = 0; r < 4; r++) acc[nt][r] *= alpha[r];
    }
    // ---- fence: u16 P-stores ordered before bf16x8 P-loads ----
    __syncthreads();
    // ---- O += P V ----
    {
      bf16x8 ap = *(const bf16x8*)(smP + (wave * 16 + l16) * 80 + quad * 16);
#pragma unroll
      for (int nt = 0; nt < 8; nt++) {
        bf16x8 bv = *(const bf16x8*)(smV + (nt * 16 + l16) * 80 + quad * 16);
        acc[nt] = MFMA16(ap, bv, acc[nt]);
      }
    }
  }
  // ---- adapter attention (10 prefix keys, separate softmax) ----
  __syncthreads();                             // all PV reads done; lK/lV/lP dead
  float* lAk = (float*)smK;                    // overlay [16384,26624) over lK+lV
  float* lAv = lAk + AL_ * HS_;
  {
    const float* aks = akbuf + (size_t)h * AL_ * HS_;
    const float* avs = avbuf + (size_t)h * AL_ * HS_;
    for (int i = tid; i < AL_ * HS_; i += 256) { lAk[i] = aks[i]; lAv[i] = avs[i]; }
  }
  __syncthreads();
  const int ar = tid >> 2, ah = tid & 3;       // 4 threads per q-row, 32 cols each
  const int asw = (ar & 7) << 4;
  float sa[AL_];
#pragma unroll
  for (int l = 0; l < AL_; l++) sa[l] = 0.f;
#pragma unroll
  for (int c = 0; c < 4; c++) {                // own quarter of d, b128 reads
    const int col = ah * 32 + c * 8;
    union { uint4 v; u16 e[8]; } qv;
    qv.v = *(const uint4*)(smQ + ar * 256 + ((col * 2) ^ asw));
#pragma unroll
    for (int j = 0; j < 8; j++) {
      const float qf = b2f(qv.e[j]);
#pragma unroll
      for (int l = 0; l < AL_; l++) sa[l] += qf * lAk[l * HS_ + col + j];
    }
  }
#pragma unroll
  for (int l = 0; l < AL_; l++) {
    sa[l] += __shfl_xor(sa[l], 1);
    sa[l] += __shfl_xor(sa[l], 2);
    sa[l] *= scale;
  }
  float smax = sa[0];
#pragma unroll
  for (int l = 1; l < AL_; l++) smax = fmaxf(smax, sa[l]);
  float ssum = 0.f;
#pragma unroll
  for (int l = 0; l < AL_; l++) { sa[l] = __expf(sa[l] - smax); ssum += sa[l]; }
  const float inv = 1.f / ssum;
#pragma unroll
  for (int l = 0; l < AL_; l++) sa[l] *= inv;
  __syncthreads();                             // all lQ reads done -> overlay lAy
  u16* lAy = (u16*)smem;                       // 64 x 128 u16, linear (16 KiB)
#pragma unroll
  for (int c = 0; c < 4; c++) {
    const int col = ah * 32 + c * 8;
    union { uint4 v; u16 e[8]; } ov;
#pragma unroll
    for (int j = 0; j < 8; j++) {
      float a = 0.f;
#pragma unroll
      for (int l = 0; l < AL_; l++) a += sa[l] * lAv[l * HS_ + col + j];
      ov.e[j] = f2b(a);
    }
    *(uint4*)(lAy + ar * HS_ + col) = ov.v;
  }
  __syncthreads();
  // ---- epilogue: y = O/l + g*ay, written over qkv q-part (block's own patch)
  const float g = rb(gating[h]);
#pragma unroll
  for (int r = 0; r < 4; r++) {
    const int row = wave * 16 + quad * 4 + r;
    const float linv = 1.f / lst[r];
    u16* yrow = Qg + (size_t)row * C3_ + l16;
#pragma unroll
    for (int nt = 0; nt < 8; nt++) {
      const float v = acc[nt][r] * linv + g * b2f(lAy[row * HS_ + nt * 16 + l16]);
      yrow[nt * 16] = f2b(v);
    }
  }
}

// ---------------------------------------------------------------------------
extern "C" void kernel_launch(void* const* d_in, const int* in_sizes, int n_in,
                              void* d_out, int out_size, void* d_ws, size_t ws_size,
                              hipStream_t stream) {
  (void)out_size;
  int ix = 0, irope = 1, iW = 3, iP = 4, iE = 5, iG = 6;
  for (int i = 0; i < n_in; i++) {
    switch (in_sizes[i]) {
      case 8388608:  ix = i;    break;   // x (2,2048,2048)
      case 262144:   irope = i; break;   // rope (2048,64,2)
      case 12582912: iW = i;    break;   // W_attn (6144,2048)
      case 20480:    iE = i;    break;   // adapter_emb (10,2048)
      case 16:       iG = i;    break;   // gating (1,16,1,1)
      case 4194304:  iP = i;    break;   // mask (idx 2) then W_proj (idx 4): last wins
      default: break;
    }
  }
  const float* x      = (const float*)d_in[ix];
  const float* rope   = (const float*)d_in[irope];
  const float* W_attn = (const float*)d_in[iW];
  const float* W_proj = (const float*)d_in[iP];
  const float* emb    = (const float*)d_in[iE];
  const float* gating = (const float*)d_in[iG];

  // Workspace layout (fast path, 96 MiB):
  //   [0,48M) qkv bf16 | [48,64M) xb | [64,88M) Wab | [88,96M) Wpb
  // d_out (32 MiB, dead until proj GEMM) hosts ak/av fp32 (160 KiB) + vt (16 MiB).
  u16*   qkv = (u16*)d_ws;
  float* akb = (float*)d_out;
  float* avb = akb + (size_t)H_ * AL_ * HS_;
  u16*   vtb = (u16*)(avb + (size_t)H_ * AL_ * HS_);

  const bool fast = ws_size >= (size_t)100663296;  // 96 MiB
  if (fast) {
    u16* xb  = qkv + (size_t)25165824;   // 48 MiB / 2
    u16* Wab = xb  + (size_t)8388608;
    u16* Wpb = Wab + (size_t)12582912;
    f32_to_bf16<<<dim3(4096), 256, 0, stream>>>(x, xb, 1048576);
    f32_to_bf16<<<dim3(6144), 256, 0, stream>>>(W_attn, Wab, 1572864);
    f32_to_bf16<<<dim3(2048), 256, 0, stream>>>(W_proj, Wpb, 524288);
    gemm_lds<false><<<dim3(48, 32), 256, 0, stream>>>(xb, Wab, qkv, 6144, 2048, 2048);
    adapter_pqkv<<<dim3(1024), 256, 0, stream>>>(emb, W_attn, akb, avb);
    rope_inplace<<<dim3(16384), 256, 0, stream>>>(qkv, rope);
    transpose_v<<<dim3(32, 16, 2), 256, 0, stream>>>(qkv, vtb);
    attn_flash<<<dim3(32, 16, 2), 256, 0, stream>>>(qkv, vtb, akb, avb, gating);
    gemm_lds<true><<<dim3(16, 32), 256, 0, stream>>>(qkv, Wpb, (float*)d_out, 2048, 2048, 6144);
  } else {
    gemm_nt<true, true, false><<<dim3(48, 32), 256, 0, stream>>>(
        x, W_attn, qkv, 6144, 2048, 2048);
    adapter_pqkv<<<dim3(1024), 256, 0, stream>>>(emb, W_attn, akb, avb);
    rope_inplace<<<dim3(16384), 256, 0, stream>>>(qkv, rope);
    transpose_v<<<dim3(32, 16, 2), 256, 0, stream>>>(qkv, vtb);
    attn_flash<<<dim3(32, 16, 2), 256, 0, stream>>>(qkv, vtb, akb, avb, gating);
    gemm_nt<false, true, true><<<dim3(16, 32), 256, 0, stream>>>(
        qkv, W_proj, (float*)d_out, 2048, 2048, 6144);
  }
}

// Round 6
// 567.262 us; speedup vs baseline: 1.2959x; 1.1103x over previous
//
#include <hip/hip_runtime.h>

typedef unsigned short u16;
typedef unsigned int u32;
typedef __bf16 bf16x8 __attribute__((ext_vector_type(8)));
typedef float f32x4 __attribute__((ext_vector_type(4)));

#define B_ 2
#define T_ 2048
#define C_ 2048
#define H_ 16
#define HS_ 128
#define AL_ 10
#define C3_ 6144
#define MASKV (-3.0e38f)   // finite "-inf": exp(MASKV - m) == 0
#define MFMA16(a, b, c) __builtin_amdgcn_mfma_f32_16x16x32_bf16(a, b, c, 0, 0, 0)

// async global->LDS DMA, 16B per lane. LDS dest = wave-uniform base + lane*16;
// global src is per-lane. size MUST be a literal (guide: Common-mistake #1).
#define GLDS16(g, l) __builtin_amdgcn_global_load_lds(                         \
    (const __attribute__((address_space(1))) u32*)(const void*)(g),            \
    (__attribute__((address_space(3))) u32*)(void*)(l), 16, 0, 0)

__device__ __forceinline__ float b2f(u16 v) {
  union { u32 u; float f; } x; x.u = ((u32)v) << 16; return x.f;
}
__device__ __forceinline__ u16 f2b(float f) {
  u32 u = __builtin_bit_cast(u32, f);
  return (u16)((u + 0x7FFFu + ((u >> 16) & 1u)) >> 16);  // RNE
}
// fp32 -> bf16 -> fp32 (match the np ref's bf16-cast of fp32 inputs)
__device__ __forceinline__ float rb(float f) { return b2f(f2b(f)); }

// ---------------------------------------------------------------------------
// f32 -> bf16 bulk convert, 8 elem/thread (16B out per lane).
// ---------------------------------------------------------------------------
__global__ __launch_bounds__(256) void f32_to_bf16(
    const float* __restrict__ in, u16* __restrict__ out, int n8)
{
  const int i = blockIdx.x * 256 + threadIdx.x;
  if (i >= n8) return;
  union { float4 v[2]; float s[8]; } f;
  f.v[0] = *(const float4*)(in + (size_t)i * 8);
  f.v[1] = *(const float4*)(in + (size_t)i * 8 + 4);
  union { uint4 v; u16 e[8]; } o;
#pragma unroll
  for (int j = 0; j < 8; j++) o.e[j] = f2b(f.s[j]);
  *(uint4*)(out + (size_t)i * 8) = o.v;
}

// ---------------------------------------------------------------------------
// Fast GEMM (m97 structure): C(MxN) = A(MxK) * B(NxK)^T, both bf16, fp32
// accum. 128x128 tile, BK=32, 4 waves x 64x64 quadrant, global_load_lds
// width-16 staging, 2 barriers/iter, bijective XCD swizzle. (unchanged)
// ---------------------------------------------------------------------------
template <bool OUTF32>
__global__ __launch_bounds__(256) void gemm_lds(
    const u16* __restrict__ Ap, const u16* __restrict__ Bp,
    void* __restrict__ Cp, int N, int K, int lda)
{
  __shared__ u16 lA[128 * 32];
  __shared__ u16 lB[128 * 32];
  const int tid  = threadIdx.x;
  const int lane = tid & 63, wave = tid >> 6;
  const int quad = lane >> 4, l16 = lane & 15;
  const int nwg = gridDim.x * gridDim.y;
  int bid = blockIdx.y * gridDim.x + blockIdx.x;
  bid = (bid & 7) * (nwg >> 3) + (bid >> 3);
  const int bm = (bid / gridDim.x) * 128, bn = (bid % gridDim.x) * 128;
  const int wm = (wave >> 1) * 64, wn = (wave & 1) * 64;

  // staging map: LDS byte = wave*1024 + j*4096 + lane*16
  const int r0 = wave * 16 + (lane >> 2);
  const int c0 = (lane & 3) * 8;
  const u16* ga0 = Ap + (size_t)(bm + r0) * lda + c0;
  const u16* ga1 = ga0 + (size_t)64 * lda;
  const u16* gb0 = Bp + (size_t)(bn + r0) * K + c0;
  const u16* gb1 = gb0 + (size_t)64 * K;
  u16* la0 = &lA[wave * 512];
  u16* lb0 = &lB[wave * 512];

  f32x4 acc[4][4] = {};
  for (int k0 = 0; k0 < K; k0 += 32) {
    __syncthreads();                       // prior-iter LDS reads done
    GLDS16(ga0, la0);
    GLDS16(ga1, la0 + 2048);
    GLDS16(gb0, lb0);
    GLDS16(gb1, lb0 + 2048);
    ga0 += 32; ga1 += 32; gb0 += 32; gb1 += 32;
    __syncthreads();                       // DMA landed
    bf16x8 af[4], bfv[4];
#pragma unroll
    for (int i = 0; i < 4; i++)
      af[i] = *(const bf16x8*)&lA[(wm + i * 16 + l16) * 32 + quad * 8];
#pragma unroll
    for (int i = 0; i < 4; i++)
      bfv[i] = *(const bf16x8*)&lB[(wn + i * 16 + l16) * 32 + quad * 8];
#pragma unroll
    for (int i = 0; i < 4; i++)
#pragma unroll
      for (int j = 0; j < 4; j++)
        acc[i][j] = MFMA16(af[i], bfv[j], acc[i][j]);
  }
  // C/D layout: col = lane&15, row = quad*4 + reg  [m89/m91 verified]
#pragma unroll
  for (int i = 0; i < 4; i++) {
#pragma unroll
    for (int r = 0; r < 4; r++) {
      const int row = bm + wm + i * 16 + quad * 4 + r;
      if constexpr (OUTF32) {
        float* crow = (float*)Cp + (size_t)row * N + bn + wn + l16;
#pragma unroll
        for (int j = 0; j < 4; j++)
          crow[j * 16] = acc[i][j][r];
      } else {
        u16* crow = (u16*)Cp + (size_t)row * N + bn + wn + l16;
#pragma unroll
        for (int j = 0; j < 4; j++)
          crow[j * 16] = f2b(acc[i][j][r]);
      }
    }
  }
}

// ---------------------------------------------------------------------------
// Fallback GEMM (used only if ws_size can't host bf16 copies).
// ---------------------------------------------------------------------------
template <bool AF32, bool BF32, bool OUTF32>
__global__ __launch_bounds__(256) void gemm_nt(
    const void* __restrict__ Ap, const void* __restrict__ Bp,
    void* __restrict__ Cp, int N, int K, int lda)
{
  __shared__ u16 lA[128 * 32];
  __shared__ u16 lB[128 * 32];
  const int tid  = threadIdx.x;
  const int lane = tid & 63, wave = tid >> 6;
  const int quad = lane >> 4, l16 = lane & 15;
  const int bm = blockIdx.y * 128, bn = blockIdx.x * 128;
  const int wm = (wave >> 1) * 64, wn = (wave & 1) * 64;
  const int srow = tid >> 1, scol = (tid & 1) * 16;
  f32x4 acc[4][4] = {};

  for (int k0 = 0; k0 < K; k0 += 32) {
    __align__(16) u16 abuf[16], bbuf[16];
    if constexpr (AF32) {
      const float* gA = (const float*)Ap + (size_t)(bm + srow) * lda + scol + k0;
      union { float4 v[4]; float s[16]; } fa;
#pragma unroll
      for (int j = 0; j < 4; j++) fa.v[j] = *(const float4*)(gA + j * 4);
#pragma unroll
      for (int j = 0; j < 16; j++) abuf[j] = f2b(fa.s[j]);
    } else {
      const u16* gA = (const u16*)Ap + (size_t)(bm + srow) * lda + scol + k0;
      *(uint4*)&abuf[0] = *(const uint4*)(gA);
      *(uint4*)&abuf[8] = *(const uint4*)(gA + 8);
    }
    if constexpr (BF32) {
      const float* gB = (const float*)Bp + (size_t)(bn + srow) * K + scol + k0;
      union { float4 v[4]; float s[16]; } fb;
#pragma unroll
      for (int j = 0; j < 4; j++) fb.v[j] = *(const float4*)(gB + j * 4);
#pragma unroll
      for (int j = 0; j < 16; j++) bbuf[j] = f2b(fb.s[j]);
    } else {
      const u16* gB = (const u16*)Bp + (size_t)(bn + srow) * K + scol + k0;
      *(uint4*)&bbuf[0] = *(const uint4*)(gB);
      *(uint4*)&bbuf[8] = *(const uint4*)(gB + 8);
    }
    __syncthreads();
    *(uint4*)&lA[srow * 32 + scol]     = *(uint4*)&abuf[0];
    *(uint4*)&lA[srow * 32 + scol + 8] = *(uint4*)&abuf[8];
    *(uint4*)&lB[srow * 32 + scol]     = *(uint4*)&bbuf[0];
    *(uint4*)&lB[srow * 32 + scol + 8] = *(uint4*)&bbuf[8];
    __syncthreads();
    bf16x8 af[4], bfv[4];
#pragma unroll
    for (int i = 0; i < 4; i++)
      af[i] = *(const bf16x8*)&lA[(wm + i * 16 + l16) * 32 + quad * 8];
#pragma unroll
    for (int i = 0; i < 4; i++)
      bfv[i] = *(const bf16x8*)&lB[(wn + i * 16 + l16) * 32 + quad * 8];
#pragma unroll
    for (int i = 0; i < 4; i++)
#pragma unroll
      for (int j = 0; j < 4; j++)
        acc[i][j] = MFMA16(af[i], bfv[j], acc[i][j]);
  }
#pragma unroll
  for (int i = 0; i < 4; i++) {
#pragma unroll
    for (int r = 0; r < 4; r++) {
      const int row = bm + wm + i * 16 + quad * 4 + r;
      if constexpr (OUTF32) {
        float* crow = (float*)Cp + (size_t)row * N + bn + wn + l16;
#pragma unroll
        for (int j = 0; j < 4; j++)
          crow[j * 16] = acc[i][j][r];
      } else {
        u16* crow = (u16*)Cp + (size_t)row * N + bn + wn + l16;
#pragma unroll
        for (int j = 0; j < 4; j++)
          crow[j * 16] = f2b(acc[i][j][r]);
      }
    }
  }
}

// ---------------------------------------------------------------------------
// Adapter pqkv: ak/av[h][l][d] = bf16(adapter_emb[l]) . bf16(W_attn[...]).
// ---------------------------------------------------------------------------
__global__ __launch_bounds__(256) void adapter_pqkv(
    const float* __restrict__ emb, const float* __restrict__ W,
    float* __restrict__ akb, float* __restrict__ avb)
{
  const int tid = threadIdx.x;
  const int lane = tid & 63;
  const int w = blockIdx.x * 4 + (tid >> 6);      // 0..4095
  const int part = w >> 11;                        // 0 = k, 1 = v
  const int col = w & 2047;                        // h*128 + d
  const float* wrow = W + (size_t)(C_ + part * C_ + col) * C_;
  float acc[AL_];
#pragma unroll
  for (int l = 0; l < AL_; l++) acc[l] = 0.f;
  for (int i = 0; i < 32; i++) {
    const int c = i * 64 + lane;
    const float wv = rb(wrow[c]);
#pragma unroll
    for (int l = 0; l < AL_; l++) acc[l] += wv * rb(emb[l * C_ + c]);
  }
#pragma unroll
  for (int l = 0; l < AL_; l++) {
    for (int off = 32; off > 0; off >>= 1) acc[l] += __shfl_xor(acc[l], off);
  }
  if (lane == 0) {
    const int h = col >> 7, d = col & 127;
    float* dst = (part == 0 ? akb : avb) + (size_t)h * AL_ * HS_ + d;
#pragma unroll
    for (int l = 0; l < AL_; l++) dst[l * HS_] = acc[l];
  }
}

// ---------------------------------------------------------------------------
// RoPE in-place on qkv's q and k parts (qkv is bf16). rope table is FP32.
// ---------------------------------------------------------------------------
__global__ __launch_bounds__(256) void rope_inplace(
    u16* __restrict__ qkv, const float* __restrict__ rope)
{
  const int g = blockIdx.x * 256 + threadIdx.x;
  const int j2 = g & 63;
  const int h  = (g >> 6) & 15;
  const int t  = (g >> 10) & 2047;
  const int b  = g >> 21;
  u16* src = qkv + (size_t)(b * T_ + t) * C3_ + h * HS_ + j2 * 2;
  const u32 qp = *(const u32*)(src);
  const u32 kp = *(const u32*)(src + C_);
  const float2 rp = *(const float2*)(rope + (t * 64 + j2) * 2);
  const float c = rb(rp.x), s = rb(rp.y);
  const float q0 = b2f((u16)qp), q1 = b2f((u16)(qp >> 16));
  const float k0 = b2f((u16)kp), k1 = b2f((u16)(kp >> 16));
  const float qr0 = q0 * c - q1 * s, qr1 = q1 * c + q0 * s;
  const float kr0 = k0 * c - k1 * s, kr1 = k1 * c + k0 * s;
  *(u32*)(src)      = (u32)f2b(qr0) | ((u32)f2b(qr1) << 16);
  *(u32*)(src + C_) = (u32)f2b(kr0) | ((u32)f2b(kr1) << 16);
}

// ---------------------------------------------------------------------------
// V transpose: vt[b][h][d][t] = qkv v-part (bf16).
// ---------------------------------------------------------------------------
__global__ __launch_bounds__(256) void transpose_v(
    const u16* __restrict__ qkv, u16* __restrict__ vt)
{
  __shared__ __align__(16) char lT[64 * 256];
  const int tid = threadIdx.x;
  const int t0 = blockIdx.x * 64, h = blockIdx.y, b = blockIdx.z;
  const u16* Vg = qkv + (size_t)(b * T_ + t0) * C3_ + 2 * C_ + h * HS_;
#pragma unroll
  for (int i = 0; i < 4; i++) {
    const int e = (i * 256 + tid) * 8;      // u16 linear index in 64x128
    const int t = e >> 7, c = e & 127;
    *(uint4*)(lT + t * 256 + ((c * 2) ^ ((t & 7) << 4))) =
        *(const uint4*)(Vg + (size_t)t * C3_ + c);
  }
  __syncthreads();
  const int d = tid >> 1, half = tid & 1;
  __align__(16) u16 out[32];
#pragma unroll
  for (int tt = 0; tt < 32; tt++) {
    const int t = half * 32 + tt;
    out[tt] = *(const u16*)(lT + t * 256 + ((d * 2) ^ ((t & 7) << 4)));
  }
  u16* dst = vt + ((size_t)(b * H_ + h) * HS_ + d) * T_ + t0 + half * 32;
  *(uint4*)(dst)      = *(const uint4*)&out[0];
  *(uint4*)(dst + 8)  = *(const uint4*)&out[8];
  *(uint4*)(dst + 16) = *(const uint4*)&out[16];
  *(uint4*)(dst + 24) = *(const uint4*)&out[24];
}

// ---------------------------------------------------------------------------
// Flash attention + gated adapter attention.
// R5 verified: QBLK=64, 4 blocks/CU, 3-barrier loop. This round's single
// variable: SWAPPED QK^T -- compute mfma(K, Q) so D[k=quad*4+r][q=l16]:
// all 8 scores in a lane belong to ONE q-row. Row-reduce becomes a lane-
// local tree + 2 shuffles (xor16, xor32) instead of 4-deep butterflies per
// row: 32 -> 8 DS shuffle ops per iteration, chain depth halved. m/l are
// per-lane scalars (q = l16); alpha broadcast to the PV layout (q =
// quad*4+r) with 4 independent shuffles; P stored as packed u32 (2-way
// bank aliasing = free, m136). MFMA count, masks, numerics unchanged.
// y written IN-PLACE over qkv q-part (block-private patch).
// ---------------------------------------------------------------------------
__global__ __launch_bounds__(256, 4) void attn_flash(
    u16* __restrict__ qkv, const u16* __restrict__ vt,
    const float* __restrict__ akbuf, const float* __restrict__ avbuf,
    const float* __restrict__ gating)
{
  __shared__ __align__(16) char smem[39936];
  char* smQ = smem;                    // [0,16384)   64 rows x 256B swizzled
  char* smK = smem + 16384;            // [16384,24576)  32 rows x 256B swizzled
  char* smV = smem + 24576;            // [24576,34816)  Vt: 128 d-rows x 80B
  char* smP = smem + 34816;            // [34816,39936)  P: 64 rows x 80B

  const int tid  = threadIdx.x;
  const int lane = tid & 63, wave = tid >> 6;
  const int quad = lane >> 4, l16 = lane & 15;
  const int qt = 31 - (int)blockIdx.x, h = blockIdx.y, b = blockIdx.z;
  u16* Qg = qkv + ((size_t)(b * T_) + qt * 64) * C3_ + h * HS_;           // q-part
  const u16* Kg = qkv + (size_t)(b * T_) * C3_ + C_ + h * HS_;            // k-part
  const u16* Vt = vt + (size_t)(b * H_ + h) * HS_ * T_;
  const float scale = 0.08838834764831845f;   // 1/sqrt(128)

#pragma unroll
  for (int i = 0; i < 4; i++) {                // Q tile (64 rows), swizzled
    const int e = (i * 256 + tid) * 8;
    const int row = e >> 7, col = e & 127;
    *(uint4*)(smQ + row * 256 + ((col * 2) ^ ((row & 7) << 4))) =
        *(const uint4*)(Qg + (size_t)row * C3_ + col);
  }
  f32x4 acc[8] = {};
  float mrun = MASKV, lrun = 0.f;              // stats for q-row = wave*16+l16

  const int nkt = (qt + 1) * 2;
  const int qg = qt * 64 + wave * 16 + l16;    // this lane's q-row (score side)
  const int krow = tid >> 3, kcolb = (tid & 7) * 32;   // K staging (byte col)
  const int ksw = (krow & 7) << 4;
  for (int kt = 0; kt < nkt; kt++) {
    __syncthreads();                           // prior-iter lK/lV/lP reads done
    {
      const u16* ks = Kg + (size_t)(kt * 32 + krow) * C3_ + (kcolb >> 1);
      char* kb = smK + krow * 256;
      *(uint4*)(kb + ((kcolb)      ^ ksw)) = *(const uint4*)(ks);
      *(uint4*)(kb + ((kcolb + 16) ^ ksw)) = *(const uint4*)(ks + 8);
      // Vt tile: 128 d-rows x 32 keys, coalesced 64B-per-4-lanes reads
#pragma unroll
      for (int it = 0; it < 2; it++) {
        const int d = it * 64 + (tid >> 2), c = tid & 3;
        *(uint4*)(smV + d * 80 + c * 16) =
            *(const uint4*)(Vt + (size_t)d * T_ + kt * 32 + c * 8);
      }
    }
    __syncthreads();
    // ---- S^T = K Q^T: D[k = n*16 + quad*4 + r][q = l16] ----
    f32x4 sacc[2] = {};
    const int sw = (l16 & 7) << 4;
#pragma unroll
    for (int kk = 0; kk < 4; kk++) {
      const int co = (kk * 64 + quad * 16) ^ sw;
      bf16x8 aq  = *(const bf16x8*)(smQ + (wave * 16 + l16) * 256 + co);
      bf16x8 bk0 = *(const bf16x8*)(smK + l16 * 256 + co);
      bf16x8 bk1 = *(const bf16x8*)(smK + (16 + l16) * 256 + co);
      sacc[0] = MFMA16(bk0, aq, sacc[0]);      // rows = keys 0..15
      sacc[1] = MFMA16(bk1, aq, sacc[1]);      // rows = keys 16..31
    }
    // ---- online softmax: whole row in-lane; tree + 2 shuffles ----
    float s[8];
#pragma unroll
    for (int n = 0; n < 2; n++)
#pragma unroll
      for (int r = 0; r < 4; r++) {
        float v = sacc[n][r] * scale;
        if (kt * 32 + n * 16 + quad * 4 + r > qg) v = MASKV;
        s[n * 4 + r] = v;
      }
    float rmax = fmaxf(fmaxf(fmaxf(s[0], s[1]), fmaxf(s[2], s[3])),
                       fmaxf(fmaxf(s[4], s[5]), fmaxf(s[6], s[7])));
    rmax = fmaxf(rmax, __shfl_xor(rmax, 16));
    rmax = fmaxf(rmax, __shfl_xor(rmax, 32));
    const float mnew = fmaxf(mrun, rmax);
    const float alpha = __expf(mrun - mnew);
    mrun = mnew;
    float p[8];
#pragma unroll
    for (int i = 0; i < 8; i++) p[i] = __expf(s[i] - mnew);
    float rs = ((p[0] + p[1]) + (p[2] + p[3])) + ((p[4] + p[5]) + (p[6] + p[7]));
    rs += __shfl_xor(rs, 16);
    rs += __shfl_xor(rs, 32);
    lrun = lrun * alpha + rs;
    // alpha in PV layout (q = quad*4 + r): 4 independent broadcasts
    float alr[4];
#pragma unroll
    for (int r = 0; r < 4; r++) alr[r] = __shfl(alpha, quad * 4 + r);
    // ---- P store: row = q (wave*16+l16), packed u32 pairs over k ----
    {
      char* prow = smP + (wave * 16 + l16) * 80;
#pragma unroll
      for (int n = 0; n < 2; n++)
#pragma unroll
        for (int rp = 0; rp < 2; rp++) {
          const u32 w = (u32)f2b(p[n * 4 + rp * 2]) |
                        ((u32)f2b(p[n * 4 + rp * 2 + 1]) << 16);
          *(u32*)(prow + (n * 16 + quad * 4 + rp * 2) * 2) = w;
        }
    }
    // ---- rescale O (acc row q = wave*16 + quad*4 + r) ----
#pragma unroll
    for (int nt = 0; nt < 8; nt++)
#pragma unroll
      for (int r = 0; r < 4; r++) acc[nt][r] *= alr[r];
    // ---- fence: P-stores ordered before P-loads ----
    __syncthreads();
    // ---- O += P V ----
    {
      bf16x8 ap = *(const bf16x8*)(smP + (wave * 16 + l16) * 80 + quad * 16);
#pragma unroll
      for (int nt = 0; nt < 8; nt++) {
        bf16x8 bv = *(const bf16x8*)(smV + (nt * 16 + l16) * 80 + quad * 16);
        acc[nt] = MFMA16(ap, bv, acc[nt]);
      }
    }
  }
  // lrun lives in q=l16 layout; epilogue needs q=quad*4+r: broadcast once
  float lr[4];
#pragma unroll
  for (int r = 0; r < 4; r++) lr[r] = __shfl(lrun, quad * 4 + r);
  // ---- adapter attention (10 prefix keys, separate softmax) ----
  __syncthreads();                             // all PV reads done; lK/lV/lP dead
  float* lAk = (float*)smK;                    // overlay [16384,26624) over lK+lV
  float* lAv = lAk + AL_ * HS_;
  {
    const float* aks = akbuf + (size_t)h * AL_ * HS_;
    const float* avs = avbuf + (size_t)h * AL_ * HS_;
    for (int i = tid; i < AL_ * HS_; i += 256) { lAk[i] = aks[i]; lAv[i] = avs[i]; }
  }
  __syncthreads();
  const int ar = tid >> 2, ah = tid & 3;       // 4 threads per q-row, 32 cols each
  const int asw = (ar & 7) << 4;
  float sa[AL_];
#pragma unroll
  for (int l = 0; l < AL_; l++) sa[l] = 0.f;
#pragma unroll
  for (int c = 0; c < 4; c++) {                // own quarter of d, b128 reads
    const int col = ah * 32 + c * 8;
    union { uint4 v; u16 e[8]; } qv;
    qv.v = *(const uint4*)(smQ + ar * 256 + ((col * 2) ^ asw));
#pragma unroll
    for (int j = 0; j < 8; j++) {
      const float qf = b2f(qv.e[j]);
#pragma unroll
      for (int l = 0; l < AL_; l++) sa[l] += qf * lAk[l * HS_ + col + j];
    }
  }
#pragma unroll
  for (int l = 0; l < AL_; l++) {
    sa[l] += __shfl_xor(sa[l], 1);
    sa[l] += __shfl_xor(sa[l], 2);
    sa[l] *= scale;
  }
  float smax = sa[0];
#pragma unroll
  for (int l = 1; l < AL_; l++) smax = fmaxf(smax, sa[l]);
  float ssum = 0.f;
#pragma unroll
  for (int l = 0; l < AL_; l++) { sa[l] = __expf(sa[l] - smax); ssum += sa[l]; }
  const float inv = 1.f / ssum;
#pragma unroll
  for (int l = 0; l < AL_; l++) sa[l] *= inv;
  __syncthreads();                             // all lQ reads done -> overlay lAy
  u16* lAy = (u16*)smem;                       // 64 x 128 u16, linear (16 KiB)
#pragma unroll
  for (int c = 0; c < 4; c++) {
    const int col = ah * 32 + c * 8;
    union { uint4 v; u16 e[8]; } ov;
#pragma unroll
    for (int j = 0; j < 8; j++) {
      float a = 0.f;
#pragma unroll
      for (int l = 0; l < AL_; l++) a += sa[l] * lAv[l * HS_ + col + j];
      ov.e[j] = f2b(a);
    }
    *(uint4*)(lAy + ar * HS_ + col) = ov.v;
  }
  __syncthreads();
  // ---- epilogue: y = O/l + g*ay, written over qkv q-part (block's own patch)
  const float g = rb(gating[h]);
#pragma unroll
  for (int r = 0; r < 4; r++) {
    const int row = wave * 16 + quad * 4 + r;
    const float linv = 1.f / lr[r];
    u16* yrow = Qg + (size_t)row * C3_ + l16;
#pragma unroll
    for (int nt = 0; nt < 8; nt++) {
      const float v = acc[nt][r] * linv + g * b2f(lAy[row * HS_ + nt * 16 + l16]);
      yrow[nt * 16] = f2b(v);
    }
  }
}

// ---------------------------------------------------------------------------
extern "C" void kernel_launch(void* const* d_in, const int* in_sizes, int n_in,
                              void* d_out, int out_size, void* d_ws, size_t ws_size,
                              hipStream_t stream) {
  (void)out_size;
  int ix = 0, irope = 1, iW = 3, iP = 4, iE = 5, iG = 6;
  for (int i = 0; i < n_in; i++) {
    switch (in_sizes[i]) {
      case 8388608:  ix = i;    break;   // x (2,2048,2048)
      case 262144:   irope = i; break;   // rope (2048,64,2)
      case 12582912: iW = i;    break;   // W_attn (6144,2048)
      case 20480:    iE = i;    break;   // adapter_emb (10,2048)
      case 16:       iG = i;    break;   // gating (1,16,1,1)
      case 4194304:  iP = i;    break;   // mask (idx 2) then W_proj (idx 4): last wins
      default: break;
    }
  }
  const float* x      = (const float*)d_in[ix];
  const float* rope   = (const float*)d_in[irope];
  const float* W_attn = (const float*)d_in[iW];
  const float* W_proj = (const float*)d_in[iP];
  const float* emb    = (const float*)d_in[iE];
  const float* gating = (const float*)d_in[iG];

  // Workspace layout (fast path, 96 MiB):
  //   [0,48M) qkv bf16 | [48,64M) xb | [64,88M) Wab | [88,96M) Wpb
  // d_out (32 MiB, dead until proj GEMM) hosts ak/av fp32 (160 KiB) + vt (16 MiB).
  u16*   qkv = (u16*)d_ws;
  float* akb = (float*)d_out;
  float* avb = akb + (size_t)H_ * AL_ * HS_;
  u16*   vtb = (u16*)(avb + (size_t)H_ * AL_ * HS_);

  const bool fast = ws_size >= (size_t)100663296;  // 96 MiB
  if (fast) {
    u16* xb  = qkv + (size_t)25165824;   // 48 MiB / 2
    u16* Wab = xb  + (size_t)8388608;
    u16* Wpb = Wab + (size_t)12582912;
    f32_to_bf16<<<dim3(4096), 256, 0, stream>>>(x, xb, 1048576);
    f32_to_bf16<<<dim3(6144), 256, 0, stream>>>(W_attn, Wab, 1572864);
    f32_to_bf16<<<dim3(2048), 256, 0, stream>>>(W_proj, Wpb, 524288);
    gemm_lds<false><<<dim3(48, 32), 256, 0, stream>>>(xb, Wab, qkv, 6144, 2048, 2048);
    adapter_pqkv<<<dim3(1024), 256, 0, stream>>>(emb, W_attn, akb, avb);
    rope_inplace<<<dim3(16384), 256, 0, stream>>>(qkv, rope);
    transpose_v<<<dim3(32, 16, 2), 256, 0, stream>>>(qkv, vtb);
    attn_flash<<<dim3(32, 16, 2), 256, 0, stream>>>(qkv, vtb, akb, avb, gating);
    gemm_lds<true><<<dim3(16, 32), 256, 0, stream>>>(qkv, Wpb, (float*)d_out, 2048, 2048, 6144);
  } else {
    gemm_nt<true, true, false><<<dim3(48, 32), 256, 0, stream>>>(
        x, W_attn, qkv, 6144, 2048, 2048);
    adapter_pqkv<<<dim3(1024), 256, 0, stream>>>(emb, W_attn, akb, avb);
    rope_inplace<<<dim3(16384), 256, 0, stream>>>(qkv, rope);
    transpose_v<<<dim3(32, 16, 2), 256, 0, stream>>>(qkv, vtb);
    attn_flash<<<dim3(32, 16, 2), 256, 0, stream>>>(qkv, vtb, akb, avb, gating);
    gemm_nt<false, true, true><<<dim3(16, 32), 256, 0, stream>>>(
        qkv, W_proj, (float*)d_out, 2048, 2048, 6144);
  }
}

// Round 7
// 557.796 us; speedup vs baseline: 1.3179x; 1.0170x over previous
//
#include <hip/hip_runtime.h>

typedef unsigned short u16;
typedef unsigned int u32;
typedef __bf16 bf16x8 __attribute__((ext_vector_type(8)));
typedef float f32x4 __attribute__((ext_vector_type(4)));

#define B_ 2
#define T_ 2048
#define C_ 2048
#define H_ 16
#define HS_ 128
#define AL_ 10
#define C3_ 6144
#define MASKV (-3.0e38f)   // finite "-inf": exp(MASKV - m) == 0
#define MFMA16(a, b, c) __builtin_amdgcn_mfma_f32_16x16x32_bf16(a, b, c, 0, 0, 0)

// async global->LDS DMA, 16B per lane. LDS dest = wave-uniform base + lane*16;
// global src is per-lane. size MUST be a literal (guide: Common-mistake #1).
#define GLDS16(g, l) __builtin_amdgcn_global_load_lds(                         \
    (const __attribute__((address_space(1))) u32*)(const void*)(g),            \
    (__attribute__((address_space(3))) u32*)(void*)(l), 16, 0, 0)

__device__ __forceinline__ float b2f(u16 v) {
  union { u32 u; float f; } x; x.u = ((u32)v) << 16; return x.f;
}
__device__ __forceinline__ u16 f2b(float f) {
  u32 u = __builtin_bit_cast(u32, f);
  return (u16)((u + 0x7FFFu + ((u >> 16) & 1u)) >> 16);  // RNE
}
// fp32 -> bf16 -> fp32 (match the np ref's bf16-cast of fp32 inputs)
__device__ __forceinline__ float rb(float f) { return b2f(f2b(f)); }

// ---------------------------------------------------------------------------
// Merged f32 -> bf16 bulk convert for x / W_attn / W_proj in ONE launch.
// 8 elem/thread; grid partitioned by linear index.
// ---------------------------------------------------------------------------
__global__ __launch_bounds__(256) void convert_all(
    const float* __restrict__ x,  u16* __restrict__ xb,
    const float* __restrict__ Wa, u16* __restrict__ Wab,
    const float* __restrict__ Wp, u16* __restrict__ Wpb)
{
  int i = blockIdx.x * 256 + threadIdx.x;        // 0 .. 3145727 (x8 elems)
  const float* in; u16* out;
  if (i < 1048576)      { in = x;  out = xb;  }
  else if (i < 2621440) { in = Wa; out = Wab; i -= 1048576; }
  else                  { in = Wp; out = Wpb; i -= 2621440; }
  union { float4 v[2]; float s[8]; } f;
  f.v[0] = *(const float4*)(in + (size_t)i * 8);
  f.v[1] = *(const float4*)(in + (size_t)i * 8 + 4);
  union { uint4 v; u16 e[8]; } o;
#pragma unroll
  for (int j = 0; j < 8; j++) o.e[j] = f2b(f.s[j]);
  *(uint4*)(out + (size_t)i * 8) = o.v;
}

// ---------------------------------------------------------------------------
// Fast GEMM (m97 structure): C(MxN) = A(MxK) * B(NxK)^T, both bf16, fp32
// accum. 128x128 tile, BK=32, 4 waves x 64x64 quadrant, global_load_lds
// width-16 staging, 2 barriers/iter, bijective XCD swizzle. (unchanged)
// ---------------------------------------------------------------------------
template <bool OUTF32>
__global__ __launch_bounds__(256) void gemm_lds(
    const u16* __restrict__ Ap, const u16* __restrict__ Bp,
    void* __restrict__ Cp, int N, int K, int lda)
{
  __shared__ u16 lA[128 * 32];
  __shared__ u16 lB[128 * 32];
  const int tid  = threadIdx.x;
  const int lane = tid & 63, wave = tid >> 6;
  const int quad = lane >> 4, l16 = lane & 15;
  const int nwg = gridDim.x * gridDim.y;
  int bid = blockIdx.y * gridDim.x + blockIdx.x;
  bid = (bid & 7) * (nwg >> 3) + (bid >> 3);
  const int bm = (bid / gridDim.x) * 128, bn = (bid % gridDim.x) * 128;
  const int wm = (wave >> 1) * 64, wn = (wave & 1) * 64;

  // staging map: LDS byte = wave*1024 + j*4096 + lane*16
  const int r0 = wave * 16 + (lane >> 2);
  const int c0 = (lane & 3) * 8;
  const u16* ga0 = Ap + (size_t)(bm + r0) * lda + c0;
  const u16* ga1 = ga0 + (size_t)64 * lda;
  const u16* gb0 = Bp + (size_t)(bn + r0) * K + c0;
  const u16* gb1 = gb0 + (size_t)64 * K;
  u16* la0 = &lA[wave * 512];
  u16* lb0 = &lB[wave * 512];

  f32x4 acc[4][4] = {};
  for (int k0 = 0; k0 < K; k0 += 32) {
    __syncthreads();                       // prior-iter LDS reads done
    GLDS16(ga0, la0);
    GLDS16(ga1, la0 + 2048);
    GLDS16(gb0, lb0);
    GLDS16(gb1, lb0 + 2048);
    ga0 += 32; ga1 += 32; gb0 += 32; gb1 += 32;
    __syncthreads();                       // DMA landed
    bf16x8 af[4], bfv[4];
#pragma unroll
    for (int i = 0; i < 4; i++)
      af[i] = *(const bf16x8*)&lA[(wm + i * 16 + l16) * 32 + quad * 8];
#pragma unroll
    for (int i = 0; i < 4; i++)
      bfv[i] = *(const bf16x8*)&lB[(wn + i * 16 + l16) * 32 + quad * 8];
#pragma unroll
    for (int i = 0; i < 4; i++)
#pragma unroll
      for (int j = 0; j < 4; j++)
        acc[i][j] = MFMA16(af[i], bfv[j], acc[i][j]);
  }
  // C/D layout: col = lane&15, row = quad*4 + reg  [m89/m91 verified]
#pragma unroll
  for (int i = 0; i < 4; i++) {
#pragma unroll
    for (int r = 0; r < 4; r++) {
      const int row = bm + wm + i * 16 + quad * 4 + r;
      if constexpr (OUTF32) {
        float* crow = (float*)Cp + (size_t)row * N + bn + wn + l16;
#pragma unroll
        for (int j = 0; j < 4; j++)
          crow[j * 16] = acc[i][j][r];
      } else {
        u16* crow = (u16*)Cp + (size_t)row * N + bn + wn + l16;
#pragma unroll
        for (int j = 0; j < 4; j++)
          crow[j * 16] = f2b(acc[i][j][r]);
      }
    }
  }
}

// ---------------------------------------------------------------------------
// Fallback GEMM (used only if ws_size can't host bf16 copies).
// ---------------------------------------------------------------------------
template <bool AF32, bool BF32, bool OUTF32>
__global__ __launch_bounds__(256) void gemm_nt(
    const void* __restrict__ Ap, const void* __restrict__ Bp,
    void* __restrict__ Cp, int N, int K, int lda)
{
  __shared__ u16 lA[128 * 32];
  __shared__ u16 lB[128 * 32];
  const int tid  = threadIdx.x;
  const int lane = tid & 63, wave = tid >> 6;
  const int quad = lane >> 4, l16 = lane & 15;
  const int bm = blockIdx.y * 128, bn = blockIdx.x * 128;
  const int wm = (wave >> 1) * 64, wn = (wave & 1) * 64;
  const int srow = tid >> 1, scol = (tid & 1) * 16;
  f32x4 acc[4][4] = {};

  for (int k0 = 0; k0 < K; k0 += 32) {
    __align__(16) u16 abuf[16], bbuf[16];
    if constexpr (AF32) {
      const float* gA = (const float*)Ap + (size_t)(bm + srow) * lda + scol + k0;
      union { float4 v[4]; float s[16]; } fa;
#pragma unroll
      for (int j = 0; j < 4; j++) fa.v[j] = *(const float4*)(gA + j * 4);
#pragma unroll
      for (int j = 0; j < 16; j++) abuf[j] = f2b(fa.s[j]);
    } else {
      const u16* gA = (const u16*)Ap + (size_t)(bm + srow) * lda + scol + k0;
      *(uint4*)&abuf[0] = *(const uint4*)(gA);
      *(uint4*)&abuf[8] = *(const uint4*)(gA + 8);
    }
    if constexpr (BF32) {
      const float* gB = (const float*)Bp + (size_t)(bn + srow) * K + scol + k0;
      union { float4 v[4]; float s[16]; } fb;
#pragma unroll
      for (int j = 0; j < 4; j++) fb.v[j] = *(const float4*)(gB + j * 4);
#pragma unroll
      for (int j = 0; j < 16; j++) bbuf[j] = f2b(fb.s[j]);
    } else {
      const u16* gB = (const u16*)Bp + (size_t)(bn + srow) * K + scol + k0;
      *(uint4*)&bbuf[0] = *(const uint4*)(gB);
      *(uint4*)&bbuf[8] = *(const uint4*)(gB + 8);
    }
    __syncthreads();
    *(uint4*)&lA[srow * 32 + scol]     = *(uint4*)&abuf[0];
    *(uint4*)&lA[srow * 32 + scol + 8] = *(uint4*)&abuf[8];
    *(uint4*)&lB[srow * 32 + scol]     = *(uint4*)&bbuf[0];
    *(uint4*)&lB[srow * 32 + scol + 8] = *(uint4*)&bbuf[8];
    __syncthreads();
    bf16x8 af[4], bfv[4];
#pragma unroll
    for (int i = 0; i < 4; i++)
      af[i] = *(const bf16x8*)&lA[(wm + i * 16 + l16) * 32 + quad * 8];
#pragma unroll
    for (int i = 0; i < 4; i++)
      bfv[i] = *(const bf16x8*)&lB[(wn + i * 16 + l16) * 32 + quad * 8];
#pragma unroll
    for (int i = 0; i < 4; i++)
#pragma unroll
      for (int j = 0; j < 4; j++)
        acc[i][j] = MFMA16(af[i], bfv[j], acc[i][j]);
  }
#pragma unroll
  for (int i = 0; i < 4; i++) {
#pragma unroll
    for (int r = 0; r < 4; r++) {
      const int row = bm + wm + i * 16 + quad * 4 + r;
      if constexpr (OUTF32) {
        float* crow = (float*)Cp + (size_t)row * N + bn + wn + l16;
#pragma unroll
        for (int j = 0; j < 4; j++)
          crow[j * 16] = acc[i][j][r];
      } else {
        u16* crow = (u16*)Cp + (size_t)row * N + bn + wn + l16;
#pragma unroll
        for (int j = 0; j < 4; j++)
          crow[j * 16] = f2b(acc[i][j][r]);
      }
    }
  }
}

// ---------------------------------------------------------------------------
// Adapter pqkv: ak/av[h][l][d] = bf16(adapter_emb[l]) . bf16(W_attn[...]).
// ---------------------------------------------------------------------------
__global__ __launch_bounds__(256) void adapter_pqkv(
    const float* __restrict__ emb, const float* __restrict__ W,
    float* __restrict__ akb, float* __restrict__ avb)
{
  const int tid = threadIdx.x;
  const int lane = tid & 63;
  const int w = blockIdx.x * 4 + (tid >> 6);      // 0..4095
  const int part = w >> 11;                        // 0 = k, 1 = v
  const int col = w & 2047;                        // h*128 + d
  const float* wrow = W + (size_t)(C_ + part * C_ + col) * C_;
  float acc[AL_];
#pragma unroll
  for (int l = 0; l < AL_; l++) acc[l] = 0.f;
  for (int i = 0; i < 32; i++) {
    const int c = i * 64 + lane;
    const float wv = rb(wrow[c]);
#pragma unroll
    for (int l = 0; l < AL_; l++) acc[l] += wv * rb(emb[l * C_ + c]);
  }
#pragma unroll
  for (int l = 0; l < AL_; l++) {
    for (int off = 32; off > 0; off >>= 1) acc[l] += __shfl_xor(acc[l], off);
  }
  if (lane == 0) {
    const int h = col >> 7, d = col & 127;
    float* dst = (part == 0 ? akb : avb) + (size_t)h * AL_ * HS_ + d;
#pragma unroll
    for (int l = 0; l < AL_; l++) dst[l * HS_] = acc[l];
  }
}

// ---------------------------------------------------------------------------
// Merged RoPE (blocks [0,16384)) + V transpose (blocks [16384,17408)).
// rope: in-place on qkv q/k parts. transpose: vt[b][h][d][t] = qkv v-part.
// One launch instead of two; bodies unchanged from their verified versions.
// ---------------------------------------------------------------------------
__global__ __launch_bounds__(256) void rope_tv(
    u16* __restrict__ qkv, const float* __restrict__ rope,
    u16* __restrict__ vt)
{
  __shared__ __align__(16) char lT[64 * 256];
  const int bid = blockIdx.x;
  if (bid < 16384) {                         // ---- rope path ----
    const int g = bid * 256 + threadIdx.x;
    const int j2 = g & 63;
    const int h  = (g >> 6) & 15;
    const int t  = (g >> 10) & 2047;
    const int b  = g >> 21;
    u16* src = qkv + (size_t)(b * T_ + t) * C3_ + h * HS_ + j2 * 2;
    const u32 qp = *(const u32*)(src);
    const u32 kp = *(const u32*)(src + C_);
    const float2 rp = *(const float2*)(rope + (t * 64 + j2) * 2);
    const float c = rb(rp.x), s = rb(rp.y);
    const float q0 = b2f((u16)qp), q1 = b2f((u16)(qp >> 16));
    const float k0 = b2f((u16)kp), k1 = b2f((u16)(kp >> 16));
    const float qr0 = q0 * c - q1 * s, qr1 = q1 * c + q0 * s;
    const float kr0 = k0 * c - k1 * s, kr1 = k1 * c + k0 * s;
    *(u32*)(src)      = (u32)f2b(qr0) | ((u32)f2b(qr1) << 16);
    *(u32*)(src + C_) = (u32)f2b(kr0) | ((u32)f2b(kr1) << 16);
    return;
  }
  // ---- transpose path (1024 blocks) ----
  const int r = bid - 16384;
  const int tid = threadIdx.x;
  const int t0 = (r & 31) * 64, h = (r >> 5) & 15, b = r >> 9;
  const u16* Vg = qkv + (size_t)(b * T_ + t0) * C3_ + 2 * C_ + h * HS_;
#pragma unroll
  for (int i = 0; i < 4; i++) {
    const int e = (i * 256 + tid) * 8;      // u16 linear index in 64x128
    const int t = e >> 7, c = e & 127;
    *(uint4*)(lT + t * 256 + ((c * 2) ^ ((t & 7) << 4))) =
        *(const uint4*)(Vg + (size_t)t * C3_ + c);
  }
  __syncthreads();
  const int d = tid >> 1, half = tid & 1;
  __align__(16) u16 out[32];
#pragma unroll
  for (int tt = 0; tt < 32; tt++) {
    const int t = half * 32 + tt;
    out[tt] = *(const u16*)(lT + t * 256 + ((d * 2) ^ ((t & 7) << 4)));
  }
  u16* dst = vt + ((size_t)(b * H_ + h) * HS_ + d) * T_ + t0 + half * 32;
  *(uint4*)(dst)      = *(const uint4*)&out[0];
  *(uint4*)(dst + 8)  = *(const uint4*)&out[8];
  *(uint4*)(dst + 16) = *(const uint4*)&out[16];
  *(uint4*)(dst + 24) = *(const uint4*)&out[24];
}

// ---------------------------------------------------------------------------
// Flash attention + gated adapter attention.
// R6 verified: QBLK=64, 4 blocks/CU, swapped QK^T in-register softmax.
// This round's single variable: the mid-loop P-fence __syncthreads is
// REMOVED. P is wave-private (written to rows [16*wave,16*wave+16) and read
// back from exactly those rows by the same wave); same-wave LDS write->read
// ordering needs only lgkmcnt, which the compiler inserts. Barriers 3 -> 2
// per kt. K/V protection barriers (loop-top + post-stage) unchanged.
// y written IN-PLACE over qkv q-part (block-private patch).
// ---------------------------------------------------------------------------
__global__ __launch_bounds__(256, 4) void attn_flash(
    u16* __restrict__ qkv, const u16* __restrict__ vt,
    const float* __restrict__ akbuf, const float* __restrict__ avbuf,
    const float* __restrict__ gating)
{
  __shared__ __align__(16) char smem[39936];
  char* smQ = smem;                    // [0,16384)   64 rows x 256B swizzled
  char* smK = smem + 16384;            // [16384,24576)  32 rows x 256B swizzled
  char* smV = smem + 24576;            // [24576,34816)  Vt: 128 d-rows x 80B
  char* smP = smem + 34816;            // [34816,39936)  P: 64 rows x 80B

  const int tid  = threadIdx.x;
  const int lane = tid & 63, wave = tid >> 6;
  const int quad = lane >> 4, l16 = lane & 15;
  const int qt = 31 - (int)blockIdx.x, h = blockIdx.y, b = blockIdx.z;
  u16* Qg = qkv + ((size_t)(b * T_) + qt * 64) * C3_ + h * HS_;           // q-part
  const u16* Kg = qkv + (size_t)(b * T_) * C3_ + C_ + h * HS_;            // k-part
  const u16* Vt = vt + (size_t)(b * H_ + h) * HS_ * T_;
  const float scale = 0.08838834764831845f;   // 1/sqrt(128)

#pragma unroll
  for (int i = 0; i < 4; i++) {                // Q tile (64 rows), swizzled
    const int e = (i * 256 + tid) * 8;
    const int row = e >> 7, col = e & 127;
    *(uint4*)(smQ + row * 256 + ((col * 2) ^ ((row & 7) << 4))) =
        *(const uint4*)(Qg + (size_t)row * C3_ + col);
  }
  f32x4 acc[8] = {};
  float mrun = MASKV, lrun = 0.f;              // stats for q-row = wave*16+l16

  const int nkt = (qt + 1) * 2;
  const int qg = qt * 64 + wave * 16 + l16;    // this lane's q-row (score side)
  const int krow = tid >> 3, kcolb = (tid & 7) * 32;   // K staging (byte col)
  const int ksw = (krow & 7) << 4;
  for (int kt = 0; kt < nkt; kt++) {
    __syncthreads();                           // prior-iter lK/lV reads done
    {
      const u16* ks = Kg + (size_t)(kt * 32 + krow) * C3_ + (kcolb >> 1);
      char* kb = smK + krow * 256;
      *(uint4*)(kb + ((kcolb)      ^ ksw)) = *(const uint4*)(ks);
      *(uint4*)(kb + ((kcolb + 16) ^ ksw)) = *(const uint4*)(ks + 8);
      // Vt tile: 128 d-rows x 32 keys, coalesced 64B-per-4-lanes reads
#pragma unroll
      for (int it = 0; it < 2; it++) {
        const int d = it * 64 + (tid >> 2), c = tid & 3;
        *(uint4*)(smV + d * 80 + c * 16) =
            *(const uint4*)(Vt + (size_t)d * T_ + kt * 32 + c * 8);
      }
    }
    __syncthreads();
    // ---- S^T = K Q^T: D[k = n*16 + quad*4 + r][q = l16] ----
    f32x4 sacc[2] = {};
    const int sw = (l16 & 7) << 4;
#pragma unroll
    for (int kk = 0; kk < 4; kk++) {
      const int co = (kk * 64 + quad * 16) ^ sw;
      bf16x8 aq  = *(const bf16x8*)(smQ + (wave * 16 + l16) * 256 + co);
      bf16x8 bk0 = *(const bf16x8*)(smK + l16 * 256 + co);
      bf16x8 bk1 = *(const bf16x8*)(smK + (16 + l16) * 256 + co);
      sacc[0] = MFMA16(bk0, aq, sacc[0]);      // rows = keys 0..15
      sacc[1] = MFMA16(bk1, aq, sacc[1]);      // rows = keys 16..31
    }
    // ---- online softmax: whole row in-lane; tree + 2 shuffles ----
    float s[8];
#pragma unroll
    for (int n = 0; n < 2; n++)
#pragma unroll
      for (int r = 0; r < 4; r++) {
        float v = sacc[n][r] * scale;
        if (kt * 32 + n * 16 + quad * 4 + r > qg) v = MASKV;
        s[n * 4 + r] = v;
      }
    float rmax = fmaxf(fmaxf(fmaxf(s[0], s[1]), fmaxf(s[2], s[3])),
                       fmaxf(fmaxf(s[4], s[5]), fmaxf(s[6], s[7])));
    rmax = fmaxf(rmax, __shfl_xor(rmax, 16));
    rmax = fmaxf(rmax, __shfl_xor(rmax, 32));
    const float mnew = fmaxf(mrun, rmax);
    const float alpha = __expf(mrun - mnew);
    mrun = mnew;
    float p[8];
#pragma unroll
    for (int i = 0; i < 8; i++) p[i] = __expf(s[i] - mnew);
    float rs = ((p[0] + p[1]) + (p[2] + p[3])) + ((p[4] + p[5]) + (p[6] + p[7]));
    rs += __shfl_xor(rs, 16);
    rs += __shfl_xor(rs, 32);
    lrun = lrun * alpha + rs;
    // alpha in PV layout (q = quad*4 + r): 4 independent broadcasts
    float alr[4];
#pragma unroll
    for (int r = 0; r < 4; r++) alr[r] = __shfl(alpha, quad * 4 + r);
    // ---- P store: row = q (wave*16+l16), packed u32 pairs over k ----
    // Wave-private region: no barrier needed before the PV read below.
    {
      char* prow = smP + (wave * 16 + l16) * 80;
#pragma unroll
      for (int n = 0; n < 2; n++)
#pragma unroll
        for (int rp = 0; rp < 2; rp++) {
          const u32 w = (u32)f2b(p[n * 4 + rp * 2]) |
                        ((u32)f2b(p[n * 4 + rp * 2 + 1]) << 16);
          *(u32*)(prow + (n * 16 + quad * 4 + rp * 2) * 2) = w;
        }
    }
    // ---- rescale O (acc row q = wave*16 + quad*4 + r) ----
#pragma unroll
    for (int nt = 0; nt < 8; nt++)
#pragma unroll
      for (int r = 0; r < 4; r++) acc[nt][r] *= alr[r];
    // ---- O += P V (P read is same-wave; lgkmcnt orders it) ----
    {
      bf16x8 ap = *(const bf16x8*)(smP + (wave * 16 + l16) * 80 + quad * 16);
#pragma unroll
      for (int nt = 0; nt < 8; nt++) {
        bf16x8 bv = *(const bf16x8*)(smV + (nt * 16 + l16) * 80 + quad * 16);
        acc[nt] = MFMA16(ap, bv, acc[nt]);
      }
    }
  }
  // lrun lives in q=l16 layout; epilogue needs q=quad*4+r: broadcast once
  float lr[4];
#pragma unroll
  for (int r = 0; r < 4; r++) lr[r] = __shfl(lrun, quad * 4 + r);
  // ---- adapter attention (10 prefix keys, separate softmax) ----
  __syncthreads();                             // all waves past PV; lK/lV/lP dead
  float* lAk = (float*)smK;                    // overlay [16384,26624) over lK+lV
  float* lAv = lAk + AL_ * HS_;
  {
    const float* aks = akbuf + (size_t)h * AL_ * HS_;
    const float* avs = avbuf + (size_t)h * AL_ * HS_;
    for (int i = tid; i < AL_ * HS_; i += 256) { lAk[i] = aks[i]; lAv[i] = avs[i]; }
  }
  __syncthreads();
  const int ar = tid >> 2, ah = tid & 3;       // 4 threads per q-row, 32 cols each
  const int asw = (ar & 7) << 4;
  float sa[AL_];
#pragma unroll
  for (int l = 0; l < AL_; l++) sa[l] = 0.f;
#pragma unroll
  for (int c = 0; c < 4; c++) {                // own quarter of d, b128 reads
    const int col = ah * 32 + c * 8;
    union { uint4 v; u16 e[8]; } qv;
    qv.v = *(const uint4*)(smQ + ar * 256 + ((col * 2) ^ asw));
#pragma unroll
    for (int j = 0; j < 8; j++) {
      const float qf = b2f(qv.e[j]);
#pragma unroll
      for (int l = 0; l < AL_; l++) sa[l] += qf * lAk[l * HS_ + col + j];
    }
  }
#pragma unroll
  for (int l = 0; l < AL_; l++) {
    sa[l] += __shfl_xor(sa[l], 1);
    sa[l] += __shfl_xor(sa[l], 2);
    sa[l] *= scale;
  }
  float smax = sa[0];
#pragma unroll
  for (int l = 1; l < AL_; l++) smax = fmaxf(smax, sa[l]);
  float ssum = 0.f;
#pragma unroll
  for (int l = 0; l < AL_; l++) { sa[l] = __expf(sa[l] - smax); ssum += sa[l]; }
  const float inv = 1.f / ssum;
#pragma unroll
  for (int l = 0; l < AL_; l++) sa[l] *= inv;
  __syncthreads();                             // all lQ reads done -> overlay lAy
  u16* lAy = (u16*)smem;                       // 64 x 128 u16, linear (16 KiB)
#pragma unroll
  for (int c = 0; c < 4; c++) {
    const int col = ah * 32 + c * 8;
    union { uint4 v; u16 e[8]; } ov;
#pragma unroll
    for (int j = 0; j < 8; j++) {
      float a = 0.f;
#pragma unroll
      for (int l = 0; l < AL_; l++) a += sa[l] * lAv[l * HS_ + col + j];
      ov.e[j] = f2b(a);
    }
    *(uint4*)(lAy + ar * HS_ + col) = ov.v;
  }
  __syncthreads();
  // ---- epilogue: y = O/l + g*ay, written over qkv q-part (block's own patch)
  const float g = rb(gating[h]);
#pragma unroll
  for (int r = 0; r < 4; r++) {
    const int row = wave * 16 + quad * 4 + r;
    const float linv = 1.f / lr[r];
    u16* yrow = Qg + (size_t)row * C3_ + l16;
#pragma unroll
    for (int nt = 0; nt < 8; nt++) {
      const float v = acc[nt][r] * linv + g * b2f(lAy[row * HS_ + nt * 16 + l16]);
      yrow[nt * 16] = f2b(v);
    }
  }
}

// ---------------------------------------------------------------------------
extern "C" void kernel_launch(void* const* d_in, const int* in_sizes, int n_in,
                              void* d_out, int out_size, void* d_ws, size_t ws_size,
                              hipStream_t stream) {
  (void)out_size;
  int ix = 0, irope = 1, iW = 3, iP = 4, iE = 5, iG = 6;
  for (int i = 0; i < n_in; i++) {
    switch (in_sizes[i]) {
      case 8388608:  ix = i;    break;   // x (2,2048,2048)
      case 262144:   irope = i; break;   // rope (2048,64,2)
      case 12582912: iW = i;    break;   // W_attn (6144,2048)
      case 20480:    iE = i;    break;   // adapter_emb (10,2048)
      case 16:       iG = i;    break;   // gating (1,16,1,1)
      case 4194304:  iP = i;    break;   // mask (idx 2) then W_proj (idx 4): last wins
      default: break;
    }
  }
  const float* x      = (const float*)d_in[ix];
  const float* rope   = (const float*)d_in[irope];
  const float* W_attn = (const float*)d_in[iW];
  const float* W_proj = (const float*)d_in[iP];
  const float* emb    = (const float*)d_in[iE];
  const float* gating = (const float*)d_in[iG];

  // Workspace layout (fast path, 96 MiB):
  //   [0,48M) qkv bf16 | [48,64M) xb | [64,88M) Wab | [88,96M) Wpb
  // d_out (32 MiB, dead until proj GEMM) hosts ak/av fp32 (160 KiB) + vt (16 MiB).
  u16*   qkv = (u16*)d_ws;
  float* akb = (float*)d_out;
  float* avb = akb + (size_t)H_ * AL_ * HS_;
  u16*   vtb = (u16*)(avb + (size_t)H_ * AL_ * HS_);

  const bool fast = ws_size >= (size_t)100663296;  // 96 MiB
  if (fast) {
    u16* xb  = qkv + (size_t)25165824;   // 48 MiB / 2
    u16* Wab = xb  + (size_t)8388608;
    u16* Wpb = Wab + (size_t)12582912;
    convert_all<<<dim3(12288), 256, 0, stream>>>(x, xb, W_attn, Wab, W_proj, Wpb);
    gemm_lds<false><<<dim3(48, 32), 256, 0, stream>>>(xb, Wab, qkv, 6144, 2048, 2048);
    adapter_pqkv<<<dim3(1024), 256, 0, stream>>>(emb, W_attn, akb, avb);
    rope_tv<<<dim3(17408), 256, 0, stream>>>(qkv, rope, vtb);
    attn_flash<<<dim3(32, 16, 2), 256, 0, stream>>>(qkv, vtb, akb, avb, gating);
    gemm_lds<true><<<dim3(16, 32), 256, 0, stream>>>(qkv, Wpb, (float*)d_out, 2048, 2048, 6144);
  } else {
    gemm_nt<true, true, false><<<dim3(48, 32), 256, 0, stream>>>(
        x, W_attn, qkv, 6144, 2048, 2048);
    adapter_pqkv<<<dim3(1024), 256, 0, stream>>>(emb, W_attn, akb, avb);
    rope_tv<<<dim3(17408), 256, 0, stream>>>(qkv, rope, vtb);
    attn_flash<<<dim3(32, 16, 2), 256, 0, stream>>>(qkv, vtb, akb, avb, gating);
    gemm_nt<false, true, true><<<dim3(16, 32), 256, 0, stream>>>(
        qkv, W_proj, (float*)d_out, 2048, 2048, 6144);
  }
}

// Round 8
// 535.097 us; speedup vs baseline: 1.3738x; 1.0424x over previous
//
#include <hip/hip_runtime.h>

typedef unsigned short u16;
typedef unsigned int u32;
typedef __bf16 bf16x8 __attribute__((ext_vector_type(8)));
typedef float f32x4 __attribute__((ext_vector_type(4)));

#define B_ 2
#define T_ 2048
#define C_ 2048
#define H_ 16
#define HS_ 128
#define AL_ 10
#define C3_ 6144
#define MASKV (-3.0e38f)   // finite "-inf": exp(MASKV - m) == 0
#define MFMA16(a, b, c) __builtin_amdgcn_mfma_f32_16x16x32_bf16(a, b, c, 0, 0, 0)

// async global->LDS DMA, 16B per lane. LDS dest = wave-uniform base + lane*16;
// global src is per-lane. size MUST be a literal (guide: Common-mistake #1).
#define GLDS16(g, l) __builtin_amdgcn_global_load_lds(                         \
    (const __attribute__((address_space(1))) u32*)(const void*)(g),            \
    (__attribute__((address_space(3))) u32*)(void*)(l), 16, 0, 0)

__device__ __forceinline__ float b2f(u16 v) {
  union { u32 u; float f; } x; x.u = ((u32)v) << 16; return x.f;
}
__device__ __forceinline__ u16 f2b(float f) {
  u32 u = __builtin_bit_cast(u32, f);
  return (u16)((u + 0x7FFFu + ((u >> 16) & 1u)) >> 16);  // RNE
}
// fp32 -> bf16 -> fp32 (match the np ref's bf16-cast of fp32 inputs)
__device__ __forceinline__ float rb(float f) { return b2f(f2b(f)); }

// ---------------------------------------------------------------------------
// Merged f32 -> bf16 bulk convert for x / W_attn / W_proj in ONE launch.
// ---------------------------------------------------------------------------
__global__ __launch_bounds__(256) void convert_all(
    const float* __restrict__ x,  u16* __restrict__ xb,
    const float* __restrict__ Wa, u16* __restrict__ Wab,
    const float* __restrict__ Wp, u16* __restrict__ Wpb)
{
  int i = blockIdx.x * 256 + threadIdx.x;        // 0 .. 3145727 (x8 elems)
  const float* in; u16* out;
  if (i < 1048576)      { in = x;  out = xb;  }
  else if (i < 2621440) { in = Wa; out = Wab; i -= 1048576; }
  else                  { in = Wp; out = Wpb; i -= 2621440; }
  union { float4 v[2]; float s[8]; } f;
  f.v[0] = *(const float4*)(in + (size_t)i * 8);
  f.v[1] = *(const float4*)(in + (size_t)i * 8 + 4);
  union { uint4 v; u16 e[8]; } o;
#pragma unroll
  for (int j = 0; j < 8; j++) o.e[j] = f2b(f.s[j]);
  *(uint4*)(out + (size_t)i * 8) = o.v;
}

// ---------------------------------------------------------------------------
// Fast GEMM (m97 structure): C(MxN) = A(MxK) * B(NxK)^T, both bf16, fp32
// accum. 128x128 tile, BK=32, 4 waves x 64x64 quadrant, global_load_lds
// width-16 staging, 2 barriers/iter, bijective XCD swizzle. (unchanged)
// ---------------------------------------------------------------------------
template <bool OUTF32>
__global__ __launch_bounds__(256) void gemm_lds(
    const u16* __restrict__ Ap, const u16* __restrict__ Bp,
    void* __restrict__ Cp, int N, int K, int lda)
{
  __shared__ u16 lA[128 * 32];
  __shared__ u16 lB[128 * 32];
  const int tid  = threadIdx.x;
  const int lane = tid & 63, wave = tid >> 6;
  const int quad = lane >> 4, l16 = lane & 15;
  const int nwg = gridDim.x * gridDim.y;
  int bid = blockIdx.y * gridDim.x + blockIdx.x;
  bid = (bid & 7) * (nwg >> 3) + (bid >> 3);
  const int bm = (bid / gridDim.x) * 128, bn = (bid % gridDim.x) * 128;
  const int wm = (wave >> 1) * 64, wn = (wave & 1) * 64;

  // staging map: LDS byte = wave*1024 + j*4096 + lane*16
  const int r0 = wave * 16 + (lane >> 2);
  const int c0 = (lane & 3) * 8;
  const u16* ga0 = Ap + (size_t)(bm + r0) * lda + c0;
  const u16* ga1 = ga0 + (size_t)64 * lda;
  const u16* gb0 = Bp + (size_t)(bn + r0) * K + c0;
  const u16* gb1 = gb0 + (size_t)64 * K;
  u16* la0 = &lA[wave * 512];
  u16* lb0 = &lB[wave * 512];

  f32x4 acc[4][4] = {};
  for (int k0 = 0; k0 < K; k0 += 32) {
    __syncthreads();                       // prior-iter LDS reads done
    GLDS16(ga0, la0);
    GLDS16(ga1, la0 + 2048);
    GLDS16(gb0, lb0);
    GLDS16(gb1, lb0 + 2048);
    ga0 += 32; ga1 += 32; gb0 += 32; gb1 += 32;
    __syncthreads();                       // DMA landed
    bf16x8 af[4], bfv[4];
#pragma unroll
    for (int i = 0; i < 4; i++)
      af[i] = *(const bf16x8*)&lA[(wm + i * 16 + l16) * 32 + quad * 8];
#pragma unroll
    for (int i = 0; i < 4; i++)
      bfv[i] = *(const bf16x8*)&lB[(wn + i * 16 + l16) * 32 + quad * 8];
#pragma unroll
    for (int i = 0; i < 4; i++)
#pragma unroll
      for (int j = 0; j < 4; j++)
        acc[i][j] = MFMA16(af[i], bfv[j], acc[i][j]);
  }
  // C/D layout: col = lane&15, row = quad*4 + reg  [m89/m91 verified]
#pragma unroll
  for (int i = 0; i < 4; i++) {
#pragma unroll
    for (int r = 0; r < 4; r++) {
      const int row = bm + wm + i * 16 + quad * 4 + r;
      if constexpr (OUTF32) {
        float* crow = (float*)Cp + (size_t)row * N + bn + wn + l16;
#pragma unroll
        for (int j = 0; j < 4; j++)
          crow[j * 16] = acc[i][j][r];
      } else {
        u16* crow = (u16*)Cp + (size_t)row * N + bn + wn + l16;
#pragma unroll
        for (int j = 0; j < 4; j++)
          crow[j * 16] = f2b(acc[i][j][r]);
      }
    }
  }
}

// ---------------------------------------------------------------------------
// Fallback GEMM (used only if ws_size can't host bf16 copies).
// ---------------------------------------------------------------------------
template <bool AF32, bool BF32, bool OUTF32>
__global__ __launch_bounds__(256) void gemm_nt(
    const void* __restrict__ Ap, const void* __restrict__ Bp,
    void* __restrict__ Cp, int N, int K, int lda)
{
  __shared__ u16 lA[128 * 32];
  __shared__ u16 lB[128 * 32];
  const int tid  = threadIdx.x;
  const int lane = tid & 63, wave = tid >> 6;
  const int quad = lane >> 4, l16 = lane & 15;
  const int bm = blockIdx.y * 128, bn = blockIdx.x * 128;
  const int wm = (wave >> 1) * 64, wn = (wave & 1) * 64;
  const int srow = tid >> 1, scol = (tid & 1) * 16;
  f32x4 acc[4][4] = {};

  for (int k0 = 0; k0 < K; k0 += 32) {
    __align__(16) u16 abuf[16], bbuf[16];
    if constexpr (AF32) {
      const float* gA = (const float*)Ap + (size_t)(bm + srow) * lda + scol + k0;
      union { float4 v[4]; float s[16]; } fa;
#pragma unroll
      for (int j = 0; j < 4; j++) fa.v[j] = *(const float4*)(gA + j * 4);
#pragma unroll
      for (int j = 0; j < 16; j++) abuf[j] = f2b(fa.s[j]);
    } else {
      const u16* gA = (const u16*)Ap + (size_t)(bm + srow) * lda + scol + k0;
      *(uint4*)&abuf[0] = *(const uint4*)(gA);
      *(uint4*)&abuf[8] = *(const uint4*)(gA + 8);
    }
    if constexpr (BF32) {
      const float* gB = (const float*)Bp + (size_t)(bn + srow) * K + scol + k0;
      union { float4 v[4]; float s[16]; } fb;
#pragma unroll
      for (int j = 0; j < 4; j++) fb.v[j] = *(const float4*)(gB + j * 4);
#pragma unroll
      for (int j = 0; j < 16; j++) bbuf[j] = f2b(fb.s[j]);
    } else {
      const u16* gB = (const u16*)Bp + (size_t)(bn + srow) * K + scol + k0;
      *(uint4*)&bbuf[0] = *(const uint4*)(gB);
      *(uint4*)&bbuf[8] = *(const uint4*)(gB + 8);
    }
    __syncthreads();
    *(uint4*)&lA[srow * 32 + scol]     = *(uint4*)&abuf[0];
    *(uint4*)&lA[srow * 32 + scol + 8] = *(uint4*)&abuf[8];
    *(uint4*)&lB[srow * 32 + scol]     = *(uint4*)&bbuf[0];
    *(uint4*)&lB[srow * 32 + scol + 8] = *(uint4*)&bbuf[8];
    __syncthreads();
    bf16x8 af[4], bfv[4];
#pragma unroll
    for (int i = 0; i < 4; i++)
      af[i] = *(const bf16x8*)&lA[(wm + i * 16 + l16) * 32 + quad * 8];
#pragma unroll
    for (int i = 0; i < 4; i++)
      bfv[i] = *(const bf16x8*)&lB[(wn + i * 16 + l16) * 32 + quad * 8];
#pragma unroll
    for (int i = 0; i < 4; i++)
#pragma unroll
      for (int j = 0; j < 4; j++)
        acc[i][j] = MFMA16(af[i], bfv[j], acc[i][j]);
  }
#pragma unroll
  for (int i = 0; i < 4; i++) {
#pragma unroll
    for (int r = 0; r < 4; r++) {
      const int row = bm + wm + i * 16 + quad * 4 + r;
      if constexpr (OUTF32) {
        float* crow = (float*)Cp + (size_t)row * N + bn + wn + l16;
#pragma unroll
        for (int j = 0; j < 4; j++)
          crow[j * 16] = acc[i][j][r];
      } else {
        u16* crow = (u16*)Cp + (size_t)row * N + bn + wn + l16;
#pragma unroll
        for (int j = 0; j < 4; j++)
          crow[j * 16] = f2b(acc[i][j][r]);
      }
    }
  }
}

// ---------------------------------------------------------------------------
// Adapter pqkv: ak/av[h][l][d] = bf16(adapter_emb[l]) . bf16(W_attn[...]).
// ---------------------------------------------------------------------------
__global__ __launch_bounds__(256) void adapter_pqkv(
    const float* __restrict__ emb, const float* __restrict__ W,
    float* __restrict__ akb, float* __restrict__ avb)
{
  const int tid = threadIdx.x;
  const int lane = tid & 63;
  const int w = blockIdx.x * 4 + (tid >> 6);      // 0..4095
  const int part = w >> 11;                        // 0 = k, 1 = v
  const int col = w & 2047;                        // h*128 + d
  const float* wrow = W + (size_t)(C_ + part * C_ + col) * C_;
  float acc[AL_];
#pragma unroll
  for (int l = 0; l < AL_; l++) acc[l] = 0.f;
  for (int i = 0; i < 32; i++) {
    const int c = i * 64 + lane;
    const float wv = rb(wrow[c]);
#pragma unroll
    for (int l = 0; l < AL_; l++) acc[l] += wv * rb(emb[l * C_ + c]);
  }
#pragma unroll
  for (int l = 0; l < AL_; l++) {
    for (int off = 32; off > 0; off >>= 1) acc[l] += __shfl_xor(acc[l], off);
  }
  if (lane == 0) {
    const int h = col >> 7, d = col & 127;
    float* dst = (part == 0 ? akb : avb) + (size_t)h * AL_ * HS_ + d;
#pragma unroll
    for (int l = 0; l < AL_; l++) dst[l * HS_] = acc[l];
  }
}

// ---------------------------------------------------------------------------
// Merged RoPE (blocks [0,16384)) + V transpose (blocks [16384,17408)).
// ---------------------------------------------------------------------------
__global__ __launch_bounds__(256) void rope_tv(
    u16* __restrict__ qkv, const float* __restrict__ rope,
    u16* __restrict__ vt)
{
  __shared__ __align__(16) char lT[64 * 256];
  const int bid = blockIdx.x;
  if (bid < 16384) {                         // ---- rope path ----
    const int g = bid * 256 + threadIdx.x;
    const int j2 = g & 63;
    const int h  = (g >> 6) & 15;
    const int t  = (g >> 10) & 2047;
    const int b  = g >> 21;
    u16* src = qkv + (size_t)(b * T_ + t) * C3_ + h * HS_ + j2 * 2;
    const u32 qp = *(const u32*)(src);
    const u32 kp = *(const u32*)(src + C_);
    const float2 rp = *(const float2*)(rope + (t * 64 + j2) * 2);
    const float c = rb(rp.x), s = rb(rp.y);
    const float q0 = b2f((u16)qp), q1 = b2f((u16)(qp >> 16));
    const float k0 = b2f((u16)kp), k1 = b2f((u16)(kp >> 16));
    const float qr0 = q0 * c - q1 * s, qr1 = q1 * c + q0 * s;
    const float kr0 = k0 * c - k1 * s, kr1 = k1 * c + k0 * s;
    *(u32*)(src)      = (u32)f2b(qr0) | ((u32)f2b(qr1) << 16);
    *(u32*)(src + C_) = (u32)f2b(kr0) | ((u32)f2b(kr1) << 16);
    return;
  }
  // ---- transpose path (1024 blocks) ----
  const int r = bid - 16384;
  const int tid = threadIdx.x;
  const int t0 = (r & 31) * 64, h = (r >> 5) & 15, b = r >> 9;
  const u16* Vg = qkv + (size_t)(b * T_ + t0) * C3_ + 2 * C_ + h * HS_;
#pragma unroll
  for (int i = 0; i < 4; i++) {
    const int e = (i * 256 + tid) * 8;      // u16 linear index in 64x128
    const int t = e >> 7, c = e & 127;
    *(uint4*)(lT + t * 256 + ((c * 2) ^ ((t & 7) << 4))) =
        *(const uint4*)(Vg + (size_t)t * C3_ + c);
  }
  __syncthreads();
  const int d = tid >> 1, half = tid & 1;
  __align__(16) u16 out[32];
#pragma unroll
  for (int tt = 0; tt < 32; tt++) {
    const int t = half * 32 + tt;
    out[tt] = *(const u16*)(lT + t * 256 + ((d * 2) ^ ((t & 7) << 4)));
  }
  u16* dst = vt + ((size_t)(b * H_ + h) * HS_ + d) * T_ + t0 + half * 32;
  *(uint4*)(dst)      = *(const uint4*)&out[0];
  *(uint4*)(dst + 8)  = *(const uint4*)&out[8];
  *(uint4*)(dst + 16) = *(const uint4*)&out[16];
  *(uint4*)(dst + 24) = *(const uint4*)&out[24];
}

// ---------------------------------------------------------------------------
// Flash attention + gated adapter attention.
// R7 post-mortem: loop-top staging latency is the exposed cost. This round:
// T3 minimum-2-phase with global_load_lds DMA K/V staging into DOUBLE-
// BUFFERED LDS: issue tile kt+1's 4 DMA ops at loop top, compute tile kt,
// ONE __syncthreads per iteration (drains vmcnt -> DMA landed). LDS dest is
// linear (wave base + lane*16, rule #21); the GLOBAL source carries the
// inverse XOR so the verified read-side swizzles are unchanged:
//   K: read byte = row*256 + (2c ^ ((row&7)<<4))   [same as R6/R7]
//   V: linear 64B rows + read ^(((d>>1)&3)<<4)  (8 bank-groups x 2 = free)
// Q hoisted to 4 bf16x8 registers (frees smQ -> K+V dbuf fit in 37888 B,
// still 4 blocks/CU). Adapter phase re-reads Q from global (L2-hot, 1x).
// Softmax / P-store / PV numerics byte-identical to R6/R7.
// y written IN-PLACE over qkv q-part (block-private patch).
// ---------------------------------------------------------------------------
__global__ __launch_bounds__(256, 4) void attn_flash(
    u16* __restrict__ qkv, const u16* __restrict__ vt,
    const float* __restrict__ akbuf, const float* __restrict__ avbuf,
    const float* __restrict__ gating)
{
  __shared__ __align__(16) char smem[37888];
  char* smKb = smem;                   // [0,16384)      2 x (32 rows x 256B)
  char* smVb = smem + 16384;           // [16384,32768)  2 x (128 d x 64B)
  char* smP  = smem + 32768;           // [32768,37888)  P: 64 rows x 80B

  const int tid  = threadIdx.x;
  const int lane = tid & 63, wave = tid >> 6;
  const int quad = lane >> 4, l16 = lane & 15;
  const int qt = 31 - (int)blockIdx.x, h = blockIdx.y, b = blockIdx.z;
  u16* Qg = qkv + ((size_t)(b * T_) + qt * 64) * C3_ + h * HS_;           // q-part
  const u16* Kg = qkv + (size_t)(b * T_) * C3_ + C_ + h * HS_;            // k-part
  const u16* Vt = vt + (size_t)(b * H_ + h) * HS_ * T_;
  const float scale = 0.08838834764831845f;   // 1/sqrt(128)

  // ---- staging geometry (DMA: LDS byte = buf + it*4096 + wave*1024 + lane*16)
  // K: row = it*16 + wave*4 + (lane>>4), colbyte = (lane&15)*16.
  //    (row&7) identical for it=0/1 -> one swizzled source offset.
  const int krow = wave * 4 + (lane >> 4);
  const int kco  = (((lane & 15) * 16) ^ ((krow & 7) << 4)) >> 1;
  // V: d = it*64 + wave*16 + (lane>>2), c2byte = (lane&3)*16.
  //    ((d>>1)&3) identical for it=0/1 -> one swizzled source offset.
  const int vd0 = wave * 16 + (lane >> 2);
  const int vco = (((lane & 3) * 16) ^ (((vd0 >> 1) & 3) << 4)) >> 1;

#define STAGE_KV(KT, BUF) do {                                                 \
    char* kb_ = smKb + (BUF) * 8192 + wave * 1024;                             \
    char* vb_ = smVb + (BUF) * 8192 + wave * 1024;                             \
    const u16* ks0_ = Kg + (size_t)((KT) * 32 + krow) * C3_ + kco;             \
    const u16* ks1_ = Kg + (size_t)((KT) * 32 + 16 + krow) * C3_ + kco;        \
    GLDS16(ks0_, kb_);                                                         \
    GLDS16(ks1_, kb_ + 4096);                                                  \
    const u16* vs0_ = Vt + (size_t)vd0 * T_ + (KT) * 32 + vco;                 \
    const u16* vs1_ = Vt + (size_t)(vd0 + 64) * T_ + (KT) * 32 + vco;          \
    GLDS16(vs0_, vb_);                                                         \
    GLDS16(vs1_, vb_ + 4096);                                                  \
  } while (0)

  // ---- Q hoist: this lane's 4 A-fragments (row wave*16+l16), from global
  bf16x8 qf[4];
  {
    const u16* qrow = Qg + (size_t)(wave * 16 + l16) * C3_;
#pragma unroll
    for (int kk = 0; kk < 4; kk++)
      qf[kk] = *(const bf16x8*)(qrow + kk * 32 + quad * 8);
  }

  f32x4 acc[8] = {};
  float mrun = MASKV, lrun = 0.f;              // stats for q-row = wave*16+l16
  const int nkt = (qt + 1) * 2;
  const int qg = qt * 64 + wave * 16 + l16;    // this lane's q-row (score side)
  const int vsw = ((l16 >> 1) & 3) << 4;       // V read swizzle (lane-const)

  // ---- prologue: tile 0 -> buffer 0
  STAGE_KV(0, 0);
  __syncthreads();                             // DMA landed (drains vmcnt)

  int cur = 0;
  for (int kt = 0; kt < nkt; kt++) {
    // ---- issue NEXT tile's DMA into the other buffer (latency hides under
    //      this tile's compute; prior reads of that buffer finished at the
    //      previous iteration's barrier)
    if (kt + 1 < nkt) STAGE_KV(kt + 1, cur ^ 1);
    const char* smK = smKb + cur * 8192;
    const char* smV = smVb + cur * 8192;
    // ---- S^T = K Q^T: D[k = n*16 + quad*4 + r][q = l16] ----
    f32x4 sacc[2] = {};
    const int sw = (l16 & 7) << 4;
#pragma unroll
    for (int kk = 0; kk < 4; kk++) {
      const int co = (kk * 64 + quad * 16) ^ sw;
      bf16x8 bk0 = *(const bf16x8*)(smK + l16 * 256 + co);
      bf16x8 bk1 = *(const bf16x8*)(smK + (16 + l16) * 256 + co);
      sacc[0] = MFMA16(bk0, qf[kk], sacc[0]);  // rows = keys 0..15
      sacc[1] = MFMA16(bk1, qf[kk], sacc[1]);  // rows = keys 16..31
    }
    // ---- online softmax: whole row in-lane; tree + 2 shuffles ----
    float s[8];
#pragma unroll
    for (int n = 0; n < 2; n++)
#pragma unroll
      for (int r = 0; r < 4; r++) {
        float v = sacc[n][r] * scale;
        if (kt * 32 + n * 16 + quad * 4 + r > qg) v = MASKV;
        s[n * 4 + r] = v;
      }
    float rmax = fmaxf(fmaxf(fmaxf(s[0], s[1]), fmaxf(s[2], s[3])),
                       fmaxf(fmaxf(s[4], s[5]), fmaxf(s[6], s[7])));
    rmax = fmaxf(rmax, __shfl_xor(rmax, 16));
    rmax = fmaxf(rmax, __shfl_xor(rmax, 32));
    const float mnew = fmaxf(mrun, rmax);
    const float alpha = __expf(mrun - mnew);
    mrun = mnew;
    float p[8];
#pragma unroll
    for (int i = 0; i < 8; i++) p[i] = __expf(s[i] - mnew);
    float rs = ((p[0] + p[1]) + (p[2] + p[3])) + ((p[4] + p[5]) + (p[6] + p[7]));
    rs += __shfl_xor(rs, 16);
    rs += __shfl_xor(rs, 32);
    lrun = lrun * alpha + rs;
    // alpha in PV layout (q = quad*4 + r): 4 independent broadcasts
    float alr[4];
#pragma unroll
    for (int r = 0; r < 4; r++) alr[r] = __shfl(alpha, quad * 4 + r);
    // ---- P store: row = q (wave*16+l16), packed u32 pairs over k ----
    // Wave-private region: same-wave lgkmcnt orders store->load.
    {
      char* prow = smP + (wave * 16 + l16) * 80;
#pragma unroll
      for (int n = 0; n < 2; n++)
#pragma unroll
        for (int rp = 0; rp < 2; rp++) {
          const u32 w = (u32)f2b(p[n * 4 + rp * 2]) |
                        ((u32)f2b(p[n * 4 + rp * 2 + 1]) << 16);
          *(u32*)(prow + (n * 16 + quad * 4 + rp * 2) * 2) = w;
        }
    }
    // ---- rescale O (acc row q = wave*16 + quad*4 + r) ----
#pragma unroll
    for (int nt = 0; nt < 8; nt++)
#pragma unroll
      for (int r = 0; r < 4; r++) acc[nt][r] *= alr[r];
    // ---- O += P V ----
    {
      bf16x8 ap = *(const bf16x8*)(smP + (wave * 16 + l16) * 80 + quad * 16);
#pragma unroll
      for (int nt = 0; nt < 8; nt++) {
        bf16x8 bv = *(const bf16x8*)(smV + (nt * 16 + l16) * 64 +
                                     ((quad * 16) ^ vsw));
        acc[nt] = MFMA16(ap, bv, acc[nt]);
      }
    }
    // ---- one barrier per tile: drains vmcnt (next buffer's DMA landed) and
    //      fences this buffer's reads before the NEXT iteration's DMA refill.
    __syncthreads();
    cur ^= 1;
  }
#undef STAGE_KV
  // lrun lives in q=l16 layout; epilogue needs q=quad*4+r: broadcast once
  float lr[4];
#pragma unroll
  for (int r = 0; r < 4; r++) lr[r] = __shfl(lrun, quad * 4 + r);
  // ---- adapter attention (10 prefix keys, separate softmax) ----
  // Loop's final barrier: all waves past PV; smKb/smVb/smP dead.
  float* lAk = (float*)smVb;                   // overlay [16384,26624)
  float* lAv = lAk + AL_ * HS_;
  {
    const float* aks = akbuf + (size_t)h * AL_ * HS_;
    const float* avs = avbuf + (size_t)h * AL_ * HS_;
    for (int i = tid; i < AL_ * HS_; i += 256) { lAk[i] = aks[i]; lAv[i] = avs[i]; }
  }
  __syncthreads();
  const int ar = tid >> 2, ah = tid & 3;       // 4 threads per q-row, 32 cols each
  const u16* qr = Qg + (size_t)ar * C3_ + ah * 32;   // Q re-read from global (L2)
  float sa[AL_];
#pragma unroll
  for (int l = 0; l < AL_; l++) sa[l] = 0.f;
#pragma unroll
  for (int c = 0; c < 4; c++) {                // own quarter of d, 16B reads
    union { uint4 v; u16 e[8]; } qv;
    qv.v = *(const uint4*)(qr + c * 8);
#pragma unroll
    for (int j = 0; j < 8; j++) {
      const float qf2 = b2f(qv.e[j]);
#pragma unroll
      for (int l = 0; l < AL_; l++) sa[l] += qf2 * lAk[l * HS_ + ah * 32 + c * 8 + j];
    }
  }
#pragma unroll
  for (int l = 0; l < AL_; l++) {
    sa[l] += __shfl_xor(sa[l], 1);
    sa[l] += __shfl_xor(sa[l], 2);
    sa[l] *= scale;
  }
  float smax = sa[0];
#pragma unroll
  for (int l = 1; l < AL_; l++) smax = fmaxf(smax, sa[l]);
  float ssum = 0.f;
#pragma unroll
  for (int l = 0; l < AL_; l++) { sa[l] = __expf(sa[l] - smax); ssum += sa[l]; }
  const float inv = 1.f / ssum;
#pragma unroll
  for (int l = 0; l < AL_; l++) sa[l] *= inv;
  __syncthreads();                             // all adapter Q/lAk reads done
  u16* lAy = (u16*)smem;                       // overlay [0,16384): 64x128 u16
#pragma unroll
  for (int c = 0; c < 4; c++) {
    const int col = ah * 32 + c * 8;
    union { uint4 v; u16 e[8]; } ov;
#pragma unroll
    for (int j = 0; j < 8; j++) {
      float a = 0.f;
#pragma unroll
      for (int l = 0; l < AL_; l++) a += sa[l] * lAv[l * HS_ + col + j];
      ov.e[j] = f2b(a);
    }
    *(uint4*)(lAy + ar * HS_ + col) = ov.v;
  }
  __syncthreads();
  // ---- epilogue: y = O/l + g*ay, written over qkv q-part (block's own patch)
  const float g = rb(gating[h]);
#pragma unroll
  for (int r = 0; r < 4; r++) {
    const int row = wave * 16 + quad * 4 + r;
    const float linv = 1.f / lr[r];
    u16* yrow = Qg + (size_t)row * C3_ + l16;
#pragma unroll
    for (int nt = 0; nt < 8; nt++) {
      const float v = acc[nt][r] * linv + g * b2f(lAy[row * HS_ + nt * 16 + l16]);
      yrow[nt * 16] = f2b(v);
    }
  }
}

// ---------------------------------------------------------------------------
extern "C" void kernel_launch(void* const* d_in, const int* in_sizes, int n_in,
                              void* d_out, int out_size, void* d_ws, size_t ws_size,
                              hipStream_t stream) {
  (void)out_size;
  int ix = 0, irope = 1, iW = 3, iP = 4, iE = 5, iG = 6;
  for (int i = 0; i < n_in; i++) {
    switch (in_sizes[i]) {
      case 8388608:  ix = i;    break;   // x (2,2048,2048)
      case 262144:   irope = i; break;   // rope (2048,64,2)
      case 12582912: iW = i;    break;   // W_attn (6144,2048)
      case 20480:    iE = i;    break;   // adapter_emb (10,2048)
      case 16:       iG = i;    break;   // gating (1,16,1,1)
      case 4194304:  iP = i;    break;   // mask (idx 2) then W_proj (idx 4): last wins
      default: break;
    }
  }
  const float* x      = (const float*)d_in[ix];
  const float* rope   = (const float*)d_in[irope];
  const float* W_attn = (const float*)d_in[iW];
  const float* W_proj = (const float*)d_in[iP];
  const float* emb    = (const float*)d_in[iE];
  const float* gating = (const float*)d_in[iG];

  // Workspace layout (fast path, 96 MiB):
  //   [0,48M) qkv bf16 | [48,64M) xb | [64,88M) Wab | [88,96M) Wpb
  // d_out (32 MiB, dead until proj GEMM) hosts ak/av fp32 (160 KiB) + vt (16 MiB).
  u16*   qkv = (u16*)d_ws;
  float* akb = (float*)d_out;
  float* avb = akb + (size_t)H_ * AL_ * HS_;
  u16*   vtb = (u16*)(avb + (size_t)H_ * AL_ * HS_);

  const bool fast = ws_size >= (size_t)100663296;  // 96 MiB
  if (fast) {
    u16* xb  = qkv + (size_t)25165824;   // 48 MiB / 2
    u16* Wab = xb  + (size_t)8388608;
    u16* Wpb = Wab + (size_t)12582912;
    convert_all<<<dim3(12288), 256, 0, stream>>>(x, xb, W_attn, Wab, W_proj, Wpb);
    gemm_lds<false><<<dim3(48, 32), 256, 0, stream>>>(xb, Wab, qkv, 6144, 2048, 2048);
    adapter_pqkv<<<dim3(1024), 256, 0, stream>>>(emb, W_attn, akb, avb);
    rope_tv<<<dim3(17408), 256, 0, stream>>>(qkv, rope, vtb);
    attn_flash<<<dim3(32, 16, 2), 256, 0, stream>>>(qkv, vtb, akb, avb, gating);
    gemm_lds<true><<<dim3(16, 32), 256, 0, stream>>>(qkv, Wpb, (float*)d_out, 2048, 2048, 6144);
  } else {
    gemm_nt<true, true, false><<<dim3(48, 32), 256, 0, stream>>>(
        x, W_attn, qkv, 6144, 2048, 2048);
    adapter_pqkv<<<dim3(1024), 256, 0, stream>>>(emb, W_attn, akb, avb);
    rope_tv<<<dim3(17408), 256, 0, stream>>>(qkv, rope, vtb);
    attn_flash<<<dim3(32, 16, 2), 256, 0, stream>>>(qkv, vtb, akb, avb, gating);
    gemm_nt<false, true, true><<<dim3(16, 32), 256, 0, stream>>>(
        qkv, W_proj, (float*)d_out, 2048, 2048, 6144);
  }
}

// Round 9
// 512.912 us; speedup vs baseline: 1.4332x; 1.0433x over previous
//
#include <hip/hip_runtime.h>

typedef unsigned short u16;
typedef unsigned int u32;
typedef __bf16 bf16x8 __attribute__((ext_vector_type(8)));
typedef float f32x4 __attribute__((ext_vector_type(4)));

#define B_ 2
#define T_ 2048
#define C_ 2048
#define H_ 16
#define HS_ 128
#define AL_ 10
#define C3_ 6144
#define MASKV (-3.0e38f)   // finite "-inf": exp(MASKV - m) == 0
#define MFMA16(a, b, c) __builtin_amdgcn_mfma_f32_16x16x32_bf16(a, b, c, 0, 0, 0)

// async global->LDS DMA, 16B per lane. LDS dest = wave-uniform base + lane*16;
// global src is per-lane. size MUST be a literal (guide: Common-mistake #1).
#define GLDS16(g, l) __builtin_amdgcn_global_load_lds(                         \
    (const __attribute__((address_space(1))) u32*)(const void*)(g),            \
    (__attribute__((address_space(3))) u32*)(void*)(l), 16, 0, 0)

__device__ __forceinline__ float b2f(u16 v) {
  union { u32 u; float f; } x; x.u = ((u32)v) << 16; return x.f;
}
__device__ __forceinline__ u16 f2b(float f) {
  u32 u = __builtin_bit_cast(u32, f);
  return (u16)((u + 0x7FFFu + ((u >> 16) & 1u)) >> 16);  // RNE
}
// fp32 -> bf16 -> fp32 (match the np ref's bf16-cast of fp32 inputs)
__device__ __forceinline__ float rb(float f) { return b2f(f2b(f)); }

// ---------------------------------------------------------------------------
// Merged f32 -> bf16 bulk convert for x / W_attn / W_proj in ONE launch.
// ---------------------------------------------------------------------------
__global__ __launch_bounds__(256) void convert_all(
    const float* __restrict__ x,  u16* __restrict__ xb,
    const float* __restrict__ Wa, u16* __restrict__ Wab,
    const float* __restrict__ Wp, u16* __restrict__ Wpb)
{
  int i = blockIdx.x * 256 + threadIdx.x;        // 0 .. 3145727 (x8 elems)
  const float* in; u16* out;
  if (i < 1048576)      { in = x;  out = xb;  }
  else if (i < 2621440) { in = Wa; out = Wab; i -= 1048576; }
  else                  { in = Wp; out = Wpb; i -= 2621440; }
  union { float4 v[2]; float s[8]; } f;
  f.v[0] = *(const float4*)(in + (size_t)i * 8);
  f.v[1] = *(const float4*)(in + (size_t)i * 8 + 4);
  union { uint4 v; u16 e[8]; } o;
#pragma unroll
  for (int j = 0; j < 8; j++) o.e[j] = f2b(f.s[j]);
  *(uint4*)(out + (size_t)i * 8) = o.v;
}

// ---------------------------------------------------------------------------
// Fast GEMM (m97 structure): C(MxN) = A(MxK) * B(NxK)^T, both bf16, fp32
// accum. 128x128 tile, BK=32, 4 waves x 64x64 quadrant, global_load_lds
// width-16 staging, 2 barriers/iter, bijective XCD swizzle. (unchanged)
// ---------------------------------------------------------------------------
template <bool OUTF32>
__global__ __launch_bounds__(256) void gemm_lds(
    const u16* __restrict__ Ap, const u16* __restrict__ Bp,
    void* __restrict__ Cp, int N, int K, int lda)
{
  __shared__ u16 lA[128 * 32];
  __shared__ u16 lB[128 * 32];
  const int tid  = threadIdx.x;
  const int lane = tid & 63, wave = tid >> 6;
  const int quad = lane >> 4, l16 = lane & 15;
  const int nwg = gridDim.x * gridDim.y;
  int bid = blockIdx.y * gridDim.x + blockIdx.x;
  bid = (bid & 7) * (nwg >> 3) + (bid >> 3);
  const int bm = (bid / gridDim.x) * 128, bn = (bid % gridDim.x) * 128;
  const int wm = (wave >> 1) * 64, wn = (wave & 1) * 64;

  // staging map: LDS byte = wave*1024 + j*4096 + lane*16
  const int r0 = wave * 16 + (lane >> 2);
  const int c0 = (lane & 3) * 8;
  const u16* ga0 = Ap + (size_t)(bm + r0) * lda + c0;
  const u16* ga1 = ga0 + (size_t)64 * lda;
  const u16* gb0 = Bp + (size_t)(bn + r0) * K + c0;
  const u16* gb1 = gb0 + (size_t)64 * K;
  u16* la0 = &lA[wave * 512];
  u16* lb0 = &lB[wave * 512];

  f32x4 acc[4][4] = {};
  for (int k0 = 0; k0 < K; k0 += 32) {
    __syncthreads();                       // prior-iter LDS reads done
    GLDS16(ga0, la0);
    GLDS16(ga1, la0 + 2048);
    GLDS16(gb0, lb0);
    GLDS16(gb1, lb0 + 2048);
    ga0 += 32; ga1 += 32; gb0 += 32; gb1 += 32;
    __syncthreads();                       // DMA landed
    bf16x8 af[4], bfv[4];
#pragma unroll
    for (int i = 0; i < 4; i++)
      af[i] = *(const bf16x8*)&lA[(wm + i * 16 + l16) * 32 + quad * 8];
#pragma unroll
    for (int i = 0; i < 4; i++)
      bfv[i] = *(const bf16x8*)&lB[(wn + i * 16 + l16) * 32 + quad * 8];
#pragma unroll
    for (int i = 0; i < 4; i++)
#pragma unroll
      for (int j = 0; j < 4; j++)
        acc[i][j] = MFMA16(af[i], bfv[j], acc[i][j]);
  }
  // C/D layout: col = lane&15, row = quad*4 + reg  [m89/m91 verified]
#pragma unroll
  for (int i = 0; i < 4; i++) {
#pragma unroll
    for (int r = 0; r < 4; r++) {
      const int row = bm + wm + i * 16 + quad * 4 + r;
      if constexpr (OUTF32) {
        float* crow = (float*)Cp + (size_t)row * N + bn + wn + l16;
#pragma unroll
        for (int j = 0; j < 4; j++)
          crow[j * 16] = acc[i][j][r];
      } else {
        u16* crow = (u16*)Cp + (size_t)row * N + bn + wn + l16;
#pragma unroll
        for (int j = 0; j < 4; j++)
          crow[j * 16] = f2b(acc[i][j][r]);
      }
    }
  }
}

// ---------------------------------------------------------------------------
// Fallback GEMM (used only if ws_size can't host bf16 copies).
// ---------------------------------------------------------------------------
template <bool AF32, bool BF32, bool OUTF32>
__global__ __launch_bounds__(256) void gemm_nt(
    const void* __restrict__ Ap, const void* __restrict__ Bp,
    void* __restrict__ Cp, int N, int K, int lda)
{
  __shared__ u16 lA[128 * 32];
  __shared__ u16 lB[128 * 32];
  const int tid  = threadIdx.x;
  const int lane = tid & 63, wave = tid >> 6;
  const int quad = lane >> 4, l16 = lane & 15;
  const int bm = blockIdx.y * 128, bn = blockIdx.x * 128;
  const int wm = (wave >> 1) * 64, wn = (wave & 1) * 64;
  const int srow = tid >> 1, scol = (tid & 1) * 16;
  f32x4 acc[4][4] = {};

  for (int k0 = 0; k0 < K; k0 += 32) {
    __align__(16) u16 abuf[16], bbuf[16];
    if constexpr (AF32) {
      const float* gA = (const float*)Ap + (size_t)(bm + srow) * lda + scol + k0;
      union { float4 v[4]; float s[16]; } fa;
#pragma unroll
      for (int j = 0; j < 4; j++) fa.v[j] = *(const float4*)(gA + j * 4);
#pragma unroll
      for (int j = 0; j < 16; j++) abuf[j] = f2b(fa.s[j]);
    } else {
      const u16* gA = (const u16*)Ap + (size_t)(bm + srow) * lda + scol + k0;
      *(uint4*)&abuf[0] = *(const uint4*)(gA);
      *(uint4*)&abuf[8] = *(const uint4*)(gA + 8);
    }
    if constexpr (BF32) {
      const float* gB = (const float*)Bp + (size_t)(bn + srow) * K + scol + k0;
      union { float4 v[4]; float s[16]; } fb;
#pragma unroll
      for (int j = 0; j < 4; j++) fb.v[j] = *(const float4*)(gB + j * 4);
#pragma unroll
      for (int j = 0; j < 16; j++) bbuf[j] = f2b(fb.s[j]);
    } else {
      const u16* gB = (const u16*)Bp + (size_t)(bn + srow) * K + scol + k0;
      *(uint4*)&bbuf[0] = *(const uint4*)(gB);
      *(uint4*)&bbuf[8] = *(const uint4*)(gB + 8);
    }
    __syncthreads();
    *(uint4*)&lA[srow * 32 + scol]     = *(uint4*)&abuf[0];
    *(uint4*)&lA[srow * 32 + scol + 8] = *(uint4*)&abuf[8];
    *(uint4*)&lB[srow * 32 + scol]     = *(uint4*)&bbuf[0];
    *(uint4*)&lB[srow * 32 + scol + 8] = *(uint4*)&bbuf[8];
    __syncthreads();
    bf16x8 af[4], bfv[4];
#pragma unroll
    for (int i = 0; i < 4; i++)
      af[i] = *(const bf16x8*)&lA[(wm + i * 16 + l16) * 32 + quad * 8];
#pragma unroll
    for (int i = 0; i < 4; i++)
      bfv[i] = *(const bf16x8*)&lB[(wn + i * 16 + l16) * 32 + quad * 8];
#pragma unroll
    for (int i = 0; i < 4; i++)
#pragma unroll
      for (int j = 0; j < 4; j++)
        acc[i][j] = MFMA16(af[i], bfv[j], acc[i][j]);
  }
#pragma unroll
  for (int i = 0; i < 4; i++) {
#pragma unroll
    for (int r = 0; r < 4; r++) {
      const int row = bm + wm + i * 16 + quad * 4 + r;
      if constexpr (OUTF32) {
        float* crow = (float*)Cp + (size_t)row * N + bn + wn + l16;
#pragma unroll
        for (int j = 0; j < 4; j++)
          crow[j * 16] = acc[i][j][r];
      } else {
        u16* crow = (u16*)Cp + (size_t)row * N + bn + wn + l16;
#pragma unroll
        for (int j = 0; j < 4; j++)
          crow[j * 16] = f2b(acc[i][j][r]);
      }
    }
  }
}

// ---------------------------------------------------------------------------
// Adapter pqkv: ak/av[h][l][d] = bf16(adapter_emb[l]) . bf16(W_attn[...]).
// ---------------------------------------------------------------------------
__global__ __launch_bounds__(256) void adapter_pqkv(
    const float* __restrict__ emb, const float* __restrict__ W,
    float* __restrict__ akb, float* __restrict__ avb)
{
  const int tid = threadIdx.x;
  const int lane = tid & 63;
  const int w = blockIdx.x * 4 + (tid >> 6);      // 0..4095
  const int part = w >> 11;                        // 0 = k, 1 = v
  const int col = w & 2047;                        // h*128 + d
  const float* wrow = W + (size_t)(C_ + part * C_ + col) * C_;
  float acc[AL_];
#pragma unroll
  for (int l = 0; l < AL_; l++) acc[l] = 0.f;
  for (int i = 0; i < 32; i++) {
    const int c = i * 64 + lane;
    const float wv = rb(wrow[c]);
#pragma unroll
    for (int l = 0; l < AL_; l++) acc[l] += wv * rb(emb[l * C_ + c]);
  }
#pragma unroll
  for (int l = 0; l < AL_; l++) {
    for (int off = 32; off > 0; off >>= 1) acc[l] += __shfl_xor(acc[l], off);
  }
  if (lane == 0) {
    const int h = col >> 7, d = col & 127;
    float* dst = (part == 0 ? akb : avb) + (size_t)h * AL_ * HS_ + d;
#pragma unroll
    for (int l = 0; l < AL_; l++) dst[l * HS_] = acc[l];
  }
}

// ---------------------------------------------------------------------------
// Merged RoPE (blocks [0,16384)) + V transpose (blocks [16384,17408)).
// ---------------------------------------------------------------------------
__global__ __launch_bounds__(256) void rope_tv(
    u16* __restrict__ qkv, const float* __restrict__ rope,
    u16* __restrict__ vt)
{
  __shared__ __align__(16) char lT[64 * 256];
  const int bid = blockIdx.x;
  if (bid < 16384) {                         // ---- rope path ----
    const int g = bid * 256 + threadIdx.x;
    const int j2 = g & 63;
    const int h  = (g >> 6) & 15;
    const int t  = (g >> 10) & 2047;
    const int b  = g >> 21;
    u16* src = qkv + (size_t)(b * T_ + t) * C3_ + h * HS_ + j2 * 2;
    const u32 qp = *(const u32*)(src);
    const u32 kp = *(const u32*)(src + C_);
    const float2 rp = *(const float2*)(rope + (t * 64 + j2) * 2);
    const float c = rb(rp.x), s = rb(rp.y);
    const float q0 = b2f((u16)qp), q1 = b2f((u16)(qp >> 16));
    const float k0 = b2f((u16)kp), k1 = b2f((u16)(kp >> 16));
    const float qr0 = q0 * c - q1 * s, qr1 = q1 * c + q0 * s;
    const float kr0 = k0 * c - k1 * s, kr1 = k1 * c + k0 * s;
    *(u32*)(src)      = (u32)f2b(qr0) | ((u32)f2b(qr1) << 16);
    *(u32*)(src + C_) = (u32)f2b(kr0) | ((u32)f2b(kr1) << 16);
    return;
  }
  // ---- transpose path (1024 blocks) ----
  const int r = bid - 16384;
  const int tid = threadIdx.x;
  const int t0 = (r & 31) * 64, h = (r >> 5) & 15, b = r >> 9;
  const u16* Vg = qkv + (size_t)(b * T_ + t0) * C3_ + 2 * C_ + h * HS_;
#pragma unroll
  for (int i = 0; i < 4; i++) {
    const int e = (i * 256 + tid) * 8;      // u16 linear index in 64x128
    const int t = e >> 7, c = e & 127;
    *(uint4*)(lT + t * 256 + ((c * 2) ^ ((t & 7) << 4))) =
        *(const uint4*)(Vg + (size_t)t * C3_ + c);
  }
  __syncthreads();
  const int d = tid >> 1, half = tid & 1;
  __align__(16) u16 out[32];
#pragma unroll
  for (int tt = 0; tt < 32; tt++) {
    const int t = half * 32 + tt;
    out[tt] = *(const u16*)(lT + t * 256 + ((d * 2) ^ ((t & 7) << 4)));
  }
  u16* dst = vt + ((size_t)(b * H_ + h) * HS_ + d) * T_ + t0 + half * 32;
  *(uint4*)(dst)      = *(const uint4*)&out[0];
  *(uint4*)(dst + 8)  = *(const uint4*)&out[8];
  *(uint4*)(dst + 16) = *(const uint4*)&out[16];
  *(uint4*)(dst + 24) = *(const uint4*)&out[24];
}

// ---------------------------------------------------------------------------
// Flash attention + gated adapter attention.
// R8 verified: DMA double-buffered K/V, swapped-QK^T in-register softmax,
// 1 barrier/kt. This round's single variable: STATIC PAIRING for load
// balance. Occupancy counter showed avg 6.6 waves/CU (of 16 possible):
// 1024 blocks spread 2..64 iters -> drained tail. Now each block runs TWO
// q-tiles, qt = 31-bx (heavy) then qt = bx (light): every block is exactly
// 66 iterations, grid 512 uniform blocks = 2/CU, zero tail. Per-half body
// byte-identical to R8; extra __syncthreads at half end fences the LDS
// overlays before the next half's DMA refill.
// y written IN-PLACE over qkv q-part (block-private patch).
// ---------------------------------------------------------------------------
__global__ __launch_bounds__(256, 4) void attn_flash(
    u16* __restrict__ qkv, const u16* __restrict__ vt,
    const float* __restrict__ akbuf, const float* __restrict__ avbuf,
    const float* __restrict__ gating)
{
  __shared__ __align__(16) char smem[37888];
  char* smKb = smem;                   // [0,16384)      2 x (32 rows x 256B)
  char* smVb = smem + 16384;           // [16384,32768)  2 x (128 d x 64B)
  char* smP  = smem + 32768;           // [32768,37888)  P: 64 rows x 80B

  const int tid  = threadIdx.x;
  const int lane = tid & 63, wave = tid >> 6;
  const int quad = lane >> 4, l16 = lane & 15;
  const int bx = blockIdx.x, h = blockIdx.y, b = blockIdx.z;
  const u16* Kg = qkv + (size_t)(b * T_) * C3_ + C_ + h * HS_;            // k-part
  const u16* Vt = vt + (size_t)(b * H_ + h) * HS_ * T_;
  const float scale = 0.08838834764831845f;   // 1/sqrt(128)

  // ---- staging geometry (DMA: LDS byte = buf + it*4096 + wave*1024 + lane*16)
  const int krow = wave * 4 + (lane >> 4);
  const int kco  = (((lane & 15) * 16) ^ ((krow & 7) << 4)) >> 1;
  const int vd0 = wave * 16 + (lane >> 2);
  const int vco = (((lane & 3) * 16) ^ (((vd0 >> 1) & 3) << 4)) >> 1;
  const int vsw = ((l16 >> 1) & 3) << 4;       // V read swizzle (lane-const)

#define STAGE_KV(KT, BUF) do {                                                 \
    char* kb_ = smKb + (BUF) * 8192 + wave * 1024;                             \
    char* vb_ = smVb + (BUF) * 8192 + wave * 1024;                             \
    const u16* ks0_ = Kg + (size_t)((KT) * 32 + krow) * C3_ + kco;             \
    const u16* ks1_ = Kg + (size_t)((KT) * 32 + 16 + krow) * C3_ + kco;        \
    GLDS16(ks0_, kb_);                                                         \
    GLDS16(ks1_, kb_ + 4096);                                                  \
    const u16* vs0_ = Vt + (size_t)vd0 * T_ + (KT) * 32 + vco;                 \
    const u16* vs1_ = Vt + (size_t)(vd0 + 64) * T_ + (KT) * 32 + vco;          \
    GLDS16(vs0_, vb_);                                                         \
    GLDS16(vs1_, vb_ + 4096);                                                  \
  } while (0)

  for (int half = 0; half < 2; half++) {
    const int qt = half ? bx : 31 - bx;        // heavy tile first
    u16* Qg = qkv + ((size_t)(b * T_) + qt * 64) * C3_ + h * HS_;

    // ---- Q hoist: this lane's 4 A-fragments (row wave*16+l16), from global
    bf16x8 qf[4];
    {
      const u16* qrow = Qg + (size_t)(wave * 16 + l16) * C3_;
#pragma unroll
      for (int kk = 0; kk < 4; kk++)
        qf[kk] = *(const bf16x8*)(qrow + kk * 32 + quad * 8);
    }

    f32x4 acc[8] = {};
    float mrun = MASKV, lrun = 0.f;            // stats for q-row = wave*16+l16
    const int nkt = (qt + 1) * 2;
    const int qg = qt * 64 + wave * 16 + l16;  // this lane's q-row (score side)

    // ---- prologue: tile 0 -> buffer 0
    STAGE_KV(0, 0);
    __syncthreads();                           // DMA landed (drains vmcnt)

    int cur = 0;
    for (int kt = 0; kt < nkt; kt++) {
      if (kt + 1 < nkt) STAGE_KV(kt + 1, cur ^ 1);
      const char* smK = smKb + cur * 8192;
      const char* smV = smVb + cur * 8192;
      // ---- S^T = K Q^T: D[k = n*16 + quad*4 + r][q = l16] ----
      f32x4 sacc[2] = {};
      const int sw = (l16 & 7) << 4;
#pragma unroll
      for (int kk = 0; kk < 4; kk++) {
        const int co = (kk * 64 + quad * 16) ^ sw;
        bf16x8 bk0 = *(const bf16x8*)(smK + l16 * 256 + co);
        bf16x8 bk1 = *(const bf16x8*)(smK + (16 + l16) * 256 + co);
        sacc[0] = MFMA16(bk0, qf[kk], sacc[0]);
        sacc[1] = MFMA16(bk1, qf[kk], sacc[1]);
      }
      // ---- online softmax: whole row in-lane; tree + 2 shuffles ----
      float s[8];
#pragma unroll
      for (int n = 0; n < 2; n++)
#pragma unroll
        for (int r = 0; r < 4; r++) {
          float v = sacc[n][r] * scale;
          if (kt * 32 + n * 16 + quad * 4 + r > qg) v = MASKV;
          s[n * 4 + r] = v;
        }
      float rmax = fmaxf(fmaxf(fmaxf(s[0], s[1]), fmaxf(s[2], s[3])),
                         fmaxf(fmaxf(s[4], s[5]), fmaxf(s[6], s[7])));
      rmax = fmaxf(rmax, __shfl_xor(rmax, 16));
      rmax = fmaxf(rmax, __shfl_xor(rmax, 32));
      const float mnew = fmaxf(mrun, rmax);
      const float alpha = __expf(mrun - mnew);
      mrun = mnew;
      float p[8];
#pragma unroll
      for (int i = 0; i < 8; i++) p[i] = __expf(s[i] - mnew);
      float rs = ((p[0] + p[1]) + (p[2] + p[3])) + ((p[4] + p[5]) + (p[6] + p[7]));
      rs += __shfl_xor(rs, 16);
      rs += __shfl_xor(rs, 32);
      lrun = lrun * alpha + rs;
      float alr[4];
#pragma unroll
      for (int r = 0; r < 4; r++) alr[r] = __shfl(alpha, quad * 4 + r);
      // ---- P store: row = q (wave*16+l16), packed u32 pairs over k ----
      {
        char* prow = smP + (wave * 16 + l16) * 80;
#pragma unroll
        for (int n = 0; n < 2; n++)
#pragma unroll
          for (int rp = 0; rp < 2; rp++) {
            const u32 w = (u32)f2b(p[n * 4 + rp * 2]) |
                          ((u32)f2b(p[n * 4 + rp * 2 + 1]) << 16);
            *(u32*)(prow + (n * 16 + quad * 4 + rp * 2) * 2) = w;
          }
      }
      // ---- rescale O (acc row q = wave*16 + quad*4 + r) ----
#pragma unroll
      for (int nt = 0; nt < 8; nt++)
#pragma unroll
        for (int r = 0; r < 4; r++) acc[nt][r] *= alr[r];
      // ---- O += P V ----
      {
        bf16x8 ap = *(const bf16x8*)(smP + (wave * 16 + l16) * 80 + quad * 16);
#pragma unroll
        for (int nt = 0; nt < 8; nt++) {
          bf16x8 bv = *(const bf16x8*)(smV + (nt * 16 + l16) * 64 +
                                       ((quad * 16) ^ vsw));
          acc[nt] = MFMA16(ap, bv, acc[nt]);
        }
      }
      __syncthreads();                         // next DMA landed; buffer reads done
      cur ^= 1;
    }
    // lrun lives in q=l16 layout; epilogue needs q=quad*4+r
    float lr[4];
#pragma unroll
    for (int r = 0; r < 4; r++) lr[r] = __shfl(lrun, quad * 4 + r);
    // ---- adapter attention (10 prefix keys, separate softmax) ----
    float* lAk = (float*)smVb;                 // overlay [16384,26624)
    float* lAv = lAk + AL_ * HS_;
    {
      const float* aks = akbuf + (size_t)h * AL_ * HS_;
      const float* avs = avbuf + (size_t)h * AL_ * HS_;
      for (int i = tid; i < AL_ * HS_; i += 256) { lAk[i] = aks[i]; lAv[i] = avs[i]; }
    }
    __syncthreads();
    const int ar = tid >> 2, ah = tid & 3;     // 4 threads per q-row
    const u16* qr = Qg + (size_t)ar * C3_ + ah * 32;   // Q re-read (L2-hot)
    float sa[AL_];
#pragma unroll
    for (int l = 0; l < AL_; l++) sa[l] = 0.f;
#pragma unroll
    for (int c = 0; c < 4; c++) {
      union { uint4 v; u16 e[8]; } qv;
      qv.v = *(const uint4*)(qr + c * 8);
#pragma unroll
      for (int j = 0; j < 8; j++) {
        const float qf2 = b2f(qv.e[j]);
#pragma unroll
        for (int l = 0; l < AL_; l++)
          sa[l] += qf2 * lAk[l * HS_ + ah * 32 + c * 8 + j];
      }
    }
#pragma unroll
    for (int l = 0; l < AL_; l++) {
      sa[l] += __shfl_xor(sa[l], 1);
      sa[l] += __shfl_xor(sa[l], 2);
      sa[l] *= scale;
    }
    float smax = sa[0];
#pragma unroll
    for (int l = 1; l < AL_; l++) smax = fmaxf(smax, sa[l]);
    float ssum = 0.f;
#pragma unroll
    for (int l = 0; l < AL_; l++) { sa[l] = __expf(sa[l] - smax); ssum += sa[l]; }
    const float inv = 1.f / ssum;
#pragma unroll
    for (int l = 0; l < AL_; l++) sa[l] *= inv;
    __syncthreads();                           // all adapter Q/lAk reads done
    u16* lAy = (u16*)smem;                     // overlay [0,16384): 64x128 u16
#pragma unroll
    for (int c = 0; c < 4; c++) {
      const int col = ah * 32 + c * 8;
      union { uint4 v; u16 e[8]; } ov;
#pragma unroll
      for (int j = 0; j < 8; j++) {
        float a = 0.f;
#pragma unroll
        for (int l = 0; l < AL_; l++) a += sa[l] * lAv[l * HS_ + col + j];
        ov.e[j] = f2b(a);
      }
      *(uint4*)(lAy + ar * HS_ + col) = ov.v;
    }
    __syncthreads();
    // ---- epilogue: y = O/l + g*ay, over qkv q-part (block's own patch) ----
    const float g = rb(gating[h]);
#pragma unroll
    for (int r = 0; r < 4; r++) {
      const int row = wave * 16 + quad * 4 + r;
      const float linv = 1.f / lr[r];
      u16* yrow = Qg + (size_t)row * C3_ + l16;
#pragma unroll
      for (int nt = 0; nt < 8; nt++) {
        const float v = acc[nt][r] * linv + g * b2f(lAy[row * HS_ + nt * 16 + l16]);
        yrow[nt * 16] = f2b(v);
      }
    }
    __syncthreads();                           // lAy reads done before next half's DMA
  }
#undef STAGE_KV
}

// ---------------------------------------------------------------------------
extern "C" void kernel_launch(void* const* d_in, const int* in_sizes, int n_in,
                              void* d_out, int out_size, void* d_ws, size_t ws_size,
                              hipStream_t stream) {
  (void)out_size;
  int ix = 0, irope = 1, iW = 3, iP = 4, iE = 5, iG = 6;
  for (int i = 0; i < n_in; i++) {
    switch (in_sizes[i]) {
      case 8388608:  ix = i;    break;   // x (2,2048,2048)
      case 262144:   irope = i; break;   // rope (2048,64,2)
      case 12582912: iW = i;    break;   // W_attn (6144,2048)
      case 20480:    iE = i;    break;   // adapter_emb (10,2048)
      case 16:       iG = i;    break;   // gating (1,16,1,1)
      case 4194304:  iP = i;    break;   // mask (idx 2) then W_proj (idx 4): last wins
      default: break;
    }
  }
  const float* x      = (const float*)d_in[ix];
  const float* rope   = (const float*)d_in[irope];
  const float* W_attn = (const float*)d_in[iW];
  const float* W_proj = (const float*)d_in[iP];
  const float* emb    = (const float*)d_in[iE];
  const float* gating = (const float*)d_in[iG];

  // Workspace layout (fast path, 96 MiB):
  //   [0,48M) qkv bf16 | [48,64M) xb | [64,88M) Wab | [88,96M) Wpb
  // d_out (32 MiB, dead until proj GEMM) hosts ak/av fp32 (160 KiB) + vt (16 MiB).
  u16*   qkv = (u16*)d_ws;
  float* akb = (float*)d_out;
  float* avb = akb + (size_t)H_ * AL_ * HS_;
  u16*   vtb = (u16*)(avb + (size_t)H_ * AL_ * HS_);

  const bool fast = ws_size >= (size_t)100663296;  // 96 MiB
  if (fast) {
    u16* xb  = qkv + (size_t)25165824;   // 48 MiB / 2
    u16* Wab = xb  + (size_t)8388608;
    u16* Wpb = Wab + (size_t)12582912;
    convert_all<<<dim3(12288), 256, 0, stream>>>(x, xb, W_attn, Wab, W_proj, Wpb);
    gemm_lds<false><<<dim3(48, 32), 256, 0, stream>>>(xb, Wab, qkv, 6144, 2048, 2048);
    adapter_pqkv<<<dim3(1024), 256, 0, stream>>>(emb, W_attn, akb, avb);
    rope_tv<<<dim3(17408), 256, 0, stream>>>(qkv, rope, vtb);
    attn_flash<<<dim3(16, 16, 2), 256, 0, stream>>>(qkv, vtb, akb, avb, gating);
    gemm_lds<true><<<dim3(16, 32), 256, 0, stream>>>(qkv, Wpb, (float*)d_out, 2048, 2048, 6144);
  } else {
    gemm_nt<true, true, false><<<dim3(48, 32), 256, 0, stream>>>(
        x, W_attn, qkv, 6144, 2048, 2048);
    adapter_pqkv<<<dim3(1024), 256, 0, stream>>>(emb, W_attn, akb, avb);
    rope_tv<<<dim3(17408), 256, 0, stream>>>(qkv, rope, vtb);
    attn_flash<<<dim3(16, 16, 2), 256, 0, stream>>>(qkv, vtb, akb, avb, gating);
    gemm_nt<false, true, true><<<dim3(16, 32), 256, 0, stream>>>(
        qkv, W_proj, (float*)d_out, 2048, 2048, 6144);
  }
}

// Round 10
// 486.284 us; speedup vs baseline: 1.5117x; 1.0548x over previous
//
#include <hip/hip_runtime.h>

typedef unsigned short u16;
typedef unsigned int u32;
typedef __bf16 bf16x8 __attribute__((ext_vector_type(8)));
typedef float f32x4 __attribute__((ext_vector_type(4)));

#define B_ 2
#define T_ 2048
#define C_ 2048
#define H_ 16
#define HS_ 128
#define AL_ 10
#define C3_ 6144
#define MASKV (-3.0e38f)   // finite "-inf": exp(MASKV - m) == 0
#define MFMA16(a, b, c) __builtin_amdgcn_mfma_f32_16x16x32_bf16(a, b, c, 0, 0, 0)

// async global->LDS DMA, 16B per lane. LDS dest = wave-uniform base + lane*16;
// global src is per-lane. size MUST be a literal (guide: Common-mistake #1).
#define GLDS16(g, l) __builtin_amdgcn_global_load_lds(                         \
    (const __attribute__((address_space(1))) u32*)(const void*)(g),            \
    (__attribute__((address_space(3))) u32*)(void*)(l), 16, 0, 0)

__device__ __forceinline__ float b2f(u16 v) {
  union { u32 u; float f; } x; x.u = ((u32)v) << 16; return x.f;
}
__device__ __forceinline__ u16 f2b(float f) {
  u32 u = __builtin_bit_cast(u32, f);
  return (u16)((u + 0x7FFFu + ((u >> 16) & 1u)) >> 16);  // RNE
}
// fp32 -> bf16 -> fp32 (match the np ref's bf16-cast of fp32 inputs)
__device__ __forceinline__ float rb(float f) { return b2f(f2b(f)); }

// ---------------------------------------------------------------------------
// Merged f32 -> bf16 bulk convert for x / W_attn / W_proj in ONE launch.
// ---------------------------------------------------------------------------
__global__ __launch_bounds__(256) void convert_all(
    const float* __restrict__ x,  u16* __restrict__ xb,
    const float* __restrict__ Wa, u16* __restrict__ Wab,
    const float* __restrict__ Wp, u16* __restrict__ Wpb)
{
  int i = blockIdx.x * 256 + threadIdx.x;        // 0 .. 3145727 (x8 elems)
  const float* in; u16* out;
  if (i < 1048576)      { in = x;  out = xb;  }
  else if (i < 2621440) { in = Wa; out = Wab; i -= 1048576; }
  else                  { in = Wp; out = Wpb; i -= 2621440; }
  union { float4 v[2]; float s[8]; } f;
  f.v[0] = *(const float4*)(in + (size_t)i * 8);
  f.v[1] = *(const float4*)(in + (size_t)i * 8 + 4);
  union { uint4 v; u16 e[8]; } o;
#pragma unroll
  for (int j = 0; j < 8; j++) o.e[j] = f2b(f.s[j]);
  *(uint4*)(out + (size_t)i * 8) = o.v;
}

// ---------------------------------------------------------------------------
// 256x256 deep-pipelined GEMM: C(MxN) = A(MxK) * B(NxK)^T, bf16 in, fp32
// accum. BK=64, 512 threads = 8 waves (2M x 4N), per-wave 128x64 output.
// All staging via global_load_lds DMA into double-buffered 128 KiB LDS with
// source-side inverse XOR swizzle (rule #21); ds_read_b128 with ^((l16&7)<<4)
// -> ~2-way banks (free). Tile t+1's 8 DMA ops issue interleaved through
// tile t's 4 compute phases (C-quadrants, setprio around 16-MFMA clusters);
// ONE raw s_barrier + vmcnt(0) per K-64 step (vs 4 full drains before).
// Barrier proof: slot^1 readers finished at previous barrier (no WAR);
// each wave awaits its own loads via vmcnt(0), barrier joins (no RAW).
// ---------------------------------------------------------------------------
template <bool OUTF32>
__global__ __launch_bounds__(512, 1) void gemm256(
    const u16* __restrict__ Ap, const u16* __restrict__ Bp,
    void* __restrict__ Cp, int N, int K, int lda)
{
  __shared__ __align__(16) u16 lds[65536];   // 2 slots x (A 16384 + B 16384)
  const int tid  = threadIdx.x;
  const int lane = tid & 63, wid = tid >> 6;
  const int quad = lane >> 4, l16 = lane & 15;
  const int wm2 = wid >> 2, wn4 = wid & 3;
  const int nwg = gridDim.x * gridDim.y;
  int bid = blockIdx.y * gridDim.x + blockIdx.x;
  bid = (bid & 7) * (nwg >> 3) + (bid >> 3);       // XCD swizzle (nwg%8==0)
  const int bm = (bid / gridDim.x) * 256, bn = (bid % gridDim.x) * 256;

  // DMA geometry: round j (0..3) covers rows j*64 + (tid>>3); thread's LDS
  // chunk s = tid&7 holds global chunk s ^ (row&7)  (row&7 == srow&7).
  const int srow = tid >> 3, schunk = tid & 7;
  const int gchunk = schunk ^ (srow & 7);
  const u16* gA = Ap + (size_t)(bm + srow) * lda + gchunk * 8;
  const u16* gB = Bp + (size_t)(bn + srow) * K + gchunk * 8;

  // PART: 0 = A rounds 0,1; 1 = A rounds 2,3; 2 = B rounds 0,1; 3 = B rounds 2,3
#define ST256(T, SL, PART) do {                                                \
    u16* d_ = lds + (SL) * 32768 + (((PART) >= 2) ? 16384 : 0)                 \
              + ((PART) & 1) * 8192 + wid * 512;                               \
    const size_t str_ = ((PART) >= 2) ? (size_t)K : (size_t)lda;               \
    const u16* g_ = (((PART) >= 2) ? gB : gA) + (size_t)(T) * 64               \
              + (size_t)((PART) & 1) * 128 * str_;                             \
    GLDS16(g_, d_);                                                            \
    GLDS16(g_ + 64 * str_, d_ + 4096);                                         \
  } while (0)

  f32x4 acc[8][4] = {};
  const int nt = K >> 6;
  const int asw = (l16 & 7) << 4;            // read-side swizzle (lane-const)

  // prologue: tile 0 -> slot 0
  ST256(0, 0, 0); ST256(0, 0, 1); ST256(0, 0, 2); ST256(0, 0, 3);
  asm volatile("s_waitcnt vmcnt(0)" ::: "memory");
  __builtin_amdgcn_s_barrier();
  __builtin_amdgcn_sched_barrier(0);

  int cur = 0;
  for (int t = 0; t < nt; ++t) {
    const char* sA = (const char*)(lds + cur * 32768);
    const char* sB = sA + 32768;             // +16384 u16
    const bool pf = (t + 1 < nt);
    const int ns = cur ^ 1;
    bf16x8 a[4][2], bq0[2][2], bq1[2][2];
    // ---- ph0: quadrant [m0-3][n0-1] ----
#pragma unroll
    for (int m = 0; m < 4; m++)
#pragma unroll
      for (int kk = 0; kk < 2; kk++)
        a[m][kk] = *(const bf16x8*)(sA + (wm2 * 128 + m * 16 + l16) * 128 +
                                    (((kk * 4 + quad) * 16) ^ asw));
#pragma unroll
    for (int n = 0; n < 2; n++)
#pragma unroll
      for (int kk = 0; kk < 2; kk++)
        bq0[n][kk] = *(const bf16x8*)(sB + (wn4 * 64 + n * 16 + l16) * 128 +
                                      (((kk * 4 + quad) * 16) ^ asw));
    if (pf) ST256(t + 1, ns, 0);
    __builtin_amdgcn_s_setprio(1);
#pragma unroll
    for (int m = 0; m < 4; m++)
#pragma unroll
      for (int n = 0; n < 2; n++)
#pragma unroll
        for (int kk = 0; kk < 2; kk++)
          acc[m][n] = MFMA16(a[m][kk], bq0[n][kk], acc[m][n]);
    __builtin_amdgcn_s_setprio(0);
    __builtin_amdgcn_sched_barrier(0);
    // ---- ph1: [m0-3][n2-3] ----
#pragma unroll
    for (int n = 0; n < 2; n++)
#pragma unroll
      for (int kk = 0; kk < 2; kk++)
        bq1[n][kk] = *(const bf16x8*)(sB + (wn4 * 64 + (n + 2) * 16 + l16) * 128 +
                                      (((kk * 4 + quad) * 16) ^ asw));
    if (pf) ST256(t + 1, ns, 1);
    __builtin_amdgcn_s_setprio(1);
#pragma unroll
    for (int m = 0; m < 4; m++)
#pragma unroll
      for (int n = 0; n < 2; n++)
#pragma unroll
        for (int kk = 0; kk < 2; kk++)
          acc[m][n + 2] = MFMA16(a[m][kk], bq1[n][kk], acc[m][n + 2]);
    __builtin_amdgcn_s_setprio(0);
    __builtin_amdgcn_sched_barrier(0);
    // ---- ph2: [m4-7][n2-3] ----
#pragma unroll
    for (int m = 0; m < 4; m++)
#pragma unroll
      for (int kk = 0; kk < 2; kk++)
        a[m][kk] = *(const bf16x8*)(sA + (wm2 * 128 + (m + 4) * 16 + l16) * 128 +
                                    (((kk * 4 + quad) * 16) ^ asw));
    if (pf) ST256(t + 1, ns, 2);
    __builtin_amdgcn_s_setprio(1);
#pragma unroll
    for (int m = 0; m < 4; m++)
#pragma unroll
      for (int n = 0; n < 2; n++)
#pragma unroll
        for (int kk = 0; kk < 2; kk++)
          acc[m + 4][n + 2] = MFMA16(a[m][kk], bq1[n][kk], acc[m + 4][n + 2]);
    __builtin_amdgcn_s_setprio(0);
    __builtin_amdgcn_sched_barrier(0);
    // ---- ph3: [m4-7][n0-1] ----
    if (pf) ST256(t + 1, ns, 3);
    __builtin_amdgcn_s_setprio(1);
#pragma unroll
    for (int m = 0; m < 4; m++)
#pragma unroll
      for (int n = 0; n < 2; n++)
#pragma unroll
        for (int kk = 0; kk < 2; kk++)
          acc[m + 4][n] = MFMA16(a[m][kk], bq0[n][kk], acc[m + 4][n]);
    __builtin_amdgcn_s_setprio(0);
    // ---- single per-tile join: next tile landed (own loads) + all waves done
    asm volatile("s_waitcnt vmcnt(0)" ::: "memory");
    __builtin_amdgcn_s_barrier();
    __builtin_amdgcn_sched_barrier(0);
    cur ^= 1;
  }
#undef ST256
  // C/D layout: col = lane&15, row = quad*4 + reg  [m89/m91 verified]
#pragma unroll
  for (int m = 0; m < 8; m++) {
#pragma unroll
    for (int r = 0; r < 4; r++) {
      const int row = bm + wm2 * 128 + m * 16 + quad * 4 + r;
      if constexpr (OUTF32) {
        float* crow = (float*)Cp + (size_t)row * N + bn + wn4 * 64 + l16;
#pragma unroll
        for (int n = 0; n < 4; n++)
          crow[n * 16] = acc[m][n][r];
      } else {
        u16* crow = (u16*)Cp + (size_t)row * N + bn + wn4 * 64 + l16;
#pragma unroll
        for (int n = 0; n < 4; n++)
          crow[n * 16] = f2b(acc[m][n][r]);
      }
    }
  }
}

// ---------------------------------------------------------------------------
// Fast GEMM (m97 structure): 128x128 tile, BK=32, verified. Used for gemm2.
// ---------------------------------------------------------------------------
template <bool OUTF32>
__global__ __launch_bounds__(256) void gemm_lds(
    const u16* __restrict__ Ap, const u16* __restrict__ Bp,
    void* __restrict__ Cp, int N, int K, int lda)
{
  __shared__ u16 lA[128 * 32];
  __shared__ u16 lB[128 * 32];
  const int tid  = threadIdx.x;
  const int lane = tid & 63, wave = tid >> 6;
  const int quad = lane >> 4, l16 = lane & 15;
  const int nwg = gridDim.x * gridDim.y;
  int bid = blockIdx.y * gridDim.x + blockIdx.x;
  bid = (bid & 7) * (nwg >> 3) + (bid >> 3);
  const int bm = (bid / gridDim.x) * 128, bn = (bid % gridDim.x) * 128;
  const int wm = (wave >> 1) * 64, wn = (wave & 1) * 64;

  const int r0 = wave * 16 + (lane >> 2);
  const int c0 = (lane & 3) * 8;
  const u16* ga0 = Ap + (size_t)(bm + r0) * lda + c0;
  const u16* ga1 = ga0 + (size_t)64 * lda;
  const u16* gb0 = Bp + (size_t)(bn + r0) * K + c0;
  const u16* gb1 = gb0 + (size_t)64 * K;
  u16* la0 = &lA[wave * 512];
  u16* lb0 = &lB[wave * 512];

  f32x4 acc[4][4] = {};
  for (int k0 = 0; k0 < K; k0 += 32) {
    __syncthreads();                       // prior-iter LDS reads done
    GLDS16(ga0, la0);
    GLDS16(ga1, la0 + 2048);
    GLDS16(gb0, lb0);
    GLDS16(gb1, lb0 + 2048);
    ga0 += 32; ga1 += 32; gb0 += 32; gb1 += 32;
    __syncthreads();                       // DMA landed
    bf16x8 af[4], bfv[4];
#pragma unroll
    for (int i = 0; i < 4; i++)
      af[i] = *(const bf16x8*)&lA[(wm + i * 16 + l16) * 32 + quad * 8];
#pragma unroll
    for (int i = 0; i < 4; i++)
      bfv[i] = *(const bf16x8*)&lB[(wn + i * 16 + l16) * 32 + quad * 8];
#pragma unroll
    for (int i = 0; i < 4; i++)
#pragma unroll
      for (int j = 0; j < 4; j++)
        acc[i][j] = MFMA16(af[i], bfv[j], acc[i][j]);
  }
#pragma unroll
  for (int i = 0; i < 4; i++) {
#pragma unroll
    for (int r = 0; r < 4; r++) {
      const int row = bm + wm + i * 16 + quad * 4 + r;
      if constexpr (OUTF32) {
        float* crow = (float*)Cp + (size_t)row * N + bn + wn + l16;
#pragma unroll
        for (int j = 0; j < 4; j++)
          crow[j * 16] = acc[i][j][r];
      } else {
        u16* crow = (u16*)Cp + (size_t)row * N + bn + wn + l16;
#pragma unroll
        for (int j = 0; j < 4; j++)
          crow[j * 16] = f2b(acc[i][j][r]);
      }
    }
  }
}

// ---------------------------------------------------------------------------
// Fallback GEMM (used only if ws_size can't host bf16 copies).
// ---------------------------------------------------------------------------
template <bool AF32, bool BF32, bool OUTF32>
__global__ __launch_bounds__(256) void gemm_nt(
    const void* __restrict__ Ap, const void* __restrict__ Bp,
    void* __restrict__ Cp, int N, int K, int lda)
{
  __shared__ u16 lA[128 * 32];
  __shared__ u16 lB[128 * 32];
  const int tid  = threadIdx.x;
  const int lane = tid & 63, wave = tid >> 6;
  const int quad = lane >> 4, l16 = lane & 15;
  const int bm = blockIdx.y * 128, bn = blockIdx.x * 128;
  const int wm = (wave >> 1) * 64, wn = (wave & 1) * 64;
  const int srow = tid >> 1, scol = (tid & 1) * 16;
  f32x4 acc[4][4] = {};

  for (int k0 = 0; k0 < K; k0 += 32) {
    __align__(16) u16 abuf[16], bbuf[16];
    if constexpr (AF32) {
      const float* gA = (const float*)Ap + (size_t)(bm + srow) * lda + scol + k0;
      union { float4 v[4]; float s[16]; } fa;
#pragma unroll
      for (int j = 0; j < 4; j++) fa.v[j] = *(const float4*)(gA + j * 4);
#pragma unroll
      for (int j = 0; j < 16; j++) abuf[j] = f2b(fa.s[j]);
    } else {
      const u16* gA = (const u16*)Ap + (size_t)(bm + srow) * lda + scol + k0;
      *(uint4*)&abuf[0] = *(const uint4*)(gA);
      *(uint4*)&abuf[8] = *(const uint4*)(gA + 8);
    }
    if constexpr (BF32) {
      const float* gB = (const float*)Bp + (size_t)(bn + srow) * K + scol + k0;
      union { float4 v[4]; float s[16]; } fb;
#pragma unroll
      for (int j = 0; j < 4; j++) fb.v[j] = *(const float4*)(gB + j * 4);
#pragma unroll
      for (int j = 0; j < 16; j++) bbuf[j] = f2b(fb.s[j]);
    } else {
      const u16* gB = (const u16*)Bp + (size_t)(bn + srow) * K + scol + k0;
      *(uint4*)&bbuf[0] = *(const uint4*)(gB);
      *(uint4*)&bbuf[8] = *(const uint4*)(gB + 8);
    }
    __syncthreads();
    *(uint4*)&lA[srow * 32 + scol]     = *(uint4*)&abuf[0];
    *(uint4*)&lA[srow * 32 + scol + 8] = *(uint4*)&abuf[8];
    *(uint4*)&lB[srow * 32 + scol]     = *(uint4*)&bbuf[0];
    *(uint4*)&lB[srow * 32 + scol + 8] = *(uint4*)&bbuf[8];
    __syncthreads();
    bf16x8 af[4], bfv[4];
#pragma unroll
    for (int i = 0; i < 4; i++)
      af[i] = *(const bf16x8*)&lA[(wm + i * 16 + l16) * 32 + quad * 8];
#pragma unroll
    for (int i = 0; i < 4; i++)
      bfv[i] = *(const bf16x8*)&lB[(wn + i * 16 + l16) * 32 + quad * 8];
#pragma unroll
    for (int i = 0; i < 4; i++)
#pragma unroll
      for (int j = 0; j < 4; j++)
        acc[i][j] = MFMA16(af[i], bfv[j], acc[i][j]);
  }
#pragma unroll
  for (int i = 0; i < 4; i++) {
#pragma unroll
    for (int r = 0; r < 4; r++) {
      const int row = bm + wm + i * 16 + quad * 4 + r;
      if constexpr (OUTF32) {
        float* crow = (float*)Cp + (size_t)row * N + bn + wn + l16;
#pragma unroll
        for (int j = 0; j < 4; j++)
          crow[j * 16] = acc[i][j][r];
      } else {
        u16* crow = (u16*)Cp + (size_t)row * N + bn + wn + l16;
#pragma unroll
        for (int j = 0; j < 4; j++)
          crow[j * 16] = f2b(acc[i][j][r]);
      }
    }
  }
}

// ---------------------------------------------------------------------------
// Adapter pqkv: ak/av[h][l][d] = bf16(adapter_emb[l]) . bf16(W_attn[...]).
// ---------------------------------------------------------------------------
__global__ __launch_bounds__(256) void adapter_pqkv(
    const float* __restrict__ emb, const float* __restrict__ W,
    float* __restrict__ akb, float* __restrict__ avb)
{
  const int tid = threadIdx.x;
  const int lane = tid & 63;
  const int w = blockIdx.x * 4 + (tid >> 6);      // 0..4095
  const int part = w >> 11;                        // 0 = k, 1 = v
  const int col = w & 2047;                        // h*128 + d
  const float* wrow = W + (size_t)(C_ + part * C_ + col) * C_;
  float acc[AL_];
#pragma unroll
  for (int l = 0; l < AL_; l++) acc[l] = 0.f;
  for (int i = 0; i < 32; i++) {
    const int c = i * 64 + lane;
    const float wv = rb(wrow[c]);
#pragma unroll
    for (int l = 0; l < AL_; l++) acc[l] += wv * rb(emb[l * C_ + c]);
  }
#pragma unroll
  for (int l = 0; l < AL_; l++) {
    for (int off = 32; off > 0; off >>= 1) acc[l] += __shfl_xor(acc[l], off);
  }
  if (lane == 0) {
    const int h = col >> 7, d = col & 127;
    float* dst = (part == 0 ? akb : avb) + (size_t)h * AL_ * HS_ + d;
#pragma unroll
    for (int l = 0; l < AL_; l++) dst[l * HS_] = acc[l];
  }
}

// ---------------------------------------------------------------------------
// Merged RoPE (blocks [0,16384)) + V transpose (blocks [16384,17408)).
// ---------------------------------------------------------------------------
__global__ __launch_bounds__(256) void rope_tv(
    u16* __restrict__ qkv, const float* __restrict__ rope,
    u16* __restrict__ vt)
{
  __shared__ __align__(16) char lT[64 * 256];
  const int bid = blockIdx.x;
  if (bid < 16384) {                         // ---- rope path ----
    const int g = bid * 256 + threadIdx.x;
    const int j2 = g & 63;
    const int h  = (g >> 6) & 15;
    const int t  = (g >> 10) & 2047;
    const int b  = g >> 21;
    u16* src = qkv + (size_t)(b * T_ + t) * C3_ + h * HS_ + j2 * 2;
    const u32 qp = *(const u32*)(src);
    const u32 kp = *(const u32*)(src + C_);
    const float2 rp = *(const float2*)(rope + (t * 64 + j2) * 2);
    const float c = rb(rp.x), s = rb(rp.y);
    const float q0 = b2f((u16)qp), q1 = b2f((u16)(qp >> 16));
    const float k0 = b2f((u16)kp), k1 = b2f((u16)(kp >> 16));
    const float qr0 = q0 * c - q1 * s, qr1 = q1 * c + q0 * s;
    const float kr0 = k0 * c - k1 * s, kr1 = k1 * c + k0 * s;
    *(u32*)(src)      = (u32)f2b(qr0) | ((u32)f2b(qr1) << 16);
    *(u32*)(src + C_) = (u32)f2b(kr0) | ((u32)f2b(kr1) << 16);
    return;
  }
  // ---- transpose path (1024 blocks) ----
  const int r = bid - 16384;
  const int tid = threadIdx.x;
  const int t0 = (r & 31) * 64, h = (r >> 5) & 15, b = r >> 9;
  const u16* Vg = qkv + (size_t)(b * T_ + t0) * C3_ + 2 * C_ + h * HS_;
#pragma unroll
  for (int i = 0; i < 4; i++) {
    const int e = (i * 256 + tid) * 8;      // u16 linear index in 64x128
    const int t = e >> 7, c = e & 127;
    *(uint4*)(lT + t * 256 + ((c * 2) ^ ((t & 7) << 4))) =
        *(const uint4*)(Vg + (size_t)t * C3_ + c);
  }
  __syncthreads();
  const int d = tid >> 1, half = tid & 1;
  __align__(16) u16 out[32];
#pragma unroll
  for (int tt = 0; tt < 32; tt++) {
    const int t = half * 32 + tt;
    out[tt] = *(const u16*)(lT + t * 256 + ((d * 2) ^ ((t & 7) << 4)));
  }
  u16* dst = vt + ((size_t)(b * H_ + h) * HS_ + d) * T_ + t0 + half * 32;
  *(uint4*)(dst)      = *(const uint4*)&out[0];
  *(uint4*)(dst + 8)  = *(const uint4*)&out[8];
  *(uint4*)(dst + 16) = *(const uint4*)&out[16];
  *(uint4*)(dst + 24) = *(const uint4*)&out[24];
}

// ---------------------------------------------------------------------------
// Flash attention + gated adapter attention (R9 verified; unchanged).
// ---------------------------------------------------------------------------
__global__ __launch_bounds__(256, 4) void attn_flash(
    u16* __restrict__ qkv, const u16* __restrict__ vt,
    const float* __restrict__ akbuf, const float* __restrict__ avbuf,
    const float* __restrict__ gating)
{
  __shared__ __align__(16) char smem[37888];
  char* smKb = smem;                   // [0,16384)      2 x (32 rows x 256B)
  char* smVb = smem + 16384;           // [16384,32768)  2 x (128 d x 64B)
  char* smP  = smem + 32768;           // [32768,37888)  P: 64 rows x 80B

  const int tid  = threadIdx.x;
  const int lane = tid & 63, wave = tid >> 6;
  const int quad = lane >> 4, l16 = lane & 15;
  const int bx = blockIdx.x, h = blockIdx.y, b = blockIdx.z;
  const u16* Kg = qkv + (size_t)(b * T_) * C3_ + C_ + h * HS_;            // k-part
  const u16* Vt = vt + (size_t)(b * H_ + h) * HS_ * T_;
  const float scale = 0.08838834764831845f;   // 1/sqrt(128)

  const int krow = wave * 4 + (lane >> 4);
  const int kco  = (((lane & 15) * 16) ^ ((krow & 7) << 4)) >> 1;
  const int vd0 = wave * 16 + (lane >> 2);
  const int vco = (((lane & 3) * 16) ^ (((vd0 >> 1) & 3) << 4)) >> 1;
  const int vsw = ((l16 >> 1) & 3) << 4;       // V read swizzle (lane-const)

#define STAGE_KV(KT, BUF) do {                                                 \
    char* kb_ = smKb + (BUF) * 8192 + wave * 1024;                             \
    char* vb_ = smVb + (BUF) * 8192 + wave * 1024;                             \
    const u16* ks0_ = Kg + (size_t)((KT) * 32 + krow) * C3_ + kco;             \
    const u16* ks1_ = Kg + (size_t)((KT) * 32 + 16 + krow) * C3_ + kco;        \
    GLDS16(ks0_, kb_);                                                         \
    GLDS16(ks1_, kb_ + 4096);                                                  \
    const u16* vs0_ = Vt + (size_t)vd0 * T_ + (KT) * 32 + vco;                 \
    const u16* vs1_ = Vt + (size_t)(vd0 + 64) * T_ + (KT) * 32 + vco;          \
    GLDS16(vs0_, vb_);                                                         \
    GLDS16(vs1_, vb_ + 4096);                                                  \
  } while (0)

  for (int half = 0; half < 2; half++) {
    const int qt = half ? bx : 31 - bx;        // heavy tile first
    u16* Qg = qkv + ((size_t)(b * T_) + qt * 64) * C3_ + h * HS_;

    bf16x8 qf[4];
    {
      const u16* qrow = Qg + (size_t)(wave * 16 + l16) * C3_;
#pragma unroll
      for (int kk = 0; kk < 4; kk++)
        qf[kk] = *(const bf16x8*)(qrow + kk * 32 + quad * 8);
    }

    f32x4 acc[8] = {};
    float mrun = MASKV, lrun = 0.f;            // stats for q-row = wave*16+l16
    const int nkt = (qt + 1) * 2;
    const int qg = qt * 64 + wave * 16 + l16;  // this lane's q-row (score side)

    STAGE_KV(0, 0);
    __syncthreads();                           // DMA landed (drains vmcnt)

    int cur = 0;
    for (int kt = 0; kt < nkt; kt++) {
      if (kt + 1 < nkt) STAGE_KV(kt + 1, cur ^ 1);
      const char* smK = smKb + cur * 8192;
      const char* smV = smVb + cur * 8192;
      f32x4 sacc[2] = {};
      const int sw = (l16 & 7) << 4;
#pragma unroll
      for (int kk = 0; kk < 4; kk++) {
        const int co = (kk * 64 + quad * 16) ^ sw;
        bf16x8 bk0 = *(const bf16x8*)(smK + l16 * 256 + co);
        bf16x8 bk1 = *(const bf16x8*)(smK + (16 + l16) * 256 + co);
        sacc[0] = MFMA16(bk0, qf[kk], sacc[0]);
        sacc[1] = MFMA16(bk1, qf[kk], sacc[1]);
      }
      float s[8];
#pragma unroll
      for (int n = 0; n < 2; n++)
#pragma unroll
        for (int r = 0; r < 4; r++) {
          float v = sacc[n][r] * scale;
          if (kt * 32 + n * 16 + quad * 4 + r > qg) v = MASKV;
          s[n * 4 + r] = v;
        }
      float rmax = fmaxf(fmaxf(fmaxf(s[0], s[1]), fmaxf(s[2], s[3])),
                         fmaxf(fmaxf(s[4], s[5]), fmaxf(s[6], s[7])));
      rmax = fmaxf(rmax, __shfl_xor(rmax, 16));
      rmax = fmaxf(rmax, __shfl_xor(rmax, 32));
      const float mnew = fmaxf(mrun, rmax);
      const float alpha = __expf(mrun - mnew);
      mrun = mnew;
      float p[8];
#pragma unroll
      for (int i = 0; i < 8; i++) p[i] = __expf(s[i] - mnew);
      float rs = ((p[0] + p[1]) + (p[2] + p[3])) + ((p[4] + p[5]) + (p[6] + p[7]));
      rs += __shfl_xor(rs, 16);
      rs += __shfl_xor(rs, 32);
      lrun = lrun * alpha + rs;
      float alr[4];
#pragma unroll
      for (int r = 0; r < 4; r++) alr[r] = __shfl(alpha, quad * 4 + r);
      {
        char* prow = smP + (wave * 16 + l16) * 80;
#pragma unroll
        for (int n = 0; n < 2; n++)
#pragma unroll
          for (int rp = 0; rp < 2; rp++) {
            const u32 w = (u32)f2b(p[n * 4 + rp * 2]) |
                          ((u32)f2b(p[n * 4 + rp * 2 + 1]) << 16);
            *(u32*)(prow + (n * 16 + quad * 4 + rp * 2) * 2) = w;
          }
      }
#pragma unroll
      for (int nt = 0; nt < 8; nt++)
#pragma unroll
        for (int r = 0; r < 4; r++) acc[nt][r] *= alr[r];
      {
        bf16x8 ap = *(const bf16x8*)(smP + (wave * 16 + l16) * 80 + quad * 16);
#pragma unroll
        for (int nt = 0; nt < 8; nt++) {
          bf16x8 bv = *(const bf16x8*)(smV + (nt * 16 + l16) * 64 +
                                       ((quad * 16) ^ vsw));
          acc[nt] = MFMA16(ap, bv, acc[nt]);
        }
      }
      __syncthreads();                         // next DMA landed; buffer reads done
      cur ^= 1;
    }
    float lr[4];
#pragma unroll
    for (int r = 0; r < 4; r++) lr[r] = __shfl(lrun, quad * 4 + r);
    // ---- adapter attention (10 prefix keys, separate softmax) ----
    float* lAk = (float*)smVb;                 // overlay [16384,26624)
    float* lAv = lAk + AL_ * HS_;
    {
      const float* aks = akbuf + (size_t)h * AL_ * HS_;
      const float* avs = avbuf + (size_t)h * AL_ * HS_;
      for (int i = tid; i < AL_ * HS_; i += 256) { lAk[i] = aks[i]; lAv[i] = avs[i]; }
    }
    __syncthreads();
    const int ar = tid >> 2, ah = tid & 3;     // 4 threads per q-row
    const u16* qr = Qg + (size_t)ar * C3_ + ah * 32;   // Q re-read (L2-hot)
    float sa[AL_];
#pragma unroll
    for (int l = 0; l < AL_; l++) sa[l] = 0.f;
#pragma unroll
    for (int c = 0; c < 4; c++) {
      union { uint4 v; u16 e[8]; } qv;
      qv.v = *(const uint4*)(qr + c * 8);
#pragma unroll
      for (int j = 0; j < 8; j++) {
        const float qf2 = b2f(qv.e[j]);
#pragma unroll
        for (int l = 0; l < AL_; l++)
          sa[l] += qf2 * lAk[l * HS_ + ah * 32 + c * 8 + j];
      }
    }
#pragma unroll
    for (int l = 0; l < AL_; l++) {
      sa[l] += __shfl_xor(sa[l], 1);
      sa[l] += __shfl_xor(sa[l], 2);
      sa[l] *= scale;
    }
    float smax = sa[0];
#pragma unroll
    for (int l = 1; l < AL_; l++) smax = fmaxf(smax, sa[l]);
    float ssum = 0.f;
#pragma unroll
    for (int l = 0; l < AL_; l++) { sa[l] = __expf(sa[l] - smax); ssum += sa[l]; }
    const float inv = 1.f / ssum;
#pragma unroll
    for (int l = 0; l < AL_; l++) sa[l] *= inv;
    __syncthreads();                           // all adapter Q/lAk reads done
    u16* lAy = (u16*)smem;                     // overlay [0,16384): 64x128 u16
#pragma unroll
    for (int c = 0; c < 4; c++) {
      const int col = ah * 32 + c * 8;
      union { uint4 v; u16 e[8]; } ov;
#pragma unroll
      for (int j = 0; j < 8; j++) {
        float a = 0.f;
#pragma unroll
        for (int l = 0; l < AL_; l++) a += sa[l] * lAv[l * HS_ + col + j];
        ov.e[j] = f2b(a);
      }
      *(uint4*)(lAy + ar * HS_ + col) = ov.v;
    }
    __syncthreads();
    // ---- epilogue: y = O/l + g*ay, over qkv q-part (block's own patch) ----
    const float g = rb(gating[h]);
#pragma unroll
    for (int r = 0; r < 4; r++) {
      const int row = wave * 16 + quad * 4 + r;
      const float linv = 1.f / lr[r];
      u16* yrow = Qg + (size_t)row * C3_ + l16;
#pragma unroll
      for (int nt = 0; nt < 8; nt++) {
        const float v = acc[nt][r] * linv + g * b2f(lAy[row * HS_ + nt * 16 + l16]);
        yrow[nt * 16] = f2b(v);
      }
    }
    __syncthreads();                           // lAy reads done before next half's DMA
  }
#undef STAGE_KV
}

// ---------------------------------------------------------------------------
extern "C" void kernel_launch(void* const* d_in, const int* in_sizes, int n_in,
                              void* d_out, int out_size, void* d_ws, size_t ws_size,
                              hipStream_t stream) {
  (void)out_size;
  int ix = 0, irope = 1, iW = 3, iP = 4, iE = 5, iG = 6;
  for (int i = 0; i < n_in; i++) {
    switch (in_sizes[i]) {
      case 8388608:  ix = i;    break;   // x (2,2048,2048)
      case 262144:   irope = i; break;   // rope (2048,64,2)
      case 12582912: iW = i;    break;   // W_attn (6144,2048)
      case 20480:    iE = i;    break;   // adapter_emb (10,2048)
      case 16:       iG = i;    break;   // gating (1,16,1,1)
      case 4194304:  iP = i;    break;   // mask (idx 2) then W_proj (idx 4): last wins
      default: break;
    }
  }
  const float* x      = (const float*)d_in[ix];
  const float* rope   = (const float*)d_in[irope];
  const float* W_attn = (const float*)d_in[iW];
  const float* W_proj = (const float*)d_in[iP];
  const float* emb    = (const float*)d_in[iE];
  const float* gating = (const float*)d_in[iG];

  // Workspace layout (fast path, 96 MiB):
  //   [0,48M) qkv bf16 | [48,64M) xb | [64,88M) Wab | [88,96M) Wpb
  // d_out (32 MiB, dead until proj GEMM) hosts ak/av fp32 (160 KiB) + vt (16 MiB).
  u16*   qkv = (u16*)d_ws;
  float* akb = (float*)d_out;
  float* avb = akb + (size_t)H_ * AL_ * HS_;
  u16*   vtb = (u16*)(avb + (size_t)H_ * AL_ * HS_);

  const bool fast = ws_size >= (size_t)100663296;  // 96 MiB
  if (fast) {
    u16* xb  = qkv + (size_t)25165824;   // 48 MiB / 2
    u16* Wab = xb  + (size_t)8388608;
    u16* Wpb = Wab + (size_t)12582912;
    convert_all<<<dim3(12288), 256, 0, stream>>>(x, xb, W_attn, Wab, W_proj, Wpb);
    // qkv = xb @ Wab^T   (M=4096, N=6144, K=2048): 256^2 deep-pipelined GEMM
    gemm256<false><<<dim3(24, 16), 512, 0, stream>>>(xb, Wab, qkv, 6144, 2048, 2048);
    adapter_pqkv<<<dim3(1024), 256, 0, stream>>>(emb, W_attn, akb, avb);
    rope_tv<<<dim3(17408), 256, 0, stream>>>(qkv, rope, vtb);
    attn_flash<<<dim3(16, 16, 2), 256, 0, stream>>>(qkv, vtb, akb, avb, gating);
    gemm_lds<true><<<dim3(16, 32), 256, 0, stream>>>(qkv, Wpb, (float*)d_out, 2048, 2048, 6144);
  } else {
    gemm_nt<true, true, false><<<dim3(48, 32), 256, 0, stream>>>(
        x, W_attn, qkv, 6144, 2048, 2048);
    adapter_pqkv<<<dim3(1024), 256, 0, stream>>>(emb, W_attn, akb, avb);
    rope_tv<<<dim3(17408), 256, 0, stream>>>(qkv, rope, vtb);
    attn_flash<<<dim3(16, 16, 2), 256, 0, stream>>>(qkv, vtb, akb, avb, gating);
    gemm_nt<false, true, true><<<dim3(16, 32), 256, 0, stream>>>(
        qkv, W_proj, (float*)d_out, 2048, 2048, 6144);
  }
}